// Round 4
// baseline (1653.787 us; speedup 1.0000x reference)
//
#include <hip/hip_runtime.h>
#include <math.h>

// B=8, C=128, H=128, W=128, D_INNER=256, D_STATE=64, HEADDIM=32, NHEADS=8,
// D_CONV=4, GN_GROUPS=8, D_XBC=384, D_INPROJ=648.
// Inputs f32 (probed via gn_g word0). OUTPUT IS F32 (reference output dtype).
// d_out = [out_2d: 16,777,216 f32][offset: 131,072 f32].
// h1 (f32) is staged in d_out's out_2d region.
//
// R1: scan de-spilled -> 3236us. R2: register-blocked VALU GEMMs -> 2123us.
// R3: MFMA f16 GEMMs -> 1078us. R4: (a) dwconv v2 - 64x64 tiles, f32 halo in
// LDS, 4x4 outputs/thread via 2x ds_read_b128/row (25 scalar u16 reads+cvt per
// output -> 1 b128); (b) scan v4 - 4-way state split across lanes
// (lane=d*4+sq, h[16]/thread, shfl_xor combine) -> 4x occupancy, 4x shorter
// per-step chain.

typedef _Float16 half8 __attribute__((ext_vector_type(8)));
typedef float f32x4 __attribute__((ext_vector_type(4)));

__device__ __forceinline__ float b2f(unsigned short u) {
  return __uint_as_float(((unsigned int)u) << 16);
}
__device__ __forceinline__ bool in_is_f32(const void* gng) {
  return ((const unsigned int*)gng)[0] == 0x3F800000u;
}

#define P_DWW 0
#define P_CW 3200
#define P_CB 4736
#define P_GNG 5120
#define P_GNB 5248
#define P_PWW 5376
#define P_PWB 5504
#define P_DTB 5505
#define P_ALOG 5513
#define P_DSKIP 5521
#define P_NG 5529

__global__ void k_prep_params(const void* dww, const void* cw, const void* cb,
                              const void* gng, const void* gnb, const void* pww,
                              const void* pwb, const void* dtbias, const void* alog,
                              const void* dskip, const void* ng, float* __restrict__ P,
                              float* __restrict__ gst) {
  bool f = in_is_f32(gng);
  int tid = threadIdx.x;
  if (tid < 128) gst[tid] = 0.f;
  auto cvt = [&](const void* src, int n, int off) {
    for (int i = tid; i < n; i += 256)
      P[off + i] = f ? ((const float*)src)[i] : b2f(((const unsigned short*)src)[i]);
  };
  cvt(dww, 3200, P_DWW);
  cvt(cw, 1536, P_CW);
  cvt(cb, 384, P_CB);
  cvt(gng, 128, P_GNG);
  cvt(gnb, 128, P_GNB);
  cvt(pww, 128, P_PWW);
  cvt(pwb, 1, P_PWB);
  cvt(dtbias, 8, P_DTB);
  cvt(alog, 8, P_ALOG);
  cvt(dskip, 8, P_DSKIP);
  cvt(ng, 256, P_NG);
}

// wprojh: 768 x 128 f16 (rows >=648 zero).  outwh: 128 x 256 f16.
__global__ void k_prep_w(const void* wproj, const void* outw, const void* gng,
                         _Float16* __restrict__ wprojh, _Float16* __restrict__ outwh) {
  bool f = in_is_f32(gng);
  int stride = gridDim.x * blockDim.x;
  for (int i = blockIdx.x * blockDim.x + threadIdx.x; i < 98304; i += stride) {
    int row = i >> 7;
    float v = 0.f;
    if (row < 648) v = f ? ((const float*)wproj)[i] : b2f(((const unsigned short*)wproj)[i]);
    wprojh[i] = (_Float16)v;
  }
  for (int i = blockIdx.x * blockDim.x + threadIdx.x; i < 32768; i += stride)
    outwh[i] = (_Float16)(f ? ((const float*)outw)[i] : b2f(((const unsigned short*)outw)[i]));
}

// ---------------- K1 v2: depthwise 5x5 conv + group stats -----------------------
// 4 blocks per (b,c): 64x64 output tile, 68x68 f32 halo in LDS (stride 72).
// Thread: 4x4 outputs; per input row two aligned b128 reads -> 8 in-regs -> 20 FMA.
__global__ __launch_bounds__(256) void k_dwconv_v2(const void* __restrict__ x,
                                                   const void* __restrict__ gng,
                                                   const float* __restrict__ P,
                                                   float* __restrict__ h1,
                                                   float* __restrict__ gst) {
  int blk = blockIdx.x;
  int bc = blk >> 2, sub = blk & 3;
  int b = bc >> 7, c = bc & 127;
  int ty0 = (sub >> 1) * 64, tx0 = (sub & 1) * 64;
  bool f32x = in_is_f32(gng);
  __shared__ __align__(16) float t[68 * 72];
  __shared__ float red[8];
  const float* xf = (const float*)x + (size_t)bc * 16384;
  const unsigned short* xb = (const unsigned short*)x + (size_t)bc * 16384;
  for (int i = threadIdx.x; i < 68 * 68; i += 256) {
    int r = i / 68, cc = i - r * 68;
    int gy = ty0 + r - 2, gx = tx0 + cc - 2;
    float v = 0.f;
    if (gy >= 0 && gy < 128 && gx >= 0 && gx < 128) {
      int off = gy * 128 + gx;
      v = f32x ? xf[off] : b2f(xb[off]);
    }
    t[r * 72 + cc] = v;
  }
  float w[25];
#pragma unroll
  for (int k = 0; k < 25; ++k) w[k] = P[P_DWW + c * 25 + k];
  __syncthreads();

  int ox = (threadIdx.x & 15) * 4;
  int oy = (threadIdx.x >> 4) * 4;
  float acc[4][4];
#pragma unroll
  for (int r = 0; r < 4; ++r)
#pragma unroll
    for (int j = 0; j < 4; ++j) acc[r][j] = 0.f;

#pragma unroll
  for (int i = 0; i < 8; ++i) {
    float4 p0 = *(const float4*)&t[(oy + i) * 72 + ox];
    float4 p1 = *(const float4*)&t[(oy + i) * 72 + ox + 4];
    float in8[8] = {p0.x, p0.y, p0.z, p0.w, p1.x, p1.y, p1.z, p1.w};
#pragma unroll
    for (int r = 0; r < 4; ++r) {
      if (i - r >= 0 && i - r <= 4) {
        int ky = i - r;
#pragma unroll
        for (int j = 0; j < 4; ++j)
#pragma unroll
          for (int kx = 0; kx < 5; ++kx)
            acc[r][j] += w[ky * 5 + kx] * in8[j + kx];
      }
    }
  }

  float s = 0.f, sq = 0.f;
  float* hp = h1 + (size_t)bc * 16384;
#pragma unroll
  for (int r = 0; r < 4; ++r) {
    *(float4*)&hp[(ty0 + oy + r) * 128 + tx0 + ox] =
        make_float4(acc[r][0], acc[r][1], acc[r][2], acc[r][3]);
#pragma unroll
    for (int j = 0; j < 4; ++j) { s += acc[r][j]; sq += acc[r][j] * acc[r][j]; }
  }
  for (int o = 32; o; o >>= 1) { s += __shfl_down(s, o, 64); sq += __shfl_down(sq, o, 64); }
  int wv = threadIdx.x >> 6;
  if ((threadIdx.x & 63) == 0) { red[wv] = s; red[4 + wv] = sq; }
  __syncthreads();
  if (threadIdx.x == 0) {
    float ts = red[0] + red[1] + red[2] + red[3];
    float tq = red[4] + red[5] + red[6] + red[7];
    int g = (b << 3) + (c >> 4);
    atomicAdd(&gst[g * 2], ts);
    atomicAdd(&gst[g * 2 + 1], tq);
  }
}

__global__ void k_stats(const float* __restrict__ gst, float* __restrict__ mr) {
  int g = threadIdx.x;
  if (g < 64) {
    const float invN = 1.f / 262144.f;
    float mean = gst[g * 2] * invN;
    float var = gst[g * 2 + 1] * invN - mean * mean;
    mr[g * 2] = mean;
    mr[g * 2 + 1] = rsqrtf(var + 1e-5f);
  }
}

// ---------------- K3: GN + exact GELU + 1x1 conv + tanh*8 -> offset (f32 out) ----
__global__ __launch_bounds__(128) void k_gn_off(const float* __restrict__ h1,
                                                const float* __restrict__ mr,
                                                const float* __restrict__ P,
                                                float* __restrict__ offf,
                                                float* __restrict__ dout) {
  int bh = blockIdx.x;
  int b = bh >> 7, h = bh & 127;
  int w = threadIdx.x;
  float acc = 0.f;
  for (int c = 0; c < 128; ++c) {
    float v = h1[(((size_t)(b * 128 + c)) * 128 + h) * 128 + w];
    int g = b * 8 + (c >> 4);
    float nv = (v - mr[g * 2]) * mr[g * 2 + 1] * P[P_GNG + c] + P[P_GNB + c];
    float ge = 0.5f * nv * (1.f + erff(nv * 0.70710678118f));
    acc += ge * P[P_PWW + c];
  }
  float off = acc + P[P_PWB];
  float ofv = tanhf(off) * 8.0f;
  offf[bh * 128 + w] = ofv;
  dout[16777216 + bh * 128 + w] = ofv;
}

// ---------------- K4: y-only grid sample + transpose -> seq f16 (l,c) ------------
__global__ __launch_bounds__(128) void k_deform(const void* __restrict__ x,
                                                const void* __restrict__ gng,
                                                const float* __restrict__ offf,
                                                _Float16* __restrict__ seqc,
                                                int s0) {
  int bh = s0 + blockIdx.x;
  int b = bh >> 7, h = bh & 127;
  int w = threadIdx.x;
  bool f32x = in_is_f32(gng);
  __shared__ float t[128 * 130];
  float ofv = offf[bh * 128 + w];
  float gy = -1.f + (2.f / 127.f) * (float)h + ofv * (2.f / 127.f);
  gy = fminf(fmaxf(gy, -1.f), 1.f);
  float py = (gy + 1.f) * 0.5f * 127.f;
  py = fminf(fmaxf(py, 0.f), 127.f);
  float y0f = floorf(py);
  float wy = py - y0f;
  int y0 = (int)y0f;
  int y1 = min(y0 + 1, 127);
  const float* xfb = (const float*)x + (size_t)b * 128 * 16384;
  const unsigned short* xbb = (const unsigned short*)x + (size_t)b * 128 * 16384;
  for (int c = 0; c < 128; ++c) {
    size_t o0 = (size_t)c * 16384 + y0 * 128 + w;
    size_t o1 = (size_t)c * 16384 + y1 * 128 + w;
    float v0, v1;
    if (f32x) { v0 = xfb[o0]; v1 = xfb[o1]; }
    else      { v0 = b2f(xbb[o0]); v1 = b2f(xbb[o1]); }
    t[c * 130 + w] = v0 + wy * (v1 - v0);
  }
  __syncthreads();
  int c = threadIdx.x;
  _Float16* sp = seqc + (size_t)blockIdx.x * 16384;
  for (int l = 0; l < 128; ++l) sp[l * 128 + c] = (_Float16)t[c * 130 + l];
}

// ---------------- G1 v3: zxbcdt = seq @ wproj^T via MFMA f16 --------------------
__global__ __launch_bounds__(256) void k_gemm1_v3(const _Float16* __restrict__ seqh,
                                                  const _Float16* __restrict__ wprojh,
                                                  const float* __restrict__ P,
                                                  float* __restrict__ z,
                                                  float* __restrict__ xbc,
                                                  float* __restrict__ dtb) {
  __shared__ __align__(16) _Float16 lA[128 * 64];
  __shared__ __align__(16) _Float16 lB[128 * 64];
  int m0 = blockIdx.x * 128;
  int e0 = blockIdx.y * 128;
  int tid = threadIdx.x;
  int lane = tid & 63;
  int wv = tid >> 6;
  f32x4 acc[2][8];
#pragma unroll
  for (int rf = 0; rf < 2; ++rf)
#pragma unroll
    for (int cf = 0; cf < 8; ++cf) acc[rf][cf] = (f32x4){0.f, 0.f, 0.f, 0.f};

  int rsel = lane & 15, q = lane >> 4;
  for (int k0 = 0; k0 < 128; k0 += 64) {
    if (k0) __syncthreads();
#pragma unroll
    for (int p = 0; p < 4; ++p) {
      int idx = tid + 256 * p;
      int row = idx >> 3, ch = idx & 7;
      int dch = ch ^ (row & 7);
      *(half8*)&lA[row * 64 + dch * 8] =
          *(const half8*)&seqh[(size_t)(m0 + row) * 128 + k0 + ch * 8];
      *(half8*)&lB[row * 64 + dch * 8] =
          *(const half8*)&wprojh[(size_t)(e0 + row) * 128 + k0 + ch * 8];
    }
    __syncthreads();
#pragma unroll
    for (int kk = 0; kk < 2; ++kk) {
      half8 a[2];
#pragma unroll
      for (int rf = 0; rf < 2; ++rf) {
        int row = wv * 32 + rf * 16 + rsel;
        int ch = (kk * 4 + q) ^ (row & 7);
        a[rf] = *(const half8*)&lA[row * 64 + ch * 8];
      }
#pragma unroll
      for (int cf = 0; cf < 8; ++cf) {
        int row = cf * 16 + rsel;
        int ch = (kk * 4 + q) ^ (row & 7);
        half8 b = *(const half8*)&lB[row * 64 + ch * 8];
        acc[0][cf] = __builtin_amdgcn_mfma_f32_16x16x32_f16(a[0], b, acc[0][cf], 0, 0, 0);
        acc[1][cf] = __builtin_amdgcn_mfma_f32_16x16x32_f16(a[1], b, acc[1][cf], 0, 0, 0);
      }
    }
  }

#pragma unroll
  for (int rf = 0; rf < 2; ++rf) {
    int mb = m0 + wv * 32 + rf * 16 + q * 4;
    if (e0 < 256) {
#pragma unroll
      for (int cf = 0; cf < 8; ++cf) {
        float* pz = z + (size_t)mb * 256 + e0 + cf * 16 + rsel;
#pragma unroll
        for (int r = 0; r < 4; ++r) pz[(size_t)r * 256] = acc[rf][cf][r];
      }
    } else if (e0 < 640) {
#pragma unroll
      for (int cf = 0; cf < 8; ++cf) {
        float* px = xbc + (size_t)mb * 384 + (e0 - 256) + cf * 16 + rsel;
#pragma unroll
        for (int r = 0; r < 4; ++r) px[(size_t)r * 384] = acc[rf][cf][r];
      }
    } else {
      if (rsel < 8) {
        float bias = P[P_DTB + rsel];
#pragma unroll
        for (int r = 0; r < 4; ++r) {
          float dv = acc[rf][0][r] + bias;
          float sp = (dv > 20.f) ? dv : log1pf(__expf(dv));
          dtb[(size_t)(mb + r) * 8 + rsel] = sp;
        }
      }
    }
  }
}

// ---------------- K5: causal conv1d + SiLU, IN-PLACE on xbc ---------------------
__global__ __launch_bounds__(256) void k_conv1d_v3(float* xbc,
                                                   const float* __restrict__ P) {
  float* buf = xbc + (size_t)blockIdx.x * 49152;   // 128*384
  for (int e = threadIdx.x; e < 384; e += 256) {
    float w0 = P[P_CW + e * 4 + 0], w1 = P[P_CW + e * 4 + 1];
    float w2 = P[P_CW + e * 4 + 2], w3 = P[P_CW + e * 4 + 3];
    float bb = P[P_CB + e];
    float x0 = 0.f, x1 = 0.f, x2 = 0.f;
    for (int l = 0; l < 128; ++l) {
      float x3 = buf[l * 384 + e];
      float a = bb + w0 * x0 + w1 * x1 + w2 * x2 + w3 * x3;
      buf[l * 384 + e] = a / (1.f + __expf(-a));
      x0 = x1; x1 = x2; x2 = x3;
    }
  }
}

// ---------------- K6 v4: selective scan, 4-way state split ----------------------
// Grid (CH, 2): block = 4 heads x 512 thr. wave = one head, 16 d-lanes x 4 sq.
// lane = (d_off<<2)|sq; thread owns states sq*16..sq*16+15 (h[16] in VGPRs).
// C-dot combined via 2x shfl_xor; sq==0 lanes store. 4x waves vs v3.
__global__ __launch_bounds__(512) void k_scan_v4(const float* __restrict__ pc,
                                                 const float* __restrict__ dtb,
                                                 const float* __restrict__ P,
                                                 float* __restrict__ ys) {
  int seq = blockIdx.x;
  int hb = blockIdx.y;
  int tid = threadIdx.x;
  int wv = tid >> 6;                 // 0..7
  int head = hb * 4 + (wv >> 1);
  int dbase = (wv & 1) * 16;
  int lane = tid & 63;
  int d = dbase + (lane >> 2);
  int sq = lane & 3;
  float A = -__expf(P[P_ALOG + head]);
  float Dk = P[P_DSKIP + head];
  float h[16];
#pragma unroll
  for (int s = 0; s < 16; ++s) h[s] = 0.f;
  const float* base = pc + (size_t)seq * 49152;
  const float* dtp = dtb + (size_t)seq * 1024;
  float* yp = ys + (size_t)seq * 32768;
  const int sO = sq * 16;
  for (int l = 0; l < 128; ++l) {
    const float* rb = base + l * 384;
    float dt = dtp[l * 8 + head];
    float xv = rb[head * 32 + d];
    float dA = __expf(dt * A);
    float coef = dt * xv;
    const float4* Bv = (const float4*)(rb + 256 + sO);
    const float4* Cv = (const float4*)(rb + 320 + sO);
    float a0 = 0.f, a1 = 0.f, a2 = 0.f, a3 = 0.f;
#pragma unroll
    for (int q = 0; q < 4; ++q) {
      float4 bq = Bv[q];
      float4 cq = Cv[q];
      h[q * 4 + 0] = h[q * 4 + 0] * dA + coef * bq.x;  a0 += h[q * 4 + 0] * cq.x;
      h[q * 4 + 1] = h[q * 4 + 1] * dA + coef * bq.y;  a1 += h[q * 4 + 1] * cq.y;
      h[q * 4 + 2] = h[q * 4 + 2] * dA + coef * bq.z;  a2 += h[q * 4 + 2] * cq.z;
      h[q * 4 + 3] = h[q * 4 + 3] * dA + coef * bq.w;  a3 += h[q * 4 + 3] * cq.w;
    }
    float acc = (a0 + a1) + (a2 + a3);
    acc += __shfl_xor(acc, 1, 64);
    acc += __shfl_xor(acc, 2, 64);
    if (sq == 0) yp[l * 256 + head * 32 + d] = acc + Dk * xv;
  }
}

// ---------------- K7: gate + RMS norm -> ynorm f16 ------------------------------
__global__ __launch_bounds__(256) void k_gate_v4(const float* __restrict__ ys,
                                                 const float* __restrict__ z,
                                                 const float* __restrict__ P,
                                                 _Float16* __restrict__ ynh) {
  int l = blockIdx.x;
  int e = threadIdx.x;
  __shared__ float red[4];
  float yv = ys[(size_t)l * 256 + e];
  float zv = z[(size_t)l * 256 + e];
  float g = zv / (1.f + __expf(-zv));
  float y = yv * g;
  float ss = y * y;
  for (int o = 32; o; o >>= 1) ss += __shfl_down(ss, o, 64);
  if ((threadIdx.x & 63) == 0) red[threadIdx.x >> 6] = ss;
  __syncthreads();
  float tot = red[0] + red[1] + red[2] + red[3];
  float r = rsqrtf(tot * (1.f / 256.f) + 1e-5f);
  ynh[(size_t)l * 256 + e] = (_Float16)(y * r * P[P_NG + e]);
}

// ---------------- G2 v3: out = ynorm @ outw^T via MFMA f16 ----------------------
__global__ __launch_bounds__(256) void k_gemm2_v3(const _Float16* __restrict__ ynh,
                                                  const _Float16* __restrict__ outwh,
                                                  float* __restrict__ dout,
                                                  int tok0) {
  __shared__ __align__(16) _Float16 lA[128 * 64];
  __shared__ __align__(16) _Float16 lB[64 * 64];
  int t0 = blockIdx.x * 64;
  int tid = threadIdx.x;
  int lane = tid & 63;
  int wv = tid >> 6;
  f32x4 acc[2][4];
#pragma unroll
  for (int rf = 0; rf < 2; ++rf)
#pragma unroll
    for (int cf = 0; cf < 4; ++cf) acc[rf][cf] = (f32x4){0.f, 0.f, 0.f, 0.f};

  int rsel = lane & 15, q = lane >> 4;
  for (int k0 = 0; k0 < 256; k0 += 64) {
    if (k0) __syncthreads();
#pragma unroll
    for (int p = 0; p < 4; ++p) {
      int idx = tid + 256 * p;
      int row = idx >> 3, ch = idx & 7;
      int dch = ch ^ (row & 7);
      *(half8*)&lA[row * 64 + dch * 8] =
          *(const half8*)&outwh[(size_t)row * 256 + k0 + ch * 8];
    }
#pragma unroll
    for (int p = 0; p < 2; ++p) {
      int idx = tid + 256 * p;
      int row = idx >> 3, ch = idx & 7;
      int dch = ch ^ (row & 7);
      *(half8*)&lB[row * 64 + dch * 8] =
          *(const half8*)&ynh[(size_t)(t0 + row) * 256 + k0 + ch * 8];
    }
    __syncthreads();
#pragma unroll
    for (int kk = 0; kk < 2; ++kk) {
      half8 a[2];
#pragma unroll
      for (int rf = 0; rf < 2; ++rf) {
        int row = wv * 32 + rf * 16 + rsel;
        int ch = (kk * 4 + q) ^ (row & 7);
        a[rf] = *(const half8*)&lA[row * 64 + ch * 8];
      }
#pragma unroll
      for (int cf = 0; cf < 4; ++cf) {
        int row = cf * 16 + rsel;
        int ch = (kk * 4 + q) ^ (row & 7);
        half8 b = *(const half8*)&lB[row * 64 + ch * 8];
        acc[0][cf] = __builtin_amdgcn_mfma_f32_16x16x32_f16(a[0], b, acc[0][cf], 0, 0, 0);
        acc[1][cf] = __builtin_amdgcn_mfma_f32_16x16x32_f16(a[1], b, acc[1][cf], 0, 0, 0);
      }
    }
  }

  int l0 = tok0 + t0;
  int b = l0 >> 14;
  int rem0 = l0 & 16383;
#pragma unroll
  for (int rf = 0; rf < 2; ++rf) {
    int cbase = wv * 32 + rf * 16 + q * 4;
#pragma unroll
    for (int cf = 0; cf < 4; ++cf) {
#pragma unroll
      for (int r = 0; r < 4; ++r) {
        dout[(size_t)(b * 128 + cbase + r) * 16384 + rem0 + cf * 16 + rsel] = acc[rf][cf][r];
      }
    }
  }
}

extern "C" void kernel_launch(void* const* d_in, const int* in_sizes, int n_in,
                              void* d_out, int out_size, void* d_ws, size_t ws_size,
                              hipStream_t stream) {
  const void* x      = d_in[0];
  const void* dww    = d_in[1];
  const void* gng    = d_in[2];
  const void* gnb    = d_in[3];
  const void* pww    = d_in[4];
  const void* pwb    = d_in[5];
  const void* wproj  = d_in[6];
  const void* cw     = d_in[7];
  const void* cb     = d_in[8];
  const void* dtbias = d_in[9];
  const void* alog   = d_in[10];
  const void* dskip  = d_in[11];
  const void* ng     = d_in[12];
  const void* outw   = d_in[13];
  float* out = (float*)d_out;

  char* ws = (char*)d_ws;
  float* gst        = (float*)(ws + 0);
  float* mr         = (float*)(ws + 4096);
  float* P          = (float*)(ws + 8192);
  _Float16* wprojh  = (_Float16*)(ws + 40960);
  _Float16* outwh   = (_Float16*)(ws + 372736);
  float* offf       = (float*)(ws + 503808);
  char* cbase       = ws + 1028096;

  // h1 (f32, 67,108,864 B) lives in d_out's out_2d region.
  float* h1f = out;

  // Per-sequence chunk bytes:
  //   seq f16 32768 + z 131072 + xbc 196608 + dtb 4096 + ys 131072 = 495616.
  //   (ynorm f16 reuses xbc region: dead after scan.)
  const int opts[11] = {1024, 512, 256, 128, 64, 32, 16, 8, 4, 2, 1};
  int CH = 1;
  for (int i = 0; i < 11; ++i) {
    if (1028096ull + (unsigned long long)opts[i] * 495616ull <= (unsigned long long)ws_size) {
      CH = opts[i];
      break;
    }
  }
  int NC = 1024 / CH;

  _Float16* seqh = (_Float16*)(cbase);
  float* zf      = (float*)(cbase + (size_t)CH * 32768);
  float* xbcf    = (float*)(cbase + (size_t)CH * 163840);
  float* dtbf    = (float*)(cbase + (size_t)CH * 360448);
  float* ysf     = (float*)(cbase + (size_t)CH * 364544);
  _Float16* ynh  = (_Float16*)xbcf;

  k_prep_params<<<1, 256, 0, stream>>>(dww, cw, cb, gng, gnb, pww, pwb, dtbias,
                                       alog, dskip, ng, P, gst);
  k_prep_w<<<128, 256, 0, stream>>>(wproj, outw, gng, wprojh, outwh);
  k_dwconv_v2<<<4096, 256, 0, stream>>>(x, gng, P, h1f, gst);
  k_stats<<<1, 64, 0, stream>>>(gst, mr);
  k_gn_off<<<1024, 128, 0, stream>>>(h1f, mr, P, offf, out);

  int M = CH * 128;
  for (int c = 0; c < NC; ++c) {
    int s0 = c * CH;
    k_deform<<<CH, 128, 0, stream>>>(x, gng, offf, seqh, s0);
    k_gemm1_v3<<<dim3(M / 128, 6), 256, 0, stream>>>(seqh, wprojh, P, zf, xbcf, dtbf);
    k_conv1d_v3<<<CH, 256, 0, stream>>>(xbcf, P);
    k_scan_v4<<<dim3(CH, 2), 512, 0, stream>>>(xbcf, dtbf, P, ysf);
    k_gate_v4<<<CH * 128, 256, 0, stream>>>(ysf, zf, P, ynh);
    k_gemm2_v3<<<dim3(M / 64), 256, 0, stream>>>(ynh, outwh, out, s0 * 128);
  }
}

// Round 5
// 1268.408 us; speedup vs baseline: 1.3038x; 1.3038x over previous
//
#include <hip/hip_runtime.h>
#include <math.h>

// B=8, C=128, H=128, W=128, D_INNER=256, D_STATE=64, HEADDIM=32, NHEADS=8,
// D_CONV=4, GN_GROUPS=8, D_XBC=384, D_INPROJ=648.
// Inputs f32 (probed via gn_g word0). OUTPUT IS F32 (reference output dtype).
// d_out = [out_2d: 16,777,216 f32][offset: 131,072 f32].
// h1 (f32) is staged in d_out's out_2d region.
//
// R1: scan de-spilled -> 3236us. R2: register-blocked VALU GEMMs -> 2123us.
// R3: MFMA f16 GEMMs -> 1078us. R4: dwconv v2 good (kept); scan v4 (4-way
// lane-split + shfl_xor) REGRESSED: VGPR=32 killed load pipelining, 2 DS ops
// in the per-step chain, VALUBusy 20% -> 496us. R5: scan v5 = v3 dataflow
// (h in regs, wave-uniform B/C broadcast loads, zero cross-lane) but states
// split 2-way ACROSS BLOCKS (partial sums to ysA/ysB, gate adds them):
// h[32]/thread, 2x resident waves, no shuffles.

typedef _Float16 half8 __attribute__((ext_vector_type(8)));
typedef float f32x4 __attribute__((ext_vector_type(4)));

__device__ __forceinline__ float b2f(unsigned short u) {
  return __uint_as_float(((unsigned int)u) << 16);
}
__device__ __forceinline__ bool in_is_f32(const void* gng) {
  return ((const unsigned int*)gng)[0] == 0x3F800000u;
}

#define P_DWW 0
#define P_CW 3200
#define P_CB 4736
#define P_GNG 5120
#define P_GNB 5248
#define P_PWW 5376
#define P_PWB 5504
#define P_DTB 5505
#define P_ALOG 5513
#define P_DSKIP 5521
#define P_NG 5529

__global__ void k_prep_params(const void* dww, const void* cw, const void* cb,
                              const void* gng, const void* gnb, const void* pww,
                              const void* pwb, const void* dtbias, const void* alog,
                              const void* dskip, const void* ng, float* __restrict__ P,
                              float* __restrict__ gst) {
  bool f = in_is_f32(gng);
  int tid = threadIdx.x;
  if (tid < 128) gst[tid] = 0.f;
  auto cvt = [&](const void* src, int n, int off) {
    for (int i = tid; i < n; i += 256)
      P[off + i] = f ? ((const float*)src)[i] : b2f(((const unsigned short*)src)[i]);
  };
  cvt(dww, 3200, P_DWW);
  cvt(cw, 1536, P_CW);
  cvt(cb, 384, P_CB);
  cvt(gng, 128, P_GNG);
  cvt(gnb, 128, P_GNB);
  cvt(pww, 128, P_PWW);
  cvt(pwb, 1, P_PWB);
  cvt(dtbias, 8, P_DTB);
  cvt(alog, 8, P_ALOG);
  cvt(dskip, 8, P_DSKIP);
  cvt(ng, 256, P_NG);
}

// wprojh: 768 x 128 f16 (rows >=648 zero).  outwh: 128 x 256 f16.
__global__ void k_prep_w(const void* wproj, const void* outw, const void* gng,
                         _Float16* __restrict__ wprojh, _Float16* __restrict__ outwh) {
  bool f = in_is_f32(gng);
  int stride = gridDim.x * blockDim.x;
  for (int i = blockIdx.x * blockDim.x + threadIdx.x; i < 98304; i += stride) {
    int row = i >> 7;
    float v = 0.f;
    if (row < 648) v = f ? ((const float*)wproj)[i] : b2f(((const unsigned short*)wproj)[i]);
    wprojh[i] = (_Float16)v;
  }
  for (int i = blockIdx.x * blockDim.x + threadIdx.x; i < 32768; i += stride)
    outwh[i] = (_Float16)(f ? ((const float*)outw)[i] : b2f(((const unsigned short*)outw)[i]));
}

// ---------------- K1 v2: depthwise 5x5 conv + group stats -----------------------
// 4 blocks per (b,c): 64x64 output tile, 68x68 f32 halo in LDS (stride 72).
// Thread: 4x4 outputs; per input row two aligned b128 reads -> 8 in-regs -> 20 FMA.
__global__ __launch_bounds__(256) void k_dwconv_v2(const void* __restrict__ x,
                                                   const void* __restrict__ gng,
                                                   const float* __restrict__ P,
                                                   float* __restrict__ h1,
                                                   float* __restrict__ gst) {
  int blk = blockIdx.x;
  int bc = blk >> 2, sub = blk & 3;
  int b = bc >> 7, c = bc & 127;
  int ty0 = (sub >> 1) * 64, tx0 = (sub & 1) * 64;
  bool f32x = in_is_f32(gng);
  __shared__ __align__(16) float t[68 * 72];
  __shared__ float red[8];
  const float* xf = (const float*)x + (size_t)bc * 16384;
  const unsigned short* xb = (const unsigned short*)x + (size_t)bc * 16384;
  for (int i = threadIdx.x; i < 68 * 68; i += 256) {
    int r = i / 68, cc = i - r * 68;
    int gy = ty0 + r - 2, gx = tx0 + cc - 2;
    float v = 0.f;
    if (gy >= 0 && gy < 128 && gx >= 0 && gx < 128) {
      int off = gy * 128 + gx;
      v = f32x ? xf[off] : b2f(xb[off]);
    }
    t[r * 72 + cc] = v;
  }
  float w[25];
#pragma unroll
  for (int k = 0; k < 25; ++k) w[k] = P[P_DWW + c * 25 + k];
  __syncthreads();

  int ox = (threadIdx.x & 15) * 4;
  int oy = (threadIdx.x >> 4) * 4;
  float acc[4][4];
#pragma unroll
  for (int r = 0; r < 4; ++r)
#pragma unroll
    for (int j = 0; j < 4; ++j) acc[r][j] = 0.f;

#pragma unroll
  for (int i = 0; i < 8; ++i) {
    float4 p0 = *(const float4*)&t[(oy + i) * 72 + ox];
    float4 p1 = *(const float4*)&t[(oy + i) * 72 + ox + 4];
    float in8[8] = {p0.x, p0.y, p0.z, p0.w, p1.x, p1.y, p1.z, p1.w};
#pragma unroll
    for (int r = 0; r < 4; ++r) {
      if (i - r >= 0 && i - r <= 4) {
        int ky = i - r;
#pragma unroll
        for (int j = 0; j < 4; ++j)
#pragma unroll
          for (int kx = 0; kx < 5; ++kx)
            acc[r][j] += w[ky * 5 + kx] * in8[j + kx];
      }
    }
  }

  float s = 0.f, sq = 0.f;
  float* hp = h1 + (size_t)bc * 16384;
#pragma unroll
  for (int r = 0; r < 4; ++r) {
    *(float4*)&hp[(ty0 + oy + r) * 128 + tx0 + ox] =
        make_float4(acc[r][0], acc[r][1], acc[r][2], acc[r][3]);
#pragma unroll
    for (int j = 0; j < 4; ++j) { s += acc[r][j]; sq += acc[r][j] * acc[r][j]; }
  }
  for (int o = 32; o; o >>= 1) { s += __shfl_down(s, o, 64); sq += __shfl_down(sq, o, 64); }
  int wv = threadIdx.x >> 6;
  if ((threadIdx.x & 63) == 0) { red[wv] = s; red[4 + wv] = sq; }
  __syncthreads();
  if (threadIdx.x == 0) {
    float ts = red[0] + red[1] + red[2] + red[3];
    float tq = red[4] + red[5] + red[6] + red[7];
    int g = (b << 3) + (c >> 4);
    atomicAdd(&gst[g * 2], ts);
    atomicAdd(&gst[g * 2 + 1], tq);
  }
}

__global__ void k_stats(const float* __restrict__ gst, float* __restrict__ mr) {
  int g = threadIdx.x;
  if (g < 64) {
    const float invN = 1.f / 262144.f;
    float mean = gst[g * 2] * invN;
    float var = gst[g * 2 + 1] * invN - mean * mean;
    mr[g * 2] = mean;
    mr[g * 2 + 1] = rsqrtf(var + 1e-5f);
  }
}

// ---------------- K3: GN + exact GELU + 1x1 conv + tanh*8 -> offset (f32 out) ----
__global__ __launch_bounds__(128) void k_gn_off(const float* __restrict__ h1,
                                                const float* __restrict__ mr,
                                                const float* __restrict__ P,
                                                float* __restrict__ offf,
                                                float* __restrict__ dout) {
  int bh = blockIdx.x;
  int b = bh >> 7, h = bh & 127;
  int w = threadIdx.x;
  float acc = 0.f;
  for (int c = 0; c < 128; ++c) {
    float v = h1[(((size_t)(b * 128 + c)) * 128 + h) * 128 + w];
    int g = b * 8 + (c >> 4);
    float nv = (v - mr[g * 2]) * mr[g * 2 + 1] * P[P_GNG + c] + P[P_GNB + c];
    float ge = 0.5f * nv * (1.f + erff(nv * 0.70710678118f));
    acc += ge * P[P_PWW + c];
  }
  float off = acc + P[P_PWB];
  float ofv = tanhf(off) * 8.0f;
  offf[bh * 128 + w] = ofv;
  dout[16777216 + bh * 128 + w] = ofv;
}

// ---------------- K4: y-only grid sample + transpose -> seq f16 (l,c) ------------
__global__ __launch_bounds__(128) void k_deform(const void* __restrict__ x,
                                                const void* __restrict__ gng,
                                                const float* __restrict__ offf,
                                                _Float16* __restrict__ seqc,
                                                int s0) {
  int bh = s0 + blockIdx.x;
  int b = bh >> 7, h = bh & 127;
  int w = threadIdx.x;
  bool f32x = in_is_f32(gng);
  __shared__ float t[128 * 130];
  float ofv = offf[bh * 128 + w];
  float gy = -1.f + (2.f / 127.f) * (float)h + ofv * (2.f / 127.f);
  gy = fminf(fmaxf(gy, -1.f), 1.f);
  float py = (gy + 1.f) * 0.5f * 127.f;
  py = fminf(fmaxf(py, 0.f), 127.f);
  float y0f = floorf(py);
  float wy = py - y0f;
  int y0 = (int)y0f;
  int y1 = min(y0 + 1, 127);
  const float* xfb = (const float*)x + (size_t)b * 128 * 16384;
  const unsigned short* xbb = (const unsigned short*)x + (size_t)b * 128 * 16384;
  for (int c = 0; c < 128; ++c) {
    size_t o0 = (size_t)c * 16384 + y0 * 128 + w;
    size_t o1 = (size_t)c * 16384 + y1 * 128 + w;
    float v0, v1;
    if (f32x) { v0 = xfb[o0]; v1 = xfb[o1]; }
    else      { v0 = b2f(xbb[o0]); v1 = b2f(xbb[o1]); }
    t[c * 130 + w] = v0 + wy * (v1 - v0);
  }
  __syncthreads();
  int c = threadIdx.x;
  _Float16* sp = seqc + (size_t)blockIdx.x * 16384;
  for (int l = 0; l < 128; ++l) sp[l * 128 + c] = (_Float16)t[c * 130 + l];
}

// ---------------- G1 v3: zxbcdt = seq @ wproj^T via MFMA f16 --------------------
__global__ __launch_bounds__(256) void k_gemm1_v3(const _Float16* __restrict__ seqh,
                                                  const _Float16* __restrict__ wprojh,
                                                  const float* __restrict__ P,
                                                  float* __restrict__ z,
                                                  float* __restrict__ xbc,
                                                  float* __restrict__ dtb) {
  __shared__ __align__(16) _Float16 lA[128 * 64];
  __shared__ __align__(16) _Float16 lB[128 * 64];
  int m0 = blockIdx.x * 128;
  int e0 = blockIdx.y * 128;
  int tid = threadIdx.x;
  int lane = tid & 63;
  int wv = tid >> 6;
  f32x4 acc[2][8];
#pragma unroll
  for (int rf = 0; rf < 2; ++rf)
#pragma unroll
    for (int cf = 0; cf < 8; ++cf) acc[rf][cf] = (f32x4){0.f, 0.f, 0.f, 0.f};

  int rsel = lane & 15, q = lane >> 4;
  for (int k0 = 0; k0 < 128; k0 += 64) {
    if (k0) __syncthreads();
#pragma unroll
    for (int p = 0; p < 4; ++p) {
      int idx = tid + 256 * p;
      int row = idx >> 3, ch = idx & 7;
      int dch = ch ^ (row & 7);
      *(half8*)&lA[row * 64 + dch * 8] =
          *(const half8*)&seqh[(size_t)(m0 + row) * 128 + k0 + ch * 8];
      *(half8*)&lB[row * 64 + dch * 8] =
          *(const half8*)&wprojh[(size_t)(e0 + row) * 128 + k0 + ch * 8];
    }
    __syncthreads();
#pragma unroll
    for (int kk = 0; kk < 2; ++kk) {
      half8 a[2];
#pragma unroll
      for (int rf = 0; rf < 2; ++rf) {
        int row = wv * 32 + rf * 16 + rsel;
        int ch = (kk * 4 + q) ^ (row & 7);
        a[rf] = *(const half8*)&lA[row * 64 + ch * 8];
      }
#pragma unroll
      for (int cf = 0; cf < 8; ++cf) {
        int row = cf * 16 + rsel;
        int ch = (kk * 4 + q) ^ (row & 7);
        half8 b = *(const half8*)&lB[row * 64 + ch * 8];
        acc[0][cf] = __builtin_amdgcn_mfma_f32_16x16x32_f16(a[0], b, acc[0][cf], 0, 0, 0);
        acc[1][cf] = __builtin_amdgcn_mfma_f32_16x16x32_f16(a[1], b, acc[1][cf], 0, 0, 0);
      }
    }
  }

#pragma unroll
  for (int rf = 0; rf < 2; ++rf) {
    int mb = m0 + wv * 32 + rf * 16 + q * 4;
    if (e0 < 256) {
#pragma unroll
      for (int cf = 0; cf < 8; ++cf) {
        float* pz = z + (size_t)mb * 256 + e0 + cf * 16 + rsel;
#pragma unroll
        for (int r = 0; r < 4; ++r) pz[(size_t)r * 256] = acc[rf][cf][r];
      }
    } else if (e0 < 640) {
#pragma unroll
      for (int cf = 0; cf < 8; ++cf) {
        float* px = xbc + (size_t)mb * 384 + (e0 - 256) + cf * 16 + rsel;
#pragma unroll
        for (int r = 0; r < 4; ++r) px[(size_t)r * 384] = acc[rf][cf][r];
      }
    } else {
      if (rsel < 8) {
        float bias = P[P_DTB + rsel];
#pragma unroll
        for (int r = 0; r < 4; ++r) {
          float dv = acc[rf][0][r] + bias;
          float sp = (dv > 20.f) ? dv : log1pf(__expf(dv));
          dtb[(size_t)(mb + r) * 8 + rsel] = sp;
        }
      }
    }
  }
}

// ---------------- K5: causal conv1d + SiLU, IN-PLACE on xbc ---------------------
__global__ __launch_bounds__(256) void k_conv1d_v3(float* xbc,
                                                   const float* __restrict__ P) {
  float* buf = xbc + (size_t)blockIdx.x * 49152;   // 128*384
  for (int e = threadIdx.x; e < 384; e += 256) {
    float w0 = P[P_CW + e * 4 + 0], w1 = P[P_CW + e * 4 + 1];
    float w2 = P[P_CW + e * 4 + 2], w3 = P[P_CW + e * 4 + 3];
    float bb = P[P_CB + e];
    float x0 = 0.f, x1 = 0.f, x2 = 0.f;
    for (int l = 0; l < 128; ++l) {
      float x3 = buf[l * 384 + e];
      float a = bb + w0 * x0 + w1 * x1 + w2 * x2 + w3 * x3;
      buf[l * 384 + e] = a / (1.f + __expf(-a));
      x0 = x1; x1 = x2; x2 = x3;
    }
  }
}

// ---------------- K6 v5: selective scan, 2-way state split ACROSS BLOCKS --------
// Grid (CH, 2). Block = 1 seq, state half sblk*32..+31. Thread = (head,d) as v3:
// h[32] in VGPRs, wave-uniform B/C float4 broadcast loads, no cross-lane ops.
// Partial C-dots -> ysA / ysB (gate adds). sblk0 adds the Dk*x skip term.
__global__ __launch_bounds__(256) void k_scan_v5(const float* __restrict__ pc,
                                                 const float* __restrict__ dtb,
                                                 const float* __restrict__ P,
                                                 float* __restrict__ ysA,
                                                 float* __restrict__ ysB) {
  int seq = blockIdx.x;
  int sblk = blockIdx.y;          // 0: states 0..31, 1: states 32..63
  int head = threadIdx.x >> 5;    // 0..7
  int d = threadIdx.x & 31;       // 0..31
  float A = -__expf(P[P_ALOG + head]);
  float Dk = P[P_DSKIP + head];
  float h[32];
#pragma unroll
  for (int s = 0; s < 32; ++s) h[s] = 0.f;
  const float* base = pc + (size_t)seq * 49152;
  const float* dtp = dtb + (size_t)seq * 1024;
  float* yp = (sblk ? ysB : ysA) + (size_t)seq * 32768;
  const int sO = sblk * 32;
  for (int l = 0; l < 128; ++l) {
    const float* rb = base + l * 384;
    float dt = dtp[l * 8 + head];
    float xv = rb[head * 32 + d];
    float dA = __expf(dt * A);
    float coef = dt * xv;
    const float4* Bv = (const float4*)(rb + 256 + sO);  // wave-uniform
    const float4* Cv = (const float4*)(rb + 320 + sO);
    float a0 = 0.f, a1 = 0.f, a2 = 0.f, a3 = 0.f;
#pragma unroll
    for (int q = 0; q < 8; ++q) {
      float4 bq = Bv[q];
      float4 cq = Cv[q];
      h[q * 4 + 0] = h[q * 4 + 0] * dA + coef * bq.x;  a0 += h[q * 4 + 0] * cq.x;
      h[q * 4 + 1] = h[q * 4 + 1] * dA + coef * bq.y;  a1 += h[q * 4 + 1] * cq.y;
      h[q * 4 + 2] = h[q * 4 + 2] * dA + coef * bq.z;  a2 += h[q * 4 + 2] * cq.z;
      h[q * 4 + 3] = h[q * 4 + 3] * dA + coef * bq.w;  a3 += h[q * 4 + 3] * cq.w;
    }
    float res = (a0 + a1) + (a2 + a3);
    if (sblk == 0) res += Dk * xv;
    yp[l * 256 + head * 32 + d] = res;
  }
}

// ---------------- K7: gate + RMS norm -> ynorm f16 (sums ysA+ysB) ----------------
__global__ __launch_bounds__(256) void k_gate_v5(const float* __restrict__ ysA,
                                                 const float* __restrict__ ysB,
                                                 const float* __restrict__ z,
                                                 const float* __restrict__ P,
                                                 _Float16* __restrict__ ynh) {
  int l = blockIdx.x;
  int e = threadIdx.x;
  __shared__ float red[4];
  size_t idx = (size_t)l * 256 + e;
  float yv = ysA[idx] + ysB[idx];
  float zv = z[idx];
  float g = zv / (1.f + __expf(-zv));
  float y = yv * g;
  float ss = y * y;
  for (int o = 32; o; o >>= 1) ss += __shfl_down(ss, o, 64);
  if ((threadIdx.x & 63) == 0) red[threadIdx.x >> 6] = ss;
  __syncthreads();
  float tot = red[0] + red[1] + red[2] + red[3];
  float r = rsqrtf(tot * (1.f / 256.f) + 1e-5f);
  ynh[idx] = (_Float16)(y * r * P[P_NG + e]);
}

// ---------------- G2 v3: out = ynorm @ outw^T via MFMA f16 ----------------------
__global__ __launch_bounds__(256) void k_gemm2_v3(const _Float16* __restrict__ ynh,
                                                  const _Float16* __restrict__ outwh,
                                                  float* __restrict__ dout,
                                                  int tok0) {
  __shared__ __align__(16) _Float16 lA[128 * 64];
  __shared__ __align__(16) _Float16 lB[64 * 64];
  int t0 = blockIdx.x * 64;
  int tid = threadIdx.x;
  int lane = tid & 63;
  int wv = tid >> 6;
  f32x4 acc[2][4];
#pragma unroll
  for (int rf = 0; rf < 2; ++rf)
#pragma unroll
    for (int cf = 0; cf < 4; ++cf) acc[rf][cf] = (f32x4){0.f, 0.f, 0.f, 0.f};

  int rsel = lane & 15, q = lane >> 4;
  for (int k0 = 0; k0 < 256; k0 += 64) {
    if (k0) __syncthreads();
#pragma unroll
    for (int p = 0; p < 4; ++p) {
      int idx = tid + 256 * p;
      int row = idx >> 3, ch = idx & 7;
      int dch = ch ^ (row & 7);
      *(half8*)&lA[row * 64 + dch * 8] =
          *(const half8*)&outwh[(size_t)row * 256 + k0 + ch * 8];
    }
#pragma unroll
    for (int p = 0; p < 2; ++p) {
      int idx = tid + 256 * p;
      int row = idx >> 3, ch = idx & 7;
      int dch = ch ^ (row & 7);
      *(half8*)&lB[row * 64 + dch * 8] =
          *(const half8*)&ynh[(size_t)(t0 + row) * 256 + k0 + ch * 8];
    }
    __syncthreads();
#pragma unroll
    for (int kk = 0; kk < 2; ++kk) {
      half8 a[2];
#pragma unroll
      for (int rf = 0; rf < 2; ++rf) {
        int row = wv * 32 + rf * 16 + rsel;
        int ch = (kk * 4 + q) ^ (row & 7);
        a[rf] = *(const half8*)&lA[row * 64 + ch * 8];
      }
#pragma unroll
      for (int cf = 0; cf < 4; ++cf) {
        int row = cf * 16 + rsel;
        int ch = (kk * 4 + q) ^ (row & 7);
        half8 b = *(const half8*)&lB[row * 64 + ch * 8];
        acc[0][cf] = __builtin_amdgcn_mfma_f32_16x16x32_f16(a[0], b, acc[0][cf], 0, 0, 0);
        acc[1][cf] = __builtin_amdgcn_mfma_f32_16x16x32_f16(a[1], b, acc[1][cf], 0, 0, 0);
      }
    }
  }

  int l0 = tok0 + t0;
  int b = l0 >> 14;
  int rem0 = l0 & 16383;
#pragma unroll
  for (int rf = 0; rf < 2; ++rf) {
    int cbase = wv * 32 + rf * 16 + q * 4;
#pragma unroll
    for (int cf = 0; cf < 4; ++cf) {
#pragma unroll
      for (int r = 0; r < 4; ++r) {
        dout[(size_t)(b * 128 + cbase + r) * 16384 + rem0 + cf * 16 + rsel] = acc[rf][cf][r];
      }
    }
  }
}

extern "C" void kernel_launch(void* const* d_in, const int* in_sizes, int n_in,
                              void* d_out, int out_size, void* d_ws, size_t ws_size,
                              hipStream_t stream) {
  const void* x      = d_in[0];
  const void* dww    = d_in[1];
  const void* gng    = d_in[2];
  const void* gnb    = d_in[3];
  const void* pww    = d_in[4];
  const void* pwb    = d_in[5];
  const void* wproj  = d_in[6];
  const void* cw     = d_in[7];
  const void* cb     = d_in[8];
  const void* dtbias = d_in[9];
  const void* alog   = d_in[10];
  const void* dskip  = d_in[11];
  const void* ng     = d_in[12];
  const void* outw   = d_in[13];
  float* out = (float*)d_out;

  char* ws = (char*)d_ws;
  float* gst        = (float*)(ws + 0);
  float* mr         = (float*)(ws + 4096);
  float* P          = (float*)(ws + 8192);
  _Float16* wprojh  = (_Float16*)(ws + 40960);
  _Float16* outwh   = (_Float16*)(ws + 372736);
  float* offf       = (float*)(ws + 503808);
  char* cbase       = ws + 1028096;

  // h1 (f32, 67,108,864 B) lives in d_out's out_2d region.
  float* h1f = out;

  // Per-sequence chunk bytes:
  //   seq f16 32768 + z 131072 + xbc 196608 + dtb 4096 + ysA 131072
  //   + ysB 131072 = 626688.  (ynorm f16 reuses xbc region.)
  const int opts[11] = {1024, 512, 256, 128, 64, 32, 16, 8, 4, 2, 1};
  int CH = 1;
  for (int i = 0; i < 11; ++i) {
    if (1028096ull + (unsigned long long)opts[i] * 626688ull <= (unsigned long long)ws_size) {
      CH = opts[i];
      break;
    }
  }
  int NC = 1024 / CH;

  _Float16* seqh = (_Float16*)(cbase);
  float* zf      = (float*)(cbase + (size_t)CH * 32768);
  float* xbcf    = (float*)(cbase + (size_t)CH * 163840);
  float* dtbf    = (float*)(cbase + (size_t)CH * 360448);
  float* ysA     = (float*)(cbase + (size_t)CH * 364544);
  float* ysB     = (float*)(cbase + (size_t)CH * 495616);
  _Float16* ynh  = (_Float16*)xbcf;

  k_prep_params<<<1, 256, 0, stream>>>(dww, cw, cb, gng, gnb, pww, pwb, dtbias,
                                       alog, dskip, ng, P, gst);
  k_prep_w<<<128, 256, 0, stream>>>(wproj, outw, gng, wprojh, outwh);
  k_dwconv_v2<<<4096, 256, 0, stream>>>(x, gng, P, h1f, gst);
  k_stats<<<1, 64, 0, stream>>>(gst, mr);
  k_gn_off<<<1024, 128, 0, stream>>>(h1f, mr, P, offf, out);

  int M = CH * 128;
  for (int c = 0; c < NC; ++c) {
    int s0 = c * CH;
    k_deform<<<CH, 128, 0, stream>>>(x, gng, offf, seqh, s0);
    k_gemm1_v3<<<dim3(M / 128, 6), 256, 0, stream>>>(seqh, wprojh, P, zf, xbcf, dtbf);
    k_conv1d_v3<<<CH, 256, 0, stream>>>(xbcf, P);
    k_scan_v5<<<dim3(CH, 2), 256, 0, stream>>>(xbcf, dtbf, P, ysA, ysB);
    k_gate_v5<<<CH * 128, 256, 0, stream>>>(ysA, ysB, zf, P, ynh);
    k_gemm2_v3<<<dim3(M / 64), 256, 0, stream>>>(ynh, outwh, out, s0 * 128);
  }
}

// Round 6
// 1074.310 us; speedup vs baseline: 1.5394x; 1.1807x over previous
//
#include <hip/hip_runtime.h>
#include <math.h>

// B=8, C=128, H=128, W=128, D_INNER=256, D_STATE=64, HEADDIM=32, NHEADS=8,
// D_CONV=4, GN_GROUPS=8, D_XBC=384, D_INPROJ=648.
// Inputs f32 (probed via gn_g word0). OUTPUT IS F32 (reference output dtype).
// d_out = [out_2d: 16,777,216 f32][offset: 131,072 f32].
// h1 (f32) is staged in d_out's out_2d region.
//
// R1: scan de-spilled -> 3236us. R2: register-blocked VALU GEMMs -> 2123us.
// R3: MFMA f16 GEMMs -> 1078us. R4: dwconv v2 kept; scan v4 regressed (shuffle
// chain + VGPR starvation). R5: scan v5 2-way block state split -> 1268us, but
// still latency-bound: B/C scalarized to SGPRs (SGPR=80, VGPR=32), no room to
// pipeline -> ~2000cyc/step. R6: scan v6 = v5 + 16-step LDS tiling of B/C+dt
// (double-buffered, coop float4 staging, issue-early/write-late, 1 barrier per
// tile); x preloaded to 16 VGPRs per tile. Per-step -> 16 broadcast
// ds_read_b128 + 64 FMA.

typedef _Float16 half8 __attribute__((ext_vector_type(8)));
typedef float f32x4 __attribute__((ext_vector_type(4)));

__device__ __forceinline__ float b2f(unsigned short u) {
  return __uint_as_float(((unsigned int)u) << 16);
}
__device__ __forceinline__ bool in_is_f32(const void* gng) {
  return ((const unsigned int*)gng)[0] == 0x3F800000u;
}

#define P_DWW 0
#define P_CW 3200
#define P_CB 4736
#define P_GNG 5120
#define P_GNB 5248
#define P_PWW 5376
#define P_PWB 5504
#define P_DTB 5505
#define P_ALOG 5513
#define P_DSKIP 5521
#define P_NG 5529

__global__ void k_prep_params(const void* dww, const void* cw, const void* cb,
                              const void* gng, const void* gnb, const void* pww,
                              const void* pwb, const void* dtbias, const void* alog,
                              const void* dskip, const void* ng, float* __restrict__ P,
                              float* __restrict__ gst) {
  bool f = in_is_f32(gng);
  int tid = threadIdx.x;
  if (tid < 128) gst[tid] = 0.f;
  auto cvt = [&](const void* src, int n, int off) {
    for (int i = tid; i < n; i += 256)
      P[off + i] = f ? ((const float*)src)[i] : b2f(((const unsigned short*)src)[i]);
  };
  cvt(dww, 3200, P_DWW);
  cvt(cw, 1536, P_CW);
  cvt(cb, 384, P_CB);
  cvt(gng, 128, P_GNG);
  cvt(gnb, 128, P_GNB);
  cvt(pww, 128, P_PWW);
  cvt(pwb, 1, P_PWB);
  cvt(dtbias, 8, P_DTB);
  cvt(alog, 8, P_ALOG);
  cvt(dskip, 8, P_DSKIP);
  cvt(ng, 256, P_NG);
}

// wprojh: 768 x 128 f16 (rows >=648 zero).  outwh: 128 x 256 f16.
__global__ void k_prep_w(const void* wproj, const void* outw, const void* gng,
                         _Float16* __restrict__ wprojh, _Float16* __restrict__ outwh) {
  bool f = in_is_f32(gng);
  int stride = gridDim.x * blockDim.x;
  for (int i = blockIdx.x * blockDim.x + threadIdx.x; i < 98304; i += stride) {
    int row = i >> 7;
    float v = 0.f;
    if (row < 648) v = f ? ((const float*)wproj)[i] : b2f(((const unsigned short*)wproj)[i]);
    wprojh[i] = (_Float16)v;
  }
  for (int i = blockIdx.x * blockDim.x + threadIdx.x; i < 32768; i += stride)
    outwh[i] = (_Float16)(f ? ((const float*)outw)[i] : b2f(((const unsigned short*)outw)[i]));
}

// ---------------- K1 v2: depthwise 5x5 conv + group stats -----------------------
__global__ __launch_bounds__(256) void k_dwconv_v2(const void* __restrict__ x,
                                                   const void* __restrict__ gng,
                                                   const float* __restrict__ P,
                                                   float* __restrict__ h1,
                                                   float* __restrict__ gst) {
  int blk = blockIdx.x;
  int bc = blk >> 2, sub = blk & 3;
  int b = bc >> 7, c = bc & 127;
  int ty0 = (sub >> 1) * 64, tx0 = (sub & 1) * 64;
  bool f32x = in_is_f32(gng);
  __shared__ __align__(16) float t[68 * 72];
  __shared__ float red[8];
  const float* xf = (const float*)x + (size_t)bc * 16384;
  const unsigned short* xb = (const unsigned short*)x + (size_t)bc * 16384;
  for (int i = threadIdx.x; i < 68 * 68; i += 256) {
    int r = i / 68, cc = i - r * 68;
    int gy = ty0 + r - 2, gx = tx0 + cc - 2;
    float v = 0.f;
    if (gy >= 0 && gy < 128 && gx >= 0 && gx < 128) {
      int off = gy * 128 + gx;
      v = f32x ? xf[off] : b2f(xb[off]);
    }
    t[r * 72 + cc] = v;
  }
  float w[25];
#pragma unroll
  for (int k = 0; k < 25; ++k) w[k] = P[P_DWW + c * 25 + k];
  __syncthreads();

  int ox = (threadIdx.x & 15) * 4;
  int oy = (threadIdx.x >> 4) * 4;
  float acc[4][4];
#pragma unroll
  for (int r = 0; r < 4; ++r)
#pragma unroll
    for (int j = 0; j < 4; ++j) acc[r][j] = 0.f;

#pragma unroll
  for (int i = 0; i < 8; ++i) {
    float4 p0 = *(const float4*)&t[(oy + i) * 72 + ox];
    float4 p1 = *(const float4*)&t[(oy + i) * 72 + ox + 4];
    float in8[8] = {p0.x, p0.y, p0.z, p0.w, p1.x, p1.y, p1.z, p1.w};
#pragma unroll
    for (int r = 0; r < 4; ++r) {
      if (i - r >= 0 && i - r <= 4) {
        int ky = i - r;
#pragma unroll
        for (int j = 0; j < 4; ++j)
#pragma unroll
          for (int kx = 0; kx < 5; ++kx)
            acc[r][j] += w[ky * 5 + kx] * in8[j + kx];
      }
    }
  }

  float s = 0.f, sq = 0.f;
  float* hp = h1 + (size_t)bc * 16384;
#pragma unroll
  for (int r = 0; r < 4; ++r) {
    *(float4*)&hp[(ty0 + oy + r) * 128 + tx0 + ox] =
        make_float4(acc[r][0], acc[r][1], acc[r][2], acc[r][3]);
#pragma unroll
    for (int j = 0; j < 4; ++j) { s += acc[r][j]; sq += acc[r][j] * acc[r][j]; }
  }
  for (int o = 32; o; o >>= 1) { s += __shfl_down(s, o, 64); sq += __shfl_down(sq, o, 64); }
  int wv = threadIdx.x >> 6;
  if ((threadIdx.x & 63) == 0) { red[wv] = s; red[4 + wv] = sq; }
  __syncthreads();
  if (threadIdx.x == 0) {
    float ts = red[0] + red[1] + red[2] + red[3];
    float tq = red[4] + red[5] + red[6] + red[7];
    int g = (b << 3) + (c >> 4);
    atomicAdd(&gst[g * 2], ts);
    atomicAdd(&gst[g * 2 + 1], tq);
  }
}

__global__ void k_stats(const float* __restrict__ gst, float* __restrict__ mr) {
  int g = threadIdx.x;
  if (g < 64) {
    const float invN = 1.f / 262144.f;
    float mean = gst[g * 2] * invN;
    float var = gst[g * 2 + 1] * invN - mean * mean;
    mr[g * 2] = mean;
    mr[g * 2 + 1] = rsqrtf(var + 1e-5f);
  }
}

// ---------------- K3: GN + exact GELU + 1x1 conv + tanh*8 -> offset (f32 out) ----
__global__ __launch_bounds__(128) void k_gn_off(const float* __restrict__ h1,
                                                const float* __restrict__ mr,
                                                const float* __restrict__ P,
                                                float* __restrict__ offf,
                                                float* __restrict__ dout) {
  int bh = blockIdx.x;
  int b = bh >> 7, h = bh & 127;
  int w = threadIdx.x;
  float acc = 0.f;
  for (int c = 0; c < 128; ++c) {
    float v = h1[(((size_t)(b * 128 + c)) * 128 + h) * 128 + w];
    int g = b * 8 + (c >> 4);
    float nv = (v - mr[g * 2]) * mr[g * 2 + 1] * P[P_GNG + c] + P[P_GNB + c];
    float ge = 0.5f * nv * (1.f + erff(nv * 0.70710678118f));
    acc += ge * P[P_PWW + c];
  }
  float off = acc + P[P_PWB];
  float ofv = tanhf(off) * 8.0f;
  offf[bh * 128 + w] = ofv;
  dout[16777216 + bh * 128 + w] = ofv;
}

// ---------------- K4: y-only grid sample + transpose -> seq f16 (l,c) ------------
__global__ __launch_bounds__(128) void k_deform(const void* __restrict__ x,
                                                const void* __restrict__ gng,
                                                const float* __restrict__ offf,
                                                _Float16* __restrict__ seqc,
                                                int s0) {
  int bh = s0 + blockIdx.x;
  int b = bh >> 7, h = bh & 127;
  int w = threadIdx.x;
  bool f32x = in_is_f32(gng);
  __shared__ float t[128 * 130];
  float ofv = offf[bh * 128 + w];
  float gy = -1.f + (2.f / 127.f) * (float)h + ofv * (2.f / 127.f);
  gy = fminf(fmaxf(gy, -1.f), 1.f);
  float py = (gy + 1.f) * 0.5f * 127.f;
  py = fminf(fmaxf(py, 0.f), 127.f);
  float y0f = floorf(py);
  float wy = py - y0f;
  int y0 = (int)y0f;
  int y1 = min(y0 + 1, 127);
  const float* xfb = (const float*)x + (size_t)b * 128 * 16384;
  const unsigned short* xbb = (const unsigned short*)x + (size_t)b * 128 * 16384;
  for (int c = 0; c < 128; ++c) {
    size_t o0 = (size_t)c * 16384 + y0 * 128 + w;
    size_t o1 = (size_t)c * 16384 + y1 * 128 + w;
    float v0, v1;
    if (f32x) { v0 = xfb[o0]; v1 = xfb[o1]; }
    else      { v0 = b2f(xbb[o0]); v1 = b2f(xbb[o1]); }
    t[c * 130 + w] = v0 + wy * (v1 - v0);
  }
  __syncthreads();
  int c = threadIdx.x;
  _Float16* sp = seqc + (size_t)blockIdx.x * 16384;
  for (int l = 0; l < 128; ++l) sp[l * 128 + c] = (_Float16)t[c * 130 + l];
}

// ---------------- G1 v3: zxbcdt = seq @ wproj^T via MFMA f16 --------------------
__global__ __launch_bounds__(256) void k_gemm1_v3(const _Float16* __restrict__ seqh,
                                                  const _Float16* __restrict__ wprojh,
                                                  const float* __restrict__ P,
                                                  float* __restrict__ z,
                                                  float* __restrict__ xbc,
                                                  float* __restrict__ dtb) {
  __shared__ __align__(16) _Float16 lA[128 * 64];
  __shared__ __align__(16) _Float16 lB[128 * 64];
  int m0 = blockIdx.x * 128;
  int e0 = blockIdx.y * 128;
  int tid = threadIdx.x;
  int lane = tid & 63;
  int wv = tid >> 6;
  f32x4 acc[2][8];
#pragma unroll
  for (int rf = 0; rf < 2; ++rf)
#pragma unroll
    for (int cf = 0; cf < 8; ++cf) acc[rf][cf] = (f32x4){0.f, 0.f, 0.f, 0.f};

  int rsel = lane & 15, q = lane >> 4;
  for (int k0 = 0; k0 < 128; k0 += 64) {
    if (k0) __syncthreads();
#pragma unroll
    for (int p = 0; p < 4; ++p) {
      int idx = tid + 256 * p;
      int row = idx >> 3, ch = idx & 7;
      int dch = ch ^ (row & 7);
      *(half8*)&lA[row * 64 + dch * 8] =
          *(const half8*)&seqh[(size_t)(m0 + row) * 128 + k0 + ch * 8];
      *(half8*)&lB[row * 64 + dch * 8] =
          *(const half8*)&wprojh[(size_t)(e0 + row) * 128 + k0 + ch * 8];
    }
    __syncthreads();
#pragma unroll
    for (int kk = 0; kk < 2; ++kk) {
      half8 a[2];
#pragma unroll
      for (int rf = 0; rf < 2; ++rf) {
        int row = wv * 32 + rf * 16 + rsel;
        int ch = (kk * 4 + q) ^ (row & 7);
        a[rf] = *(const half8*)&lA[row * 64 + ch * 8];
      }
#pragma unroll
      for (int cf = 0; cf < 8; ++cf) {
        int row = cf * 16 + rsel;
        int ch = (kk * 4 + q) ^ (row & 7);
        half8 b = *(const half8*)&lB[row * 64 + ch * 8];
        acc[0][cf] = __builtin_amdgcn_mfma_f32_16x16x32_f16(a[0], b, acc[0][cf], 0, 0, 0);
        acc[1][cf] = __builtin_amdgcn_mfma_f32_16x16x32_f16(a[1], b, acc[1][cf], 0, 0, 0);
      }
    }
  }

#pragma unroll
  for (int rf = 0; rf < 2; ++rf) {
    int mb = m0 + wv * 32 + rf * 16 + q * 4;
    if (e0 < 256) {
#pragma unroll
      for (int cf = 0; cf < 8; ++cf) {
        float* pz = z + (size_t)mb * 256 + e0 + cf * 16 + rsel;
#pragma unroll
        for (int r = 0; r < 4; ++r) pz[(size_t)r * 256] = acc[rf][cf][r];
      }
    } else if (e0 < 640) {
#pragma unroll
      for (int cf = 0; cf < 8; ++cf) {
        float* px = xbc + (size_t)mb * 384 + (e0 - 256) + cf * 16 + rsel;
#pragma unroll
        for (int r = 0; r < 4; ++r) px[(size_t)r * 384] = acc[rf][cf][r];
      }
    } else {
      if (rsel < 8) {
        float bias = P[P_DTB + rsel];
#pragma unroll
        for (int r = 0; r < 4; ++r) {
          float dv = acc[rf][0][r] + bias;
          float sp = (dv > 20.f) ? dv : log1pf(__expf(dv));
          dtb[(size_t)(mb + r) * 8 + rsel] = sp;
        }
      }
    }
  }
}

// ---------------- K5: causal conv1d + SiLU, IN-PLACE on xbc ---------------------
__global__ __launch_bounds__(256) void k_conv1d_v3(float* xbc,
                                                   const float* __restrict__ P) {
  float* buf = xbc + (size_t)blockIdx.x * 49152;   // 128*384
  for (int e = threadIdx.x; e < 384; e += 256) {
    float w0 = P[P_CW + e * 4 + 0], w1 = P[P_CW + e * 4 + 1];
    float w2 = P[P_CW + e * 4 + 2], w3 = P[P_CW + e * 4 + 3];
    float bb = P[P_CB + e];
    float x0 = 0.f, x1 = 0.f, x2 = 0.f;
    for (int l = 0; l < 128; ++l) {
      float x3 = buf[l * 384 + e];
      float a = bb + w0 * x0 + w1 * x1 + w2 * x2 + w3 * x3;
      buf[l * 384 + e] = a / (1.f + __expf(-a));
      x0 = x1; x1 = x2; x2 = x3;
    }
  }
}

// ---------------- K6 v6: selective scan, 2-way block split + LDS tiling ----------
// Grid (CH, 2). Block = 1 seq, states sblk*32..+31. 16-step tiles: B/C (64 f32
// per step) + dt staged in double-buffered LDS by all 256 threads (1 float4
// each, coalesced); x preloaded into 16 VGPRs per tile. Per step: 16 broadcast
// ds_read_b128 + 64 FMA, zero cross-lane ops. Issue-early/write-late staging,
// one barrier per tile.
__global__ __launch_bounds__(256) void k_scan_v6(const float* __restrict__ pc,
                                                 const float* __restrict__ dtb,
                                                 const float* __restrict__ P,
                                                 float* __restrict__ ysA,
                                                 float* __restrict__ ysB) {
  int seq = blockIdx.x;
  int sblk = blockIdx.y;          // 0: states 0..31, 1: states 32..63
  int tid = threadIdx.x;
  int head = tid >> 5;            // 0..7
  int d = tid & 31;               // 0..31  (head*32+d == tid)
  float A = -__expf(P[P_ALOG + head]);
  float Dk = P[P_DSKIP + head];
  float h[32];
#pragma unroll
  for (int s = 0; s < 32; ++s) h[s] = 0.f;

  __shared__ __align__(16) float sBC[2][16][64];  // [step][0..31]=B, [32..63]=C
  __shared__ float sdt[2][128];                   // [step*8+head]

  const float* base = pc + (size_t)seq * 49152;
  const float* dtp = dtb + (size_t)seq * 1024;
  float* yp = (sblk ? ysB : ysA) + (size_t)seq * 32768;

  int st = tid >> 4;              // 0..15 staging step
  int q = tid & 15;               // 0..15 staging quad
  size_t bcoff = (size_t)st * 384 +
                 (q < 8 ? (size_t)(256 + sblk * 32 + q * 4)
                        : (size_t)(320 + sblk * 32 + (q - 8) * 4));
  int ldst = (q < 8) ? q * 4 : 32 + (q - 8) * 4;

  // prologue: stage tile 0 into buf0
  {
    float4 rv = *(const float4*)(base + bcoff);
    float rdt = (tid < 128) ? dtp[tid] : 0.f;
    *(float4*)&sBC[0][st][ldst] = rv;
    if (tid < 128) sdt[0][tid] = rdt;
  }
  __syncthreads();

  for (int t = 0; t < 8; ++t) {
    int buf = t & 1;
    int l0 = t * 16;
    // x for this tile -> 16 VGPRs (coalesced dword per step)
    float xs[16];
#pragma unroll
    for (int s = 0; s < 16; ++s) xs[s] = base[(size_t)(l0 + s) * 384 + tid];
    // issue next tile's staging loads early (complete under this tile's compute)
    float4 rv;
    float rdt = 0.f;
    if (t < 7) {
      rv = *(const float4*)(base + (size_t)(l0 + 16) * 384 + bcoff);
      if (tid < 128) rdt = dtp[(l0 + 16) * 8 + tid];
    }
#pragma unroll
    for (int s = 0; s < 16; ++s) {
      float dt = sdt[buf][s * 8 + head];
      float dA = __expf(dt * A);
      float coef = dt * xs[s];
      float a0 = 0.f, a1 = 0.f, a2 = 0.f, a3 = 0.f;
#pragma unroll
      for (int qq = 0; qq < 8; ++qq) {
        float4 bq = *(const float4*)&sBC[buf][s][qq * 4];
        float4 cq = *(const float4*)&sBC[buf][s][32 + qq * 4];
        h[qq * 4 + 0] = h[qq * 4 + 0] * dA + coef * bq.x;  a0 += h[qq * 4 + 0] * cq.x;
        h[qq * 4 + 1] = h[qq * 4 + 1] * dA + coef * bq.y;  a1 += h[qq * 4 + 1] * cq.y;
        h[qq * 4 + 2] = h[qq * 4 + 2] * dA + coef * bq.z;  a2 += h[qq * 4 + 2] * cq.z;
        h[qq * 4 + 3] = h[qq * 4 + 3] * dA + coef * bq.w;  a3 += h[qq * 4 + 3] * cq.w;
      }
      float res = (a0 + a1) + (a2 + a3);
      if (sblk == 0) res += Dk * xs[s];
      yp[(size_t)(l0 + s) * 256 + tid] = res;
    }
    if (t < 7) {
      *(float4*)&sBC[buf ^ 1][st][ldst] = rv;
      if (tid < 128) sdt[buf ^ 1][tid] = rdt;
    }
    __syncthreads();
  }
}

// ---------------- K7: gate + RMS norm -> ynorm f16 (sums ysA+ysB) ----------------
__global__ __launch_bounds__(256) void k_gate_v5(const float* __restrict__ ysA,
                                                 const float* __restrict__ ysB,
                                                 const float* __restrict__ z,
                                                 const float* __restrict__ P,
                                                 _Float16* __restrict__ ynh) {
  int l = blockIdx.x;
  int e = threadIdx.x;
  __shared__ float red[4];
  size_t idx = (size_t)l * 256 + e;
  float yv = ysA[idx] + ysB[idx];
  float zv = z[idx];
  float g = zv / (1.f + __expf(-zv));
  float y = yv * g;
  float ss = y * y;
  for (int o = 32; o; o >>= 1) ss += __shfl_down(ss, o, 64);
  if ((threadIdx.x & 63) == 0) red[threadIdx.x >> 6] = ss;
  __syncthreads();
  float tot = red[0] + red[1] + red[2] + red[3];
  float r = rsqrtf(tot * (1.f / 256.f) + 1e-5f);
  ynh[idx] = (_Float16)(y * r * P[P_NG + e]);
}

// ---------------- G2 v3: out = ynorm @ outw^T via MFMA f16 ----------------------
__global__ __launch_bounds__(256) void k_gemm2_v3(const _Float16* __restrict__ ynh,
                                                  const _Float16* __restrict__ outwh,
                                                  float* __restrict__ dout,
                                                  int tok0) {
  __shared__ __align__(16) _Float16 lA[128 * 64];
  __shared__ __align__(16) _Float16 lB[64 * 64];
  int t0 = blockIdx.x * 64;
  int tid = threadIdx.x;
  int lane = tid & 63;
  int wv = tid >> 6;
  f32x4 acc[2][4];
#pragma unroll
  for (int rf = 0; rf < 2; ++rf)
#pragma unroll
    for (int cf = 0; cf < 4; ++cf) acc[rf][cf] = (f32x4){0.f, 0.f, 0.f, 0.f};

  int rsel = lane & 15, q = lane >> 4;
  for (int k0 = 0; k0 < 256; k0 += 64) {
    if (k0) __syncthreads();
#pragma unroll
    for (int p = 0; p < 4; ++p) {
      int idx = tid + 256 * p;
      int row = idx >> 3, ch = idx & 7;
      int dch = ch ^ (row & 7);
      *(half8*)&lA[row * 64 + dch * 8] =
          *(const half8*)&outwh[(size_t)row * 256 + k0 + ch * 8];
    }
#pragma unroll
    for (int p = 0; p < 2; ++p) {
      int idx = tid + 256 * p;
      int row = idx >> 3, ch = idx & 7;
      int dch = ch ^ (row & 7);
      *(half8*)&lB[row * 64 + dch * 8] =
          *(const half8*)&ynh[(size_t)(t0 + row) * 256 + k0 + ch * 8];
    }
    __syncthreads();
#pragma unroll
    for (int kk = 0; kk < 2; ++kk) {
      half8 a[2];
#pragma unroll
      for (int rf = 0; rf < 2; ++rf) {
        int row = wv * 32 + rf * 16 + rsel;
        int ch = (kk * 4 + q) ^ (row & 7);
        a[rf] = *(const half8*)&lA[row * 64 + ch * 8];
      }
#pragma unroll
      for (int cf = 0; cf < 4; ++cf) {
        int row = cf * 16 + rsel;
        int ch = (kk * 4 + q) ^ (row & 7);
        half8 b = *(const half8*)&lB[row * 64 + ch * 8];
        acc[0][cf] = __builtin_amdgcn_mfma_f32_16x16x32_f16(a[0], b, acc[0][cf], 0, 0, 0);
        acc[1][cf] = __builtin_amdgcn_mfma_f32_16x16x32_f16(a[1], b, acc[1][cf], 0, 0, 0);
      }
    }
  }

  int l0 = tok0 + t0;
  int b = l0 >> 14;
  int rem0 = l0 & 16383;
#pragma unroll
  for (int rf = 0; rf < 2; ++rf) {
    int cbase = wv * 32 + rf * 16 + q * 4;
#pragma unroll
    for (int cf = 0; cf < 4; ++cf) {
#pragma unroll
      for (int r = 0; r < 4; ++r) {
        dout[(size_t)(b * 128 + cbase + r) * 16384 + rem0 + cf * 16 + rsel] = acc[rf][cf][r];
      }
    }
  }
}

extern "C" void kernel_launch(void* const* d_in, const int* in_sizes, int n_in,
                              void* d_out, int out_size, void* d_ws, size_t ws_size,
                              hipStream_t stream) {
  const void* x      = d_in[0];
  const void* dww    = d_in[1];
  const void* gng    = d_in[2];
  const void* gnb    = d_in[3];
  const void* pww    = d_in[4];
  const void* pwb    = d_in[5];
  const void* wproj  = d_in[6];
  const void* cw     = d_in[7];
  const void* cb     = d_in[8];
  const void* dtbias = d_in[9];
  const void* alog   = d_in[10];
  const void* dskip  = d_in[11];
  const void* ng     = d_in[12];
  const void* outw   = d_in[13];
  float* out = (float*)d_out;

  char* ws = (char*)d_ws;
  float* gst        = (float*)(ws + 0);
  float* mr         = (float*)(ws + 4096);
  float* P          = (float*)(ws + 8192);
  _Float16* wprojh  = (_Float16*)(ws + 40960);
  _Float16* outwh   = (_Float16*)(ws + 372736);
  float* offf       = (float*)(ws + 503808);
  char* cbase       = ws + 1028096;

  // h1 (f32, 67,108,864 B) lives in d_out's out_2d region.
  float* h1f = out;

  // Per-sequence chunk bytes:
  //   seq f16 32768 + z 131072 + xbc 196608 + dtb 4096 + ysA 131072
  //   + ysB 131072 = 626688.  (ynorm f16 reuses xbc region.)
  const int opts[11] = {1024, 512, 256, 128, 64, 32, 16, 8, 4, 2, 1};
  int CH = 1;
  for (int i = 0; i < 11; ++i) {
    if (1028096ull + (unsigned long long)opts[i] * 626688ull <= (unsigned long long)ws_size) {
      CH = opts[i];
      break;
    }
  }
  int NC = 1024 / CH;

  _Float16* seqh = (_Float16*)(cbase);
  float* zf      = (float*)(cbase + (size_t)CH * 32768);
  float* xbcf    = (float*)(cbase + (size_t)CH * 163840);
  float* dtbf    = (float*)(cbase + (size_t)CH * 360448);
  float* ysA     = (float*)(cbase + (size_t)CH * 364544);
  float* ysB     = (float*)(cbase + (size_t)CH * 495616);
  _Float16* ynh  = (_Float16*)xbcf;

  k_prep_params<<<1, 256, 0, stream>>>(dww, cw, cb, gng, gnb, pww, pwb, dtbias,
                                       alog, dskip, ng, P, gst);
  k_prep_w<<<128, 256, 0, stream>>>(wproj, outw, gng, wprojh, outwh);
  k_dwconv_v2<<<4096, 256, 0, stream>>>(x, gng, P, h1f, gst);
  k_stats<<<1, 64, 0, stream>>>(gst, mr);
  k_gn_off<<<1024, 128, 0, stream>>>(h1f, mr, P, offf, out);

  int M = CH * 128;
  for (int c = 0; c < NC; ++c) {
    int s0 = c * CH;
    k_deform<<<CH, 128, 0, stream>>>(x, gng, offf, seqh, s0);
    k_gemm1_v3<<<dim3(M / 128, 6), 256, 0, stream>>>(seqh, wprojh, P, zf, xbcf, dtbf);
    k_conv1d_v3<<<CH, 256, 0, stream>>>(xbcf, P);
    k_scan_v6<<<dim3(CH, 2), 256, 0, stream>>>(xbcf, dtbf, P, ysA, ysB);
    k_gate_v5<<<CH * 128, 256, 0, stream>>>(ysA, ysB, zf, P, ynh);
    k_gemm2_v3<<<dim3(M / 64), 256, 0, stream>>>(ynh, outwh, out, s0 * 128);
  }
}

// Round 7
// 866.302 us; speedup vs baseline: 1.9090x; 1.2401x over previous
//
#include <hip/hip_runtime.h>
#include <math.h>

// B=8, C=128, H=128, W=128, D_INNER=256, D_STATE=64, HEADDIM=32, NHEADS=8,
// D_CONV=4, GN_GROUPS=8, D_XBC=384, D_INPROJ=648.
// Inputs f32 (probed via gn_g word0). OUTPUT IS F32 (reference output dtype).
// d_out = [out_2d: 16,777,216 f32][offset: 131,072 f32].
// h1 (f32) is staged in d_out's out_2d region.
//
// R1: scan de-spilled -> 3236us. R2: register-blocked VALU GEMMs -> 2123us.
// R3: MFMA f16 GEMMs -> 1078us. R4: dwconv v2 kept; scan v4 regressed.
// R5: scan v5 block state split -> 1268us. R6: scan v6 LDS-tiled B/C -> 1074us.
// R7: (a) conv1d ELIMINATED - fused into scan v7 (x-path: rolling 3-reg window;
// B/C staging: 4-tap loads + conv + SiLU before LDS write). Removes a full
// xbc round trip AND the in-place aliasing serialization. (b) deform v2:
// 256 threads (c split for loads, l split for writes) halves both serial loops.

typedef _Float16 half8 __attribute__((ext_vector_type(8)));
typedef float f32x4 __attribute__((ext_vector_type(4)));

__device__ __forceinline__ float b2f(unsigned short u) {
  return __uint_as_float(((unsigned int)u) << 16);
}
__device__ __forceinline__ bool in_is_f32(const void* gng) {
  return ((const unsigned int*)gng)[0] == 0x3F800000u;
}

#define P_DWW 0
#define P_CW 3200
#define P_CB 4736
#define P_GNG 5120
#define P_GNB 5248
#define P_PWW 5376
#define P_PWB 5504
#define P_DTB 5505
#define P_ALOG 5513
#define P_DSKIP 5521
#define P_NG 5529

__global__ void k_prep_params(const void* dww, const void* cw, const void* cb,
                              const void* gng, const void* gnb, const void* pww,
                              const void* pwb, const void* dtbias, const void* alog,
                              const void* dskip, const void* ng, float* __restrict__ P,
                              float* __restrict__ gst) {
  bool f = in_is_f32(gng);
  int tid = threadIdx.x;
  if (tid < 128) gst[tid] = 0.f;
  auto cvt = [&](const void* src, int n, int off) {
    for (int i = tid; i < n; i += 256)
      P[off + i] = f ? ((const float*)src)[i] : b2f(((const unsigned short*)src)[i]);
  };
  cvt(dww, 3200, P_DWW);
  cvt(cw, 1536, P_CW);
  cvt(cb, 384, P_CB);
  cvt(gng, 128, P_GNG);
  cvt(gnb, 128, P_GNB);
  cvt(pww, 128, P_PWW);
  cvt(pwb, 1, P_PWB);
  cvt(dtbias, 8, P_DTB);
  cvt(alog, 8, P_ALOG);
  cvt(dskip, 8, P_DSKIP);
  cvt(ng, 256, P_NG);
}

// wprojh: 768 x 128 f16 (rows >=648 zero).  outwh: 128 x 256 f16.
__global__ void k_prep_w(const void* wproj, const void* outw, const void* gng,
                         _Float16* __restrict__ wprojh, _Float16* __restrict__ outwh) {
  bool f = in_is_f32(gng);
  int stride = gridDim.x * blockDim.x;
  for (int i = blockIdx.x * blockDim.x + threadIdx.x; i < 98304; i += stride) {
    int row = i >> 7;
    float v = 0.f;
    if (row < 648) v = f ? ((const float*)wproj)[i] : b2f(((const unsigned short*)wproj)[i]);
    wprojh[i] = (_Float16)v;
  }
  for (int i = blockIdx.x * blockDim.x + threadIdx.x; i < 32768; i += stride)
    outwh[i] = (_Float16)(f ? ((const float*)outw)[i] : b2f(((const unsigned short*)outw)[i]));
}

// ---------------- K1 v2: depthwise 5x5 conv + group stats -----------------------
__global__ __launch_bounds__(256) void k_dwconv_v2(const void* __restrict__ x,
                                                   const void* __restrict__ gng,
                                                   const float* __restrict__ P,
                                                   float* __restrict__ h1,
                                                   float* __restrict__ gst) {
  int blk = blockIdx.x;
  int bc = blk >> 2, sub = blk & 3;
  int b = bc >> 7, c = bc & 127;
  int ty0 = (sub >> 1) * 64, tx0 = (sub & 1) * 64;
  bool f32x = in_is_f32(gng);
  __shared__ __align__(16) float t[68 * 72];
  __shared__ float red[8];
  const float* xf = (const float*)x + (size_t)bc * 16384;
  const unsigned short* xb = (const unsigned short*)x + (size_t)bc * 16384;
  for (int i = threadIdx.x; i < 68 * 68; i += 256) {
    int r = i / 68, cc = i - r * 68;
    int gy = ty0 + r - 2, gx = tx0 + cc - 2;
    float v = 0.f;
    if (gy >= 0 && gy < 128 && gx >= 0 && gx < 128) {
      int off = gy * 128 + gx;
      v = f32x ? xf[off] : b2f(xb[off]);
    }
    t[r * 72 + cc] = v;
  }
  float w[25];
#pragma unroll
  for (int k = 0; k < 25; ++k) w[k] = P[P_DWW + c * 25 + k];
  __syncthreads();

  int ox = (threadIdx.x & 15) * 4;
  int oy = (threadIdx.x >> 4) * 4;
  float acc[4][4];
#pragma unroll
  for (int r = 0; r < 4; ++r)
#pragma unroll
    for (int j = 0; j < 4; ++j) acc[r][j] = 0.f;

#pragma unroll
  for (int i = 0; i < 8; ++i) {
    float4 p0 = *(const float4*)&t[(oy + i) * 72 + ox];
    float4 p1 = *(const float4*)&t[(oy + i) * 72 + ox + 4];
    float in8[8] = {p0.x, p0.y, p0.z, p0.w, p1.x, p1.y, p1.z, p1.w};
#pragma unroll
    for (int r = 0; r < 4; ++r) {
      if (i - r >= 0 && i - r <= 4) {
        int ky = i - r;
#pragma unroll
        for (int j = 0; j < 4; ++j)
#pragma unroll
          for (int kx = 0; kx < 5; ++kx)
            acc[r][j] += w[ky * 5 + kx] * in8[j + kx];
      }
    }
  }

  float s = 0.f, sq = 0.f;
  float* hp = h1 + (size_t)bc * 16384;
#pragma unroll
  for (int r = 0; r < 4; ++r) {
    *(float4*)&hp[(ty0 + oy + r) * 128 + tx0 + ox] =
        make_float4(acc[r][0], acc[r][1], acc[r][2], acc[r][3]);
#pragma unroll
    for (int j = 0; j < 4; ++j) { s += acc[r][j]; sq += acc[r][j] * acc[r][j]; }
  }
  for (int o = 32; o; o >>= 1) { s += __shfl_down(s, o, 64); sq += __shfl_down(sq, o, 64); }
  int wv = threadIdx.x >> 6;
  if ((threadIdx.x & 63) == 0) { red[wv] = s; red[4 + wv] = sq; }
  __syncthreads();
  if (threadIdx.x == 0) {
    float ts = red[0] + red[1] + red[2] + red[3];
    float tq = red[4] + red[5] + red[6] + red[7];
    int g = (b << 3) + (c >> 4);
    atomicAdd(&gst[g * 2], ts);
    atomicAdd(&gst[g * 2 + 1], tq);
  }
}

__global__ void k_stats(const float* __restrict__ gst, float* __restrict__ mr) {
  int g = threadIdx.x;
  if (g < 64) {
    const float invN = 1.f / 262144.f;
    float mean = gst[g * 2] * invN;
    float var = gst[g * 2 + 1] * invN - mean * mean;
    mr[g * 2] = mean;
    mr[g * 2 + 1] = rsqrtf(var + 1e-5f);
  }
}

// ---------------- K3: GN + exact GELU + 1x1 conv + tanh*8 -> offset (f32 out) ----
__global__ __launch_bounds__(128) void k_gn_off(const float* __restrict__ h1,
                                                const float* __restrict__ mr,
                                                const float* __restrict__ P,
                                                float* __restrict__ offf,
                                                float* __restrict__ dout) {
  int bh = blockIdx.x;
  int b = bh >> 7, h = bh & 127;
  int w = threadIdx.x;
  float acc = 0.f;
  for (int c = 0; c < 128; ++c) {
    float v = h1[(((size_t)(b * 128 + c)) * 128 + h) * 128 + w];
    int g = b * 8 + (c >> 4);
    float nv = (v - mr[g * 2]) * mr[g * 2 + 1] * P[P_GNG + c] + P[P_GNB + c];
    float ge = 0.5f * nv * (1.f + erff(nv * 0.70710678118f));
    acc += ge * P[P_PWW + c];
  }
  float off = acc + P[P_PWB];
  float ofv = tanhf(off) * 8.0f;
  offf[bh * 128 + w] = ofv;
  dout[16777216 + bh * 128 + w] = ofv;
}

// ---------------- K4 v2: y-only grid sample + transpose -> seq f16 (l,c) --------
// 256 threads: loads split 2-way over c (64 iters), writes split 2-way over l.
__global__ __launch_bounds__(256) void k_deform_v2(const void* __restrict__ x,
                                                   const void* __restrict__ gng,
                                                   const float* __restrict__ offf,
                                                   _Float16* __restrict__ seqc,
                                                   int s0) {
  int bh = s0 + blockIdx.x;
  int b = bh >> 7, h = bh & 127;
  int tid = threadIdx.x;
  int w = tid & 127;
  int half = tid >> 7;
  bool f32x = in_is_f32(gng);
  __shared__ float t[128 * 130];
  float ofv = offf[bh * 128 + w];
  float gy = -1.f + (2.f / 127.f) * (float)h + ofv * (2.f / 127.f);
  gy = fminf(fmaxf(gy, -1.f), 1.f);
  float py = (gy + 1.f) * 0.5f * 127.f;
  py = fminf(fmaxf(py, 0.f), 127.f);
  float y0f = floorf(py);
  float wy = py - y0f;
  int y0 = (int)y0f;
  int y1 = min(y0 + 1, 127);
  const float* xfb = (const float*)x + (size_t)b * 128 * 16384;
  const unsigned short* xbb = (const unsigned short*)x + (size_t)b * 128 * 16384;
  int c0 = half * 64;
  for (int i = 0; i < 64; ++i) {
    int c = c0 + i;
    size_t o0 = (size_t)c * 16384 + y0 * 128 + w;
    size_t o1 = (size_t)c * 16384 + y1 * 128 + w;
    float v0, v1;
    if (f32x) { v0 = xfb[o0]; v1 = xfb[o1]; }
    else      { v0 = b2f(xbb[o0]); v1 = b2f(xbb[o1]); }
    t[c * 130 + w] = v0 + wy * (v1 - v0);
  }
  __syncthreads();
  int c2 = tid & 127;
  int lb = (tid >> 7) * 64;
  _Float16* sp = seqc + (size_t)blockIdx.x * 16384;
  for (int i = 0; i < 64; ++i) {
    int l = lb + i;
    sp[l * 128 + c2] = (_Float16)t[c2 * 130 + l];
  }
}

// ---------------- G1 v3: zxbcdt = seq @ wproj^T via MFMA f16 --------------------
__global__ __launch_bounds__(256) void k_gemm1_v3(const _Float16* __restrict__ seqh,
                                                  const _Float16* __restrict__ wprojh,
                                                  const float* __restrict__ P,
                                                  float* __restrict__ z,
                                                  float* __restrict__ xbc,
                                                  float* __restrict__ dtb) {
  __shared__ __align__(16) _Float16 lA[128 * 64];
  __shared__ __align__(16) _Float16 lB[128 * 64];
  int m0 = blockIdx.x * 128;
  int e0 = blockIdx.y * 128;
  int tid = threadIdx.x;
  int lane = tid & 63;
  int wv = tid >> 6;
  f32x4 acc[2][8];
#pragma unroll
  for (int rf = 0; rf < 2; ++rf)
#pragma unroll
    for (int cf = 0; cf < 8; ++cf) acc[rf][cf] = (f32x4){0.f, 0.f, 0.f, 0.f};

  int rsel = lane & 15, q = lane >> 4;
  for (int k0 = 0; k0 < 128; k0 += 64) {
    if (k0) __syncthreads();
#pragma unroll
    for (int p = 0; p < 4; ++p) {
      int idx = tid + 256 * p;
      int row = idx >> 3, ch = idx & 7;
      int dch = ch ^ (row & 7);
      *(half8*)&lA[row * 64 + dch * 8] =
          *(const half8*)&seqh[(size_t)(m0 + row) * 128 + k0 + ch * 8];
      *(half8*)&lB[row * 64 + dch * 8] =
          *(const half8*)&wprojh[(size_t)(e0 + row) * 128 + k0 + ch * 8];
    }
    __syncthreads();
#pragma unroll
    for (int kk = 0; kk < 2; ++kk) {
      half8 a[2];
#pragma unroll
      for (int rf = 0; rf < 2; ++rf) {
        int row = wv * 32 + rf * 16 + rsel;
        int ch = (kk * 4 + q) ^ (row & 7);
        a[rf] = *(const half8*)&lA[row * 64 + ch * 8];
      }
#pragma unroll
      for (int cf = 0; cf < 8; ++cf) {
        int row = cf * 16 + rsel;
        int ch = (kk * 4 + q) ^ (row & 7);
        half8 b = *(const half8*)&lB[row * 64 + ch * 8];
        acc[0][cf] = __builtin_amdgcn_mfma_f32_16x16x32_f16(a[0], b, acc[0][cf], 0, 0, 0);
        acc[1][cf] = __builtin_amdgcn_mfma_f32_16x16x32_f16(a[1], b, acc[1][cf], 0, 0, 0);
      }
    }
  }

#pragma unroll
  for (int rf = 0; rf < 2; ++rf) {
    int mb = m0 + wv * 32 + rf * 16 + q * 4;
    if (e0 < 256) {
#pragma unroll
      for (int cf = 0; cf < 8; ++cf) {
        float* pz = z + (size_t)mb * 256 + e0 + cf * 16 + rsel;
#pragma unroll
        for (int r = 0; r < 4; ++r) pz[(size_t)r * 256] = acc[rf][cf][r];
      }
    } else if (e0 < 640) {
#pragma unroll
      for (int cf = 0; cf < 8; ++cf) {
        float* px = xbc + (size_t)mb * 384 + (e0 - 256) + cf * 16 + rsel;
#pragma unroll
        for (int r = 0; r < 4; ++r) px[(size_t)r * 384] = acc[rf][cf][r];
      }
    } else {
      if (rsel < 8) {
        float bias = P[P_DTB + rsel];
#pragma unroll
        for (int r = 0; r < 4; ++r) {
          float dv = acc[rf][0][r] + bias;
          float sp = (dv > 20.f) ? dv : log1pf(__expf(dv));
          dtb[(size_t)(mb + r) * 8 + rsel] = sp;
        }
      }
    }
  }
}

// ---------------- K6 v7: selective scan with FUSED causal conv1d + SiLU ----------
// Grid (CH, 2). Block = 1 seq, states sblk*32..+31. Reads RAW xbc (gemm1 out).
// x-path (e=tid): rolling 3-reg window + per-thread conv weights -> conv+SiLU
// inline. B/C staging threads: 4-tap float4 loads + conv + SiLU before the LDS
// write (double-buffered, issue-early/write-late, 1 barrier per 16-step tile).
__global__ __launch_bounds__(256) void k_scan_v7(const float* __restrict__ xbc,
                                                 const float* __restrict__ dtb,
                                                 const float* __restrict__ P,
                                                 float* __restrict__ ysA,
                                                 float* __restrict__ ysB) {
  int seq = blockIdx.x;
  int sblk = blockIdx.y;          // 0: states 0..31, 1: states 32..63
  int tid = threadIdx.x;
  int head = tid >> 5;            // 0..7
  float A = -__expf(P[P_ALOG + head]);
  float Dk = P[P_DSKIP + head];
  // x-path conv weights (e = tid, 0..255)
  float wx0 = P[P_CW + tid * 4 + 0], wx1 = P[P_CW + tid * 4 + 1];
  float wx2 = P[P_CW + tid * 4 + 2], wx3 = P[P_CW + tid * 4 + 3];
  float cbx = P[P_CB + tid];
  float h[32];
#pragma unroll
  for (int s = 0; s < 32; ++s) h[s] = 0.f;

  __shared__ __align__(16) float sBC[2][16][64];  // [step][0..31]=B, [32..63]=C
  __shared__ float sdt[2][128];                   // [step*8+head]

  const float* base = xbc + (size_t)seq * 49152;
  const float* dtp = dtb + (size_t)seq * 1024;
  float* yp = (sblk ? ysB : ysA) + (size_t)seq * 32768;

  int st = tid >> 4;              // 0..15 staging step
  int q = tid & 15;               // 0..15 staging quad
  int colbase = (q < 8) ? (256 + sblk * 32 + q * 4)
                        : (320 + sblk * 32 + (q - 8) * 4);
  int ldst = (q < 8) ? q * 4 : 32 + (q - 8) * 4;
  // B/C conv weights for this thread's 4 columns
  float cwt[4][4], cbv[4];
#pragma unroll
  for (int j = 0; j < 4; ++j) {
#pragma unroll
    for (int k = 0; k < 4; ++k) cwt[j][k] = P[P_CW + (colbase + j) * 4 + k];
    cbv[j] = P[P_CB + colbase + j];
  }

  auto conv4 = [&](int row) -> float4 {
    // out[l] = w0*x[l-3] + w1*x[l-2] + w2*x[l-1] + w3*x[l] (+bias), SiLU
    float4 r0 = *(const float4*)(base + (size_t)row * 384 + colbase);
    float4 r1 = make_float4(0.f, 0.f, 0.f, 0.f);
    float4 r2 = r1, r3 = r1;
    if (row >= 1) r1 = *(const float4*)(base + (size_t)(row - 1) * 384 + colbase);
    if (row >= 2) r2 = *(const float4*)(base + (size_t)(row - 2) * 384 + colbase);
    if (row >= 3) r3 = *(const float4*)(base + (size_t)(row - 3) * 384 + colbase);
    float4 o;
    o.x = cbv[0] + cwt[0][3] * r0.x + cwt[0][2] * r1.x + cwt[0][1] * r2.x + cwt[0][0] * r3.x;
    o.y = cbv[1] + cwt[1][3] * r0.y + cwt[1][2] * r1.y + cwt[1][1] * r2.y + cwt[1][0] * r3.y;
    o.z = cbv[2] + cwt[2][3] * r0.z + cwt[2][2] * r1.z + cwt[2][1] * r2.z + cwt[2][0] * r3.z;
    o.w = cbv[3] + cwt[3][3] * r0.w + cwt[3][2] * r1.w + cwt[3][1] * r2.w + cwt[3][0] * r3.w;
    o.x = o.x / (1.f + __expf(-o.x));
    o.y = o.y / (1.f + __expf(-o.y));
    o.z = o.z / (1.f + __expf(-o.z));
    o.w = o.w / (1.f + __expf(-o.w));
    return o;
  };

  // prologue: stage tile 0 into buf0 (conv applied)
  {
    float4 rv = conv4(st);
    float rdt = (tid < 128) ? dtp[tid] : 0.f;
    *(float4*)&sBC[0][st][ldst] = rv;
    if (tid < 128) sdt[0][tid] = rdt;
  }
  __syncthreads();

  float x0 = 0.f, x1 = 0.f, x2 = 0.f;   // rolling raw-x window for e=tid
  for (int t = 0; t < 8; ++t) {
    int buf = t & 1;
    int l0 = t * 16;
    // raw x for this tile -> 16 VGPRs (coalesced dword per step)
    float xr[16];
#pragma unroll
    for (int s = 0; s < 16; ++s) xr[s] = base[(size_t)(l0 + s) * 384 + tid];
    // issue next tile's staging loads early (complete under this tile's compute)
    float4 rv;
    float rdt = 0.f;
    if (t < 7) {
      rv = conv4(l0 + 16 + st);
      if (tid < 128) rdt = dtp[(l0 + 16) * 8 + tid];
    }
#pragma unroll
    for (int s = 0; s < 16; ++s) {
      // fused causal conv + SiLU for x
      float a = cbx + wx0 * x0 + wx1 * x1 + wx2 * x2 + wx3 * xr[s];
      float xv = a / (1.f + __expf(-a));
      x0 = x1; x1 = x2; x2 = xr[s];
      float dt = sdt[buf][s * 8 + head];
      float dA = __expf(dt * A);
      float coef = dt * xv;
      float a0 = 0.f, a1 = 0.f, a2 = 0.f, a3 = 0.f;
#pragma unroll
      for (int qq = 0; qq < 8; ++qq) {
        float4 bq = *(const float4*)&sBC[buf][s][qq * 4];
        float4 cq = *(const float4*)&sBC[buf][s][32 + qq * 4];
        h[qq * 4 + 0] = h[qq * 4 + 0] * dA + coef * bq.x;  a0 += h[qq * 4 + 0] * cq.x;
        h[qq * 4 + 1] = h[qq * 4 + 1] * dA + coef * bq.y;  a1 += h[qq * 4 + 1] * cq.y;
        h[qq * 4 + 2] = h[qq * 4 + 2] * dA + coef * bq.z;  a2 += h[qq * 4 + 2] * cq.z;
        h[qq * 4 + 3] = h[qq * 4 + 3] * dA + coef * bq.w;  a3 += h[qq * 4 + 3] * cq.w;
      }
      float res = (a0 + a1) + (a2 + a3);
      if (sblk == 0) res += Dk * xv;
      yp[(size_t)(l0 + s) * 256 + tid] = res;
    }
    if (t < 7) {
      *(float4*)&sBC[buf ^ 1][st][ldst] = rv;
      if (tid < 128) sdt[buf ^ 1][tid] = rdt;
    }
    __syncthreads();
  }
}

// ---------------- K7: gate + RMS norm -> ynorm f16 (sums ysA+ysB) ----------------
__global__ __launch_bounds__(256) void k_gate_v5(const float* __restrict__ ysA,
                                                 const float* __restrict__ ysB,
                                                 const float* __restrict__ z,
                                                 const float* __restrict__ P,
                                                 _Float16* __restrict__ ynh) {
  int l = blockIdx.x;
  int e = threadIdx.x;
  __shared__ float red[4];
  size_t idx = (size_t)l * 256 + e;
  float yv = ysA[idx] + ysB[idx];
  float zv = z[idx];
  float g = zv / (1.f + __expf(-zv));
  float y = yv * g;
  float ss = y * y;
  for (int o = 32; o; o >>= 1) ss += __shfl_down(ss, o, 64);
  if ((threadIdx.x & 63) == 0) red[threadIdx.x >> 6] = ss;
  __syncthreads();
  float tot = red[0] + red[1] + red[2] + red[3];
  float r = rsqrtf(tot * (1.f / 256.f) + 1e-5f);
  ynh[idx] = (_Float16)(y * r * P[P_NG + e]);
}

// ---------------- G2 v3: out = ynorm @ outw^T via MFMA f16 ----------------------
__global__ __launch_bounds__(256) void k_gemm2_v3(const _Float16* __restrict__ ynh,
                                                  const _Float16* __restrict__ outwh,
                                                  float* __restrict__ dout,
                                                  int tok0) {
  __shared__ __align__(16) _Float16 lA[128 * 64];
  __shared__ __align__(16) _Float16 lB[64 * 64];
  int t0 = blockIdx.x * 64;
  int tid = threadIdx.x;
  int lane = tid & 63;
  int wv = tid >> 6;
  f32x4 acc[2][4];
#pragma unroll
  for (int rf = 0; rf < 2; ++rf)
#pragma unroll
    for (int cf = 0; cf < 4; ++cf) acc[rf][cf] = (f32x4){0.f, 0.f, 0.f, 0.f};

  int rsel = lane & 15, q = lane >> 4;
  for (int k0 = 0; k0 < 256; k0 += 64) {
    if (k0) __syncthreads();
#pragma unroll
    for (int p = 0; p < 4; ++p) {
      int idx = tid + 256 * p;
      int row = idx >> 3, ch = idx & 7;
      int dch = ch ^ (row & 7);
      *(half8*)&lA[row * 64 + dch * 8] =
          *(const half8*)&outwh[(size_t)row * 256 + k0 + ch * 8];
    }
#pragma unroll
    for (int p = 0; p < 2; ++p) {
      int idx = tid + 256 * p;
      int row = idx >> 3, ch = idx & 7;
      int dch = ch ^ (row & 7);
      *(half8*)&lB[row * 64 + dch * 8] =
          *(const half8*)&ynh[(size_t)(t0 + row) * 256 + k0 + ch * 8];
    }
    __syncthreads();
#pragma unroll
    for (int kk = 0; kk < 2; ++kk) {
      half8 a[2];
#pragma unroll
      for (int rf = 0; rf < 2; ++rf) {
        int row = wv * 32 + rf * 16 + rsel;
        int ch = (kk * 4 + q) ^ (row & 7);
        a[rf] = *(const half8*)&lA[row * 64 + ch * 8];
      }
#pragma unroll
      for (int cf = 0; cf < 4; ++cf) {
        int row = cf * 16 + rsel;
        int ch = (kk * 4 + q) ^ (row & 7);
        half8 b = *(const half8*)&lB[row * 64 + ch * 8];
        acc[0][cf] = __builtin_amdgcn_mfma_f32_16x16x32_f16(a[0], b, acc[0][cf], 0, 0, 0);
        acc[1][cf] = __builtin_amdgcn_mfma_f32_16x16x32_f16(a[1], b, acc[1][cf], 0, 0, 0);
      }
    }
  }

  int l0 = tok0 + t0;
  int b = l0 >> 14;
  int rem0 = l0 & 16383;
#pragma unroll
  for (int rf = 0; rf < 2; ++rf) {
    int cbase = wv * 32 + rf * 16 + q * 4;
#pragma unroll
    for (int cf = 0; cf < 4; ++cf) {
#pragma unroll
      for (int r = 0; r < 4; ++r) {
        dout[(size_t)(b * 128 + cbase + r) * 16384 + rem0 + cf * 16 + rsel] = acc[rf][cf][r];
      }
    }
  }
}

extern "C" void kernel_launch(void* const* d_in, const int* in_sizes, int n_in,
                              void* d_out, int out_size, void* d_ws, size_t ws_size,
                              hipStream_t stream) {
  const void* x      = d_in[0];
  const void* dww    = d_in[1];
  const void* gng    = d_in[2];
  const void* gnb    = d_in[3];
  const void* pww    = d_in[4];
  const void* pwb    = d_in[5];
  const void* wproj  = d_in[6];
  const void* cw     = d_in[7];
  const void* cb     = d_in[8];
  const void* dtbias = d_in[9];
  const void* alog   = d_in[10];
  const void* dskip  = d_in[11];
  const void* ng     = d_in[12];
  const void* outw   = d_in[13];
  float* out = (float*)d_out;

  char* ws = (char*)d_ws;
  float* gst        = (float*)(ws + 0);
  float* mr         = (float*)(ws + 4096);
  float* P          = (float*)(ws + 8192);
  _Float16* wprojh  = (_Float16*)(ws + 40960);
  _Float16* outwh   = (_Float16*)(ws + 372736);
  float* offf       = (float*)(ws + 503808);
  char* cbase       = ws + 1028096;

  // h1 (f32, 67,108,864 B) lives in d_out's out_2d region.
  float* h1f = out;

  // Per-sequence chunk bytes:
  //   seq f16 32768 + z 131072 + xbc 196608 + dtb 4096 + ysA 131072
  //   + ysB 131072 = 626688.  (ynorm f16 reuses xbc region, dead after scan.)
  const int opts[11] = {1024, 512, 256, 128, 64, 32, 16, 8, 4, 2, 1};
  int CH = 1;
  for (int i = 0; i < 11; ++i) {
    if (1028096ull + (unsigned long long)opts[i] * 626688ull <= (unsigned long long)ws_size) {
      CH = opts[i];
      break;
    }
  }
  int NC = 1024 / CH;

  _Float16* seqh = (_Float16*)(cbase);
  float* zf      = (float*)(cbase + (size_t)CH * 32768);
  float* xbcf    = (float*)(cbase + (size_t)CH * 163840);
  float* dtbf    = (float*)(cbase + (size_t)CH * 360448);
  float* ysA     = (float*)(cbase + (size_t)CH * 364544);
  float* ysB     = (float*)(cbase + (size_t)CH * 495616);
  _Float16* ynh  = (_Float16*)xbcf;

  k_prep_params<<<1, 256, 0, stream>>>(dww, cw, cb, gng, gnb, pww, pwb, dtbias,
                                       alog, dskip, ng, P, gst);
  k_prep_w<<<128, 256, 0, stream>>>(wproj, outw, gng, wprojh, outwh);
  k_dwconv_v2<<<4096, 256, 0, stream>>>(x, gng, P, h1f, gst);
  k_stats<<<1, 64, 0, stream>>>(gst, mr);
  k_gn_off<<<1024, 128, 0, stream>>>(h1f, mr, P, offf, out);

  int M = CH * 128;
  for (int c = 0; c < NC; ++c) {
    int s0 = c * CH;
    k_deform_v2<<<CH, 256, 0, stream>>>(x, gng, offf, seqh, s0);
    k_gemm1_v3<<<dim3(M / 128, 6), 256, 0, stream>>>(seqh, wprojh, P, zf, xbcf, dtbf);
    k_scan_v7<<<dim3(CH, 2), 256, 0, stream>>>(xbcf, dtbf, P, ysA, ysB);
    k_gate_v5<<<CH * 128, 256, 0, stream>>>(ysA, ysB, zf, P, ynh);
    k_gemm2_v3<<<dim3(M / 64), 256, 0, stream>>>(ynh, outwh, out, s0 * 128);
  }
}

// Round 8
// 800.421 us; speedup vs baseline: 2.0661x; 1.0823x over previous
//
#include <hip/hip_runtime.h>
#include <math.h>

// B=8, C=128, H=128, W=128, D_INNER=256, D_STATE=64, HEADDIM=32, NHEADS=8,
// D_CONV=4, GN_GROUPS=8, D_XBC=384, D_INPROJ=648.
// Inputs f32 (probed via gn_g word0). OUTPUT IS F32 (reference output dtype).
// d_out = [out_2d: 16,777,216 f32][offset: 131,072 f32].
// h1 (f32) is staged in d_out's out_2d region.
//
// R1 scan de-spill 3236 -> R2 reg-blocked GEMMs 2123 -> R3 MFMA f16 1078 ->
// R4 dwconv v2 (scan v4 regressed) -> R5 scan v5 1268 -> R6 scan v6 LDS-tiled
// 1074 -> R7 conv1d fused into scan + deform v2 866.
// R8: (a) dwconv v3: 128x32 tiles, coalesced float4 staging (1152 vec loads vs
// 4624 branchy scalar + /68), pre-zeroed halo cols; (b) gn_off v2: 256 thr,
// c split 2-way + LDS combine; (c) ys partials f16; (d) z f16.

typedef _Float16 half8 __attribute__((ext_vector_type(8)));
typedef float f32x4 __attribute__((ext_vector_type(4)));

__device__ __forceinline__ float b2f(unsigned short u) {
  return __uint_as_float(((unsigned int)u) << 16);
}
__device__ __forceinline__ bool in_is_f32(const void* gng) {
  return ((const unsigned int*)gng)[0] == 0x3F800000u;
}

#define P_DWW 0
#define P_CW 3200
#define P_CB 4736
#define P_GNG 5120
#define P_GNB 5248
#define P_PWW 5376
#define P_PWB 5504
#define P_DTB 5505
#define P_ALOG 5513
#define P_DSKIP 5521
#define P_NG 5529

__global__ void k_prep_params(const void* dww, const void* cw, const void* cb,
                              const void* gng, const void* gnb, const void* pww,
                              const void* pwb, const void* dtbias, const void* alog,
                              const void* dskip, const void* ng, float* __restrict__ P,
                              float* __restrict__ gst) {
  bool f = in_is_f32(gng);
  int tid = threadIdx.x;
  if (tid < 128) gst[tid] = 0.f;
  auto cvt = [&](const void* src, int n, int off) {
    for (int i = tid; i < n; i += 256)
      P[off + i] = f ? ((const float*)src)[i] : b2f(((const unsigned short*)src)[i]);
  };
  cvt(dww, 3200, P_DWW);
  cvt(cw, 1536, P_CW);
  cvt(cb, 384, P_CB);
  cvt(gng, 128, P_GNG);
  cvt(gnb, 128, P_GNB);
  cvt(pww, 128, P_PWW);
  cvt(pwb, 1, P_PWB);
  cvt(dtbias, 8, P_DTB);
  cvt(alog, 8, P_ALOG);
  cvt(dskip, 8, P_DSKIP);
  cvt(ng, 256, P_NG);
}

// wprojh: 768 x 128 f16 (rows >=648 zero).  outwh: 128 x 256 f16.
__global__ void k_prep_w(const void* wproj, const void* outw, const void* gng,
                         _Float16* __restrict__ wprojh, _Float16* __restrict__ outwh) {
  bool f = in_is_f32(gng);
  int stride = gridDim.x * blockDim.x;
  for (int i = blockIdx.x * blockDim.x + threadIdx.x; i < 98304; i += stride) {
    int row = i >> 7;
    float v = 0.f;
    if (row < 648) v = f ? ((const float*)wproj)[i] : b2f(((const unsigned short*)wproj)[i]);
    wprojh[i] = (_Float16)v;
  }
  for (int i = blockIdx.x * blockDim.x + threadIdx.x; i < 32768; i += stride)
    outwh[i] = (_Float16)(f ? ((const float*)outw)[i] : b2f(((const unsigned short*)outw)[i]));
}

// ---------------- K1 v3: depthwise 5x5 conv + group stats -----------------------
// 4 blocks per (b,c): 128w x 32h output tile. LDS halo tile 36 rows x 132 cols
// (data at cols 2..129, edge cols pre-zeroed). Staging: 1152 coalesced float4
// global loads -> 2x ds_write_b64 each (col-2 shift). Compute: 4x4 out/thread,
// 2 aligned b128 LDS reads per input row.
__global__ __launch_bounds__(256) void k_dwconv_v3(const void* __restrict__ x,
                                                   const void* __restrict__ gng,
                                                   const float* __restrict__ P,
                                                   float* __restrict__ h1,
                                                   float* __restrict__ gst) {
  int blk = blockIdx.x;
  int bc = blk >> 2, sub = blk & 3;
  int b = bc >> 7, c = bc & 127;
  int ty0 = sub * 32;
  bool f32x = in_is_f32(gng);
  __shared__ __align__(16) float t[36 * 132];
  __shared__ float red[8];
  const float* xf = (const float*)x + (size_t)bc * 16384;
  const unsigned short* xb = (const unsigned short*)x + (size_t)bc * 16384;
  // zero edge columns {0,1,130,131}
  for (int i = threadIdx.x; i < 144; i += 256) {
    int r = i >> 2, e = i & 3;
    t[r * 132 + (e < 2 ? e : 128 + e)] = 0.f;
  }
  // stage 36 rows x 128 cols
  for (int i = threadIdx.x; i < 1152; i += 256) {
    int r = i >> 5, cq = i & 31;
    int gy = ty0 + r - 2;
    float4 v = make_float4(0.f, 0.f, 0.f, 0.f);
    if (gy >= 0 && gy < 128) {
      if (f32x) {
        v = *(const float4*)(xf + gy * 128 + cq * 4);
      } else {
        ushort4 u = *(const ushort4*)(xb + gy * 128 + cq * 4);
        v = make_float4(b2f(u.x), b2f(u.y), b2f(u.z), b2f(u.w));
      }
    }
    *(float2*)&t[r * 132 + 2 + cq * 4] = make_float2(v.x, v.y);
    *(float2*)&t[r * 132 + 4 + cq * 4] = make_float2(v.z, v.w);
  }
  float w[25];
#pragma unroll
  for (int k = 0; k < 25; ++k) w[k] = P[P_DWW + c * 25 + k];
  __syncthreads();

  int ox = (threadIdx.x & 31) * 4;
  int oy = (threadIdx.x >> 5) * 4;
  float acc[4][4];
#pragma unroll
  for (int r = 0; r < 4; ++r)
#pragma unroll
    for (int j = 0; j < 4; ++j) acc[r][j] = 0.f;

#pragma unroll
  for (int i = 0; i < 8; ++i) {
    float4 p0 = *(const float4*)&t[(oy + i) * 132 + ox];
    float4 p1 = *(const float4*)&t[(oy + i) * 132 + ox + 4];
    float in8[8] = {p0.x, p0.y, p0.z, p0.w, p1.x, p1.y, p1.z, p1.w};
#pragma unroll
    for (int r = 0; r < 4; ++r) {
      if (i - r >= 0 && i - r <= 4) {
        int ky = i - r;
#pragma unroll
        for (int j = 0; j < 4; ++j)
#pragma unroll
          for (int kx = 0; kx < 5; ++kx)
            acc[r][j] += w[ky * 5 + kx] * in8[j + kx];
      }
    }
  }

  float s = 0.f, sq = 0.f;
  float* hp = h1 + (size_t)bc * 16384;
#pragma unroll
  for (int r = 0; r < 4; ++r) {
    *(float4*)&hp[(ty0 + oy + r) * 128 + ox] =
        make_float4(acc[r][0], acc[r][1], acc[r][2], acc[r][3]);
#pragma unroll
    for (int j = 0; j < 4; ++j) { s += acc[r][j]; sq += acc[r][j] * acc[r][j]; }
  }
  for (int o = 32; o; o >>= 1) { s += __shfl_down(s, o, 64); sq += __shfl_down(sq, o, 64); }
  int wv = threadIdx.x >> 6;
  if ((threadIdx.x & 63) == 0) { red[wv] = s; red[4 + wv] = sq; }
  __syncthreads();
  if (threadIdx.x == 0) {
    float ts = red[0] + red[1] + red[2] + red[3];
    float tq = red[4] + red[5] + red[6] + red[7];
    int g = (b << 3) + (c >> 4);
    atomicAdd(&gst[g * 2], ts);
    atomicAdd(&gst[g * 2 + 1], tq);
  }
}

__global__ void k_stats(const float* __restrict__ gst, float* __restrict__ mr) {
  int g = threadIdx.x;
  if (g < 64) {
    const float invN = 1.f / 262144.f;
    float mean = gst[g * 2] * invN;
    float var = gst[g * 2 + 1] * invN - mean * mean;
    mr[g * 2] = mean;
    mr[g * 2 + 1] = rsqrtf(var + 1e-5f);
  }
}

// ---------------- K3 v2: GN + GELU + 1x1 conv + tanh*8 -> offset ----------------
// 256 threads: c split 2-way (halves serial chain), LDS combine.
__global__ __launch_bounds__(256) void k_gn_off_v2(const float* __restrict__ h1,
                                                   const float* __restrict__ mr,
                                                   const float* __restrict__ P,
                                                   float* __restrict__ offf,
                                                   float* __restrict__ dout) {
  int bh = blockIdx.x;
  int b = bh >> 7, h = bh & 127;
  int tid = threadIdx.x;
  int w = tid & 127;
  int chh = tid >> 7;
  __shared__ float sacc[2][128];
  float acc = 0.f;
  for (int ci = 0; ci < 64; ++ci) {
    int c = chh * 64 + ci;
    float v = h1[(((size_t)(b * 128 + c)) * 128 + h) * 128 + w];
    int g = b * 8 + (c >> 4);
    float nv = (v - mr[g * 2]) * mr[g * 2 + 1] * P[P_GNG + c] + P[P_GNB + c];
    float ge = 0.5f * nv * (1.f + erff(nv * 0.70710678118f));
    acc += ge * P[P_PWW + c];
  }
  sacc[chh][w] = acc;
  __syncthreads();
  if (chh == 0) {
    float off = acc + sacc[1][w] + P[P_PWB];
    float ofv = tanhf(off) * 8.0f;
    offf[bh * 128 + w] = ofv;
    dout[16777216 + bh * 128 + w] = ofv;
  }
}

// ---------------- K4 v2: y-only grid sample + transpose -> seq f16 (l,c) --------
__global__ __launch_bounds__(256) void k_deform_v2(const void* __restrict__ x,
                                                   const void* __restrict__ gng,
                                                   const float* __restrict__ offf,
                                                   _Float16* __restrict__ seqc,
                                                   int s0) {
  int bh = s0 + blockIdx.x;
  int b = bh >> 7, h = bh & 127;
  int tid = threadIdx.x;
  int w = tid & 127;
  int half = tid >> 7;
  bool f32x = in_is_f32(gng);
  __shared__ float t[128 * 130];
  float ofv = offf[bh * 128 + w];
  float gy = -1.f + (2.f / 127.f) * (float)h + ofv * (2.f / 127.f);
  gy = fminf(fmaxf(gy, -1.f), 1.f);
  float py = (gy + 1.f) * 0.5f * 127.f;
  py = fminf(fmaxf(py, 0.f), 127.f);
  float y0f = floorf(py);
  float wy = py - y0f;
  int y0 = (int)y0f;
  int y1 = min(y0 + 1, 127);
  const float* xfb = (const float*)x + (size_t)b * 128 * 16384;
  const unsigned short* xbb = (const unsigned short*)x + (size_t)b * 128 * 16384;
  int c0 = half * 64;
  for (int i = 0; i < 64; ++i) {
    int c = c0 + i;
    size_t o0 = (size_t)c * 16384 + y0 * 128 + w;
    size_t o1 = (size_t)c * 16384 + y1 * 128 + w;
    float v0, v1;
    if (f32x) { v0 = xfb[o0]; v1 = xfb[o1]; }
    else      { v0 = b2f(xbb[o0]); v1 = b2f(xbb[o1]); }
    t[c * 130 + w] = v0 + wy * (v1 - v0);
  }
  __syncthreads();
  int c2 = tid & 127;
  int lb = (tid >> 7) * 64;
  _Float16* sp = seqc + (size_t)blockIdx.x * 16384;
  for (int i = 0; i < 64; ++i) {
    int l = lb + i;
    sp[l * 128 + c2] = (_Float16)t[c2 * 130 + l];
  }
}

// ---------------- G1 v4: zxbcdt = seq @ wproj^T via MFMA f16; z out f16 ---------
__global__ __launch_bounds__(256) void k_gemm1_v4(const _Float16* __restrict__ seqh,
                                                  const _Float16* __restrict__ wprojh,
                                                  const float* __restrict__ P,
                                                  _Float16* __restrict__ zh,
                                                  float* __restrict__ xbc,
                                                  float* __restrict__ dtb) {
  __shared__ __align__(16) _Float16 lA[128 * 64];
  __shared__ __align__(16) _Float16 lB[128 * 64];
  int m0 = blockIdx.x * 128;
  int e0 = blockIdx.y * 128;
  int tid = threadIdx.x;
  int lane = tid & 63;
  int wv = tid >> 6;
  f32x4 acc[2][8];
#pragma unroll
  for (int rf = 0; rf < 2; ++rf)
#pragma unroll
    for (int cf = 0; cf < 8; ++cf) acc[rf][cf] = (f32x4){0.f, 0.f, 0.f, 0.f};

  int rsel = lane & 15, q = lane >> 4;
  for (int k0 = 0; k0 < 128; k0 += 64) {
    if (k0) __syncthreads();
#pragma unroll
    for (int p = 0; p < 4; ++p) {
      int idx = tid + 256 * p;
      int row = idx >> 3, ch = idx & 7;
      int dch = ch ^ (row & 7);
      *(half8*)&lA[row * 64 + dch * 8] =
          *(const half8*)&seqh[(size_t)(m0 + row) * 128 + k0 + ch * 8];
      *(half8*)&lB[row * 64 + dch * 8] =
          *(const half8*)&wprojh[(size_t)(e0 + row) * 128 + k0 + ch * 8];
    }
    __syncthreads();
#pragma unroll
    for (int kk = 0; kk < 2; ++kk) {
      half8 a[2];
#pragma unroll
      for (int rf = 0; rf < 2; ++rf) {
        int row = wv * 32 + rf * 16 + rsel;
        int ch = (kk * 4 + q) ^ (row & 7);
        a[rf] = *(const half8*)&lA[row * 64 + ch * 8];
      }
#pragma unroll
      for (int cf = 0; cf < 8; ++cf) {
        int row = cf * 16 + rsel;
        int ch = (kk * 4 + q) ^ (row & 7);
        half8 b = *(const half8*)&lB[row * 64 + ch * 8];
        acc[0][cf] = __builtin_amdgcn_mfma_f32_16x16x32_f16(a[0], b, acc[0][cf], 0, 0, 0);
        acc[1][cf] = __builtin_amdgcn_mfma_f32_16x16x32_f16(a[1], b, acc[1][cf], 0, 0, 0);
      }
    }
  }

#pragma unroll
  for (int rf = 0; rf < 2; ++rf) {
    int mb = m0 + wv * 32 + rf * 16 + q * 4;
    if (e0 < 256) {
#pragma unroll
      for (int cf = 0; cf < 8; ++cf) {
        _Float16* pz = zh + (size_t)mb * 256 + e0 + cf * 16 + rsel;
#pragma unroll
        for (int r = 0; r < 4; ++r) pz[(size_t)r * 256] = (_Float16)acc[rf][cf][r];
      }
    } else if (e0 < 640) {
#pragma unroll
      for (int cf = 0; cf < 8; ++cf) {
        float* px = xbc + (size_t)mb * 384 + (e0 - 256) + cf * 16 + rsel;
#pragma unroll
        for (int r = 0; r < 4; ++r) px[(size_t)r * 384] = acc[rf][cf][r];
      }
    } else {
      if (rsel < 8) {
        float bias = P[P_DTB + rsel];
#pragma unroll
        for (int r = 0; r < 4; ++r) {
          float dv = acc[rf][0][r] + bias;
          float sp = (dv > 20.f) ? dv : log1pf(__expf(dv));
          dtb[(size_t)(mb + r) * 8 + rsel] = sp;
        }
      }
    }
  }
}

// ---------------- K6 v7b: scan + fused conv1d; f16 partial outputs ---------------
__global__ __launch_bounds__(256) void k_scan_v7(const float* __restrict__ xbc,
                                                 const float* __restrict__ dtb,
                                                 const float* __restrict__ P,
                                                 _Float16* __restrict__ ysA,
                                                 _Float16* __restrict__ ysB) {
  int seq = blockIdx.x;
  int sblk = blockIdx.y;          // 0: states 0..31, 1: states 32..63
  int tid = threadIdx.x;
  int head = tid >> 5;            // 0..7
  float A = -__expf(P[P_ALOG + head]);
  float Dk = P[P_DSKIP + head];
  // x-path conv weights (e = tid, 0..255)
  float wx0 = P[P_CW + tid * 4 + 0], wx1 = P[P_CW + tid * 4 + 1];
  float wx2 = P[P_CW + tid * 4 + 2], wx3 = P[P_CW + tid * 4 + 3];
  float cbx = P[P_CB + tid];
  float h[32];
#pragma unroll
  for (int s = 0; s < 32; ++s) h[s] = 0.f;

  __shared__ __align__(16) float sBC[2][16][64];  // [step][0..31]=B, [32..63]=C
  __shared__ float sdt[2][128];                   // [step*8+head]

  const float* base = xbc + (size_t)seq * 49152;
  const float* dtp = dtb + (size_t)seq * 1024;
  _Float16* yp = (sblk ? ysB : ysA) + (size_t)seq * 32768;

  int st = tid >> 4;              // 0..15 staging step
  int q = tid & 15;               // 0..15 staging quad
  int colbase = (q < 8) ? (256 + sblk * 32 + q * 4)
                        : (320 + sblk * 32 + (q - 8) * 4);
  int ldst = (q < 8) ? q * 4 : 32 + (q - 8) * 4;
  // B/C conv weights for this thread's 4 columns
  float cwt[4][4], cbv[4];
#pragma unroll
  for (int j = 0; j < 4; ++j) {
#pragma unroll
    for (int k = 0; k < 4; ++k) cwt[j][k] = P[P_CW + (colbase + j) * 4 + k];
    cbv[j] = P[P_CB + colbase + j];
  }

  auto conv4 = [&](int row) -> float4 {
    float4 r0 = *(const float4*)(base + (size_t)row * 384 + colbase);
    float4 r1 = make_float4(0.f, 0.f, 0.f, 0.f);
    float4 r2 = r1, r3 = r1;
    if (row >= 1) r1 = *(const float4*)(base + (size_t)(row - 1) * 384 + colbase);
    if (row >= 2) r2 = *(const float4*)(base + (size_t)(row - 2) * 384 + colbase);
    if (row >= 3) r3 = *(const float4*)(base + (size_t)(row - 3) * 384 + colbase);
    float4 o;
    o.x = cbv[0] + cwt[0][3] * r0.x + cwt[0][2] * r1.x + cwt[0][1] * r2.x + cwt[0][0] * r3.x;
    o.y = cbv[1] + cwt[1][3] * r0.y + cwt[1][2] * r1.y + cwt[1][1] * r2.y + cwt[1][0] * r3.y;
    o.z = cbv[2] + cwt[2][3] * r0.z + cwt[2][2] * r1.z + cwt[2][1] * r2.z + cwt[2][0] * r3.z;
    o.w = cbv[3] + cwt[3][3] * r0.w + cwt[3][2] * r1.w + cwt[3][1] * r2.w + cwt[3][0] * r3.w;
    o.x = o.x / (1.f + __expf(-o.x));
    o.y = o.y / (1.f + __expf(-o.y));
    o.z = o.z / (1.f + __expf(-o.z));
    o.w = o.w / (1.f + __expf(-o.w));
    return o;
  };

  // prologue: stage tile 0 into buf0 (conv applied)
  {
    float4 rv = conv4(st);
    float rdt = (tid < 128) ? dtp[tid] : 0.f;
    *(float4*)&sBC[0][st][ldst] = rv;
    if (tid < 128) sdt[0][tid] = rdt;
  }
  __syncthreads();

  float x0 = 0.f, x1 = 0.f, x2 = 0.f;   // rolling raw-x window for e=tid
  for (int t = 0; t < 8; ++t) {
    int buf = t & 1;
    int l0 = t * 16;
    float xr[16];
#pragma unroll
    for (int s = 0; s < 16; ++s) xr[s] = base[(size_t)(l0 + s) * 384 + tid];
    float4 rv;
    float rdt = 0.f;
    if (t < 7) {
      rv = conv4(l0 + 16 + st);
      if (tid < 128) rdt = dtp[(l0 + 16) * 8 + tid];
    }
#pragma unroll
    for (int s = 0; s < 16; ++s) {
      float a = cbx + wx0 * x0 + wx1 * x1 + wx2 * x2 + wx3 * xr[s];
      float xv = a / (1.f + __expf(-a));
      x0 = x1; x1 = x2; x2 = xr[s];
      float dt = sdt[buf][s * 8 + head];
      float dA = __expf(dt * A);
      float coef = dt * xv;
      float a0 = 0.f, a1 = 0.f, a2 = 0.f, a3 = 0.f;
#pragma unroll
      for (int qq = 0; qq < 8; ++qq) {
        float4 bq = *(const float4*)&sBC[buf][s][qq * 4];
        float4 cq = *(const float4*)&sBC[buf][s][32 + qq * 4];
        h[qq * 4 + 0] = h[qq * 4 + 0] * dA + coef * bq.x;  a0 += h[qq * 4 + 0] * cq.x;
        h[qq * 4 + 1] = h[qq * 4 + 1] * dA + coef * bq.y;  a1 += h[qq * 4 + 1] * cq.y;
        h[qq * 4 + 2] = h[qq * 4 + 2] * dA + coef * bq.z;  a2 += h[qq * 4 + 2] * cq.z;
        h[qq * 4 + 3] = h[qq * 4 + 3] * dA + coef * bq.w;  a3 += h[qq * 4 + 3] * cq.w;
      }
      float res = (a0 + a1) + (a2 + a3);
      if (sblk == 0) res += Dk * xv;
      yp[(size_t)(l0 + s) * 256 + tid] = (_Float16)res;
    }
    if (t < 7) {
      *(float4*)&sBC[buf ^ 1][st][ldst] = rv;
      if (tid < 128) sdt[buf ^ 1][tid] = rdt;
    }
    __syncthreads();
  }
}

// ---------------- K7 v6: gate + RMS norm -> ynorm f16 (f16 inputs) ---------------
__global__ __launch_bounds__(256) void k_gate_v6(const _Float16* __restrict__ ysA,
                                                 const _Float16* __restrict__ ysB,
                                                 const _Float16* __restrict__ zh,
                                                 const float* __restrict__ P,
                                                 _Float16* __restrict__ ynh) {
  int l = blockIdx.x;
  int e = threadIdx.x;
  __shared__ float red[4];
  size_t idx = (size_t)l * 256 + e;
  float yv = (float)ysA[idx] + (float)ysB[idx];
  float zv = (float)zh[idx];
  float g = zv / (1.f + __expf(-zv));
  float y = yv * g;
  float ss = y * y;
  for (int o = 32; o; o >>= 1) ss += __shfl_down(ss, o, 64);
  if ((threadIdx.x & 63) == 0) red[threadIdx.x >> 6] = ss;
  __syncthreads();
  float tot = red[0] + red[1] + red[2] + red[3];
  float r = rsqrtf(tot * (1.f / 256.f) + 1e-5f);
  ynh[idx] = (_Float16)(y * r * P[P_NG + e]);
}

// ---------------- G2 v3: out = ynorm @ outw^T via MFMA f16 ----------------------
__global__ __launch_bounds__(256) void k_gemm2_v3(const _Float16* __restrict__ ynh,
                                                  const _Float16* __restrict__ outwh,
                                                  float* __restrict__ dout,
                                                  int tok0) {
  __shared__ __align__(16) _Float16 lA[128 * 64];
  __shared__ __align__(16) _Float16 lB[64 * 64];
  int t0 = blockIdx.x * 64;
  int tid = threadIdx.x;
  int lane = tid & 63;
  int wv = tid >> 6;
  f32x4 acc[2][4];
#pragma unroll
  for (int rf = 0; rf < 2; ++rf)
#pragma unroll
    for (int cf = 0; cf < 4; ++cf) acc[rf][cf] = (f32x4){0.f, 0.f, 0.f, 0.f};

  int rsel = lane & 15, q = lane >> 4;
  for (int k0 = 0; k0 < 256; k0 += 64) {
    if (k0) __syncthreads();
#pragma unroll
    for (int p = 0; p < 4; ++p) {
      int idx = tid + 256 * p;
      int row = idx >> 3, ch = idx & 7;
      int dch = ch ^ (row & 7);
      *(half8*)&lA[row * 64 + dch * 8] =
          *(const half8*)&outwh[(size_t)row * 256 + k0 + ch * 8];
    }
#pragma unroll
    for (int p = 0; p < 2; ++p) {
      int idx = tid + 256 * p;
      int row = idx >> 3, ch = idx & 7;
      int dch = ch ^ (row & 7);
      *(half8*)&lB[row * 64 + dch * 8] =
          *(const half8*)&ynh[(size_t)(t0 + row) * 256 + k0 + ch * 8];
    }
    __syncthreads();
#pragma unroll
    for (int kk = 0; kk < 2; ++kk) {
      half8 a[2];
#pragma unroll
      for (int rf = 0; rf < 2; ++rf) {
        int row = wv * 32 + rf * 16 + rsel;
        int ch = (kk * 4 + q) ^ (row & 7);
        a[rf] = *(const half8*)&lA[row * 64 + ch * 8];
      }
#pragma unroll
      for (int cf = 0; cf < 4; ++cf) {
        int row = cf * 16 + rsel;
        int ch = (kk * 4 + q) ^ (row & 7);
        half8 b = *(const half8*)&lB[row * 64 + ch * 8];
        acc[0][cf] = __builtin_amdgcn_mfma_f32_16x16x32_f16(a[0], b, acc[0][cf], 0, 0, 0);
        acc[1][cf] = __builtin_amdgcn_mfma_f32_16x16x32_f16(a[1], b, acc[1][cf], 0, 0, 0);
      }
    }
  }

  int l0 = tok0 + t0;
  int b = l0 >> 14;
  int rem0 = l0 & 16383;
#pragma unroll
  for (int rf = 0; rf < 2; ++rf) {
    int cbase = wv * 32 + rf * 16 + q * 4;
#pragma unroll
    for (int cf = 0; cf < 4; ++cf) {
#pragma unroll
      for (int r = 0; r < 4; ++r) {
        dout[(size_t)(b * 128 + cbase + r) * 16384 + rem0 + cf * 16 + rsel] = acc[rf][cf][r];
      }
    }
  }
}

extern "C" void kernel_launch(void* const* d_in, const int* in_sizes, int n_in,
                              void* d_out, int out_size, void* d_ws, size_t ws_size,
                              hipStream_t stream) {
  const void* x      = d_in[0];
  const void* dww    = d_in[1];
  const void* gng    = d_in[2];
  const void* gnb    = d_in[3];
  const void* pww    = d_in[4];
  const void* pwb    = d_in[5];
  const void* wproj  = d_in[6];
  const void* cw     = d_in[7];
  const void* cb     = d_in[8];
  const void* dtbias = d_in[9];
  const void* alog   = d_in[10];
  const void* dskip  = d_in[11];
  const void* ng     = d_in[12];
  const void* outw   = d_in[13];
  float* out = (float*)d_out;

  char* ws = (char*)d_ws;
  float* gst        = (float*)(ws + 0);
  float* mr         = (float*)(ws + 4096);
  float* P          = (float*)(ws + 8192);
  _Float16* wprojh  = (_Float16*)(ws + 40960);
  _Float16* outwh   = (_Float16*)(ws + 372736);
  float* offf       = (float*)(ws + 503808);
  char* cbase       = ws + 1028096;

  // h1 (f32, 67,108,864 B) lives in d_out's out_2d region.
  float* h1f = out;

  // Per-sequence chunk bytes:
  //   seq f16 32768 + zh f16 65536 + xbc 196608 + dtb 4096 + ysA f16 65536
  //   + ysB f16 65536 = 430080.  (ynorm f16 reuses xbc region, dead after scan.)
  const int opts[11] = {1024, 512, 256, 128, 64, 32, 16, 8, 4, 2, 1};
  int CH = 1;
  for (int i = 0; i < 11; ++i) {
    if (1028096ull + (unsigned long long)opts[i] * 430080ull <= (unsigned long long)ws_size) {
      CH = opts[i];
      break;
    }
  }
  int NC = 1024 / CH;

  _Float16* seqh = (_Float16*)(cbase);
  _Float16* zh   = (_Float16*)(cbase + (size_t)CH * 32768);
  float* xbcf    = (float*)(cbase + (size_t)CH * 98304);
  float* dtbf    = (float*)(cbase + (size_t)CH * 294912);
  _Float16* ysA  = (_Float16*)(cbase + (size_t)CH * 299008);
  _Float16* ysB  = (_Float16*)(cbase + (size_t)CH * 364544);
  _Float16* ynh  = (_Float16*)xbcf;

  k_prep_params<<<1, 256, 0, stream>>>(dww, cw, cb, gng, gnb, pww, pwb, dtbias,
                                       alog, dskip, ng, P, gst);
  k_prep_w<<<128, 256, 0, stream>>>(wproj, outw, gng, wprojh, outwh);
  k_dwconv_v3<<<4096, 256, 0, stream>>>(x, gng, P, h1f, gst);
  k_stats<<<1, 64, 0, stream>>>(gst, mr);
  k_gn_off_v2<<<1024, 256, 0, stream>>>(h1f, mr, P, offf, out);

  int M = CH * 128;
  for (int c = 0; c < NC; ++c) {
    int s0 = c * CH;
    k_deform_v2<<<CH, 256, 0, stream>>>(x, gng, offf, seqh, s0);
    k_gemm1_v4<<<dim3(M / 128, 6), 256, 0, stream>>>(seqh, wprojh, P, zh, xbcf, dtbf);
    k_scan_v7<<<dim3(CH, 2), 256, 0, stream>>>(xbcf, dtbf, P, ysA, ysB);
    k_gate_v6<<<CH * 128, 256, 0, stream>>>(ysA, ysB, zh, P, ynh);
    k_gemm2_v3<<<dim3(M / 64), 256, 0, stream>>>(ynh, outwh, out, s0 * 128);
  }
}

// Round 9
// 778.302 us; speedup vs baseline: 2.1249x; 1.0284x over previous
//
#include <hip/hip_runtime.h>
#include <math.h>

// B=8, C=128, H=128, W=128, D_INNER=256, D_STATE=64, HEADDIM=32, NHEADS=8,
// D_CONV=4, GN_GROUPS=8, D_XBC=384, D_INPROJ=648.
// Inputs f32 (probed via gn_g word0). OUTPUT IS F32 (reference output dtype).
// d_out = [out_2d: 16,777,216 f32][offset: 131,072 f32].
// h1 (f32) is staged in d_out's out_2d region.
//
// R1 scan de-spill 3236 -> R2 reg-blocked GEMMs 2123 -> R3 MFMA f16 1078 ->
// R4 dwconv v2 -> R5 scan v5 1268 -> R6 scan v6 LDS-tiled 1074 -> R7 conv1d
// fused + deform v2 866 -> R8 dwconv v3 + gn_off v2 + f16 ys/z 800.
// R9: scan v8 - 2 d-values per thread (128 thr, h=float2[32]). One broadcast
// B/C ds_read_b128 now feeds TWO d-lanes (LDS insts/work halved; scan was
// LDS-issue-bound: 4 waves x 16 uniform b128 reads/step = 192cyc vs 96 VALU
// ops), and the float2 inner loop maps to v_pk_fma_f32 (VALU halved).

typedef _Float16 half8 __attribute__((ext_vector_type(8)));
typedef float f32x4 __attribute__((ext_vector_type(4)));
typedef float f32x2 __attribute__((ext_vector_type(2)));

__device__ __forceinline__ float b2f(unsigned short u) {
  return __uint_as_float(((unsigned int)u) << 16);
}
__device__ __forceinline__ bool in_is_f32(const void* gng) {
  return ((const unsigned int*)gng)[0] == 0x3F800000u;
}

#define P_DWW 0
#define P_CW 3200
#define P_CB 4736
#define P_GNG 5120
#define P_GNB 5248
#define P_PWW 5376
#define P_PWB 5504
#define P_DTB 5505
#define P_ALOG 5513
#define P_DSKIP 5521
#define P_NG 5529

__global__ void k_prep_params(const void* dww, const void* cw, const void* cb,
                              const void* gng, const void* gnb, const void* pww,
                              const void* pwb, const void* dtbias, const void* alog,
                              const void* dskip, const void* ng, float* __restrict__ P,
                              float* __restrict__ gst) {
  bool f = in_is_f32(gng);
  int tid = threadIdx.x;
  if (tid < 128) gst[tid] = 0.f;
  auto cvt = [&](const void* src, int n, int off) {
    for (int i = tid; i < n; i += 256)
      P[off + i] = f ? ((const float*)src)[i] : b2f(((const unsigned short*)src)[i]);
  };
  cvt(dww, 3200, P_DWW);
  cvt(cw, 1536, P_CW);
  cvt(cb, 384, P_CB);
  cvt(gng, 128, P_GNG);
  cvt(gnb, 128, P_GNB);
  cvt(pww, 128, P_PWW);
  cvt(pwb, 1, P_PWB);
  cvt(dtbias, 8, P_DTB);
  cvt(alog, 8, P_ALOG);
  cvt(dskip, 8, P_DSKIP);
  cvt(ng, 256, P_NG);
}

// wprojh: 768 x 128 f16 (rows >=648 zero).  outwh: 128 x 256 f16.
__global__ void k_prep_w(const void* wproj, const void* outw, const void* gng,
                         _Float16* __restrict__ wprojh, _Float16* __restrict__ outwh) {
  bool f = in_is_f32(gng);
  int stride = gridDim.x * blockDim.x;
  for (int i = blockIdx.x * blockDim.x + threadIdx.x; i < 98304; i += stride) {
    int row = i >> 7;
    float v = 0.f;
    if (row < 648) v = f ? ((const float*)wproj)[i] : b2f(((const unsigned short*)wproj)[i]);
    wprojh[i] = (_Float16)v;
  }
  for (int i = blockIdx.x * blockDim.x + threadIdx.x; i < 32768; i += stride)
    outwh[i] = (_Float16)(f ? ((const float*)outw)[i] : b2f(((const unsigned short*)outw)[i]));
}

// ---------------- K1 v3: depthwise 5x5 conv + group stats -----------------------
__global__ __launch_bounds__(256) void k_dwconv_v3(const void* __restrict__ x,
                                                   const void* __restrict__ gng,
                                                   const float* __restrict__ P,
                                                   float* __restrict__ h1,
                                                   float* __restrict__ gst) {
  int blk = blockIdx.x;
  int bc = blk >> 2, sub = blk & 3;
  int b = bc >> 7, c = bc & 127;
  int ty0 = sub * 32;
  bool f32x = in_is_f32(gng);
  __shared__ __align__(16) float t[36 * 132];
  __shared__ float red[8];
  const float* xf = (const float*)x + (size_t)bc * 16384;
  const unsigned short* xb = (const unsigned short*)x + (size_t)bc * 16384;
  for (int i = threadIdx.x; i < 144; i += 256) {
    int r = i >> 2, e = i & 3;
    t[r * 132 + (e < 2 ? e : 128 + e)] = 0.f;
  }
  for (int i = threadIdx.x; i < 1152; i += 256) {
    int r = i >> 5, cq = i & 31;
    int gy = ty0 + r - 2;
    float4 v = make_float4(0.f, 0.f, 0.f, 0.f);
    if (gy >= 0 && gy < 128) {
      if (f32x) {
        v = *(const float4*)(xf + gy * 128 + cq * 4);
      } else {
        ushort4 u = *(const ushort4*)(xb + gy * 128 + cq * 4);
        v = make_float4(b2f(u.x), b2f(u.y), b2f(u.z), b2f(u.w));
      }
    }
    *(float2*)&t[r * 132 + 2 + cq * 4] = make_float2(v.x, v.y);
    *(float2*)&t[r * 132 + 4 + cq * 4] = make_float2(v.z, v.w);
  }
  float w[25];
#pragma unroll
  for (int k = 0; k < 25; ++k) w[k] = P[P_DWW + c * 25 + k];
  __syncthreads();

  int ox = (threadIdx.x & 31) * 4;
  int oy = (threadIdx.x >> 5) * 4;
  float acc[4][4];
#pragma unroll
  for (int r = 0; r < 4; ++r)
#pragma unroll
    for (int j = 0; j < 4; ++j) acc[r][j] = 0.f;

#pragma unroll
  for (int i = 0; i < 8; ++i) {
    float4 p0 = *(const float4*)&t[(oy + i) * 132 + ox];
    float4 p1 = *(const float4*)&t[(oy + i) * 132 + ox + 4];
    float in8[8] = {p0.x, p0.y, p0.z, p0.w, p1.x, p1.y, p1.z, p1.w};
#pragma unroll
    for (int r = 0; r < 4; ++r) {
      if (i - r >= 0 && i - r <= 4) {
        int ky = i - r;
#pragma unroll
        for (int j = 0; j < 4; ++j)
#pragma unroll
          for (int kx = 0; kx < 5; ++kx)
            acc[r][j] += w[ky * 5 + kx] * in8[j + kx];
      }
    }
  }

  float s = 0.f, sq = 0.f;
  float* hp = h1 + (size_t)bc * 16384;
#pragma unroll
  for (int r = 0; r < 4; ++r) {
    *(float4*)&hp[(ty0 + oy + r) * 128 + ox] =
        make_float4(acc[r][0], acc[r][1], acc[r][2], acc[r][3]);
#pragma unroll
    for (int j = 0; j < 4; ++j) { s += acc[r][j]; sq += acc[r][j] * acc[r][j]; }
  }
  for (int o = 32; o; o >>= 1) { s += __shfl_down(s, o, 64); sq += __shfl_down(sq, o, 64); }
  int wv = threadIdx.x >> 6;
  if ((threadIdx.x & 63) == 0) { red[wv] = s; red[4 + wv] = sq; }
  __syncthreads();
  if (threadIdx.x == 0) {
    float ts = red[0] + red[1] + red[2] + red[3];
    float tq = red[4] + red[5] + red[6] + red[7];
    int g = (b << 3) + (c >> 4);
    atomicAdd(&gst[g * 2], ts);
    atomicAdd(&gst[g * 2 + 1], tq);
  }
}

__global__ void k_stats(const float* __restrict__ gst, float* __restrict__ mr) {
  int g = threadIdx.x;
  if (g < 64) {
    const float invN = 1.f / 262144.f;
    float mean = gst[g * 2] * invN;
    float var = gst[g * 2 + 1] * invN - mean * mean;
    mr[g * 2] = mean;
    mr[g * 2 + 1] = rsqrtf(var + 1e-5f);
  }
}

// ---------------- K3 v2: GN + GELU + 1x1 conv + tanh*8 -> offset ----------------
__global__ __launch_bounds__(256) void k_gn_off_v2(const float* __restrict__ h1,
                                                   const float* __restrict__ mr,
                                                   const float* __restrict__ P,
                                                   float* __restrict__ offf,
                                                   float* __restrict__ dout) {
  int bh = blockIdx.x;
  int b = bh >> 7, h = bh & 127;
  int tid = threadIdx.x;
  int w = tid & 127;
  int chh = tid >> 7;
  __shared__ float sacc[2][128];
  float acc = 0.f;
  for (int ci = 0; ci < 64; ++ci) {
    int c = chh * 64 + ci;
    float v = h1[(((size_t)(b * 128 + c)) * 128 + h) * 128 + w];
    int g = b * 8 + (c >> 4);
    float nv = (v - mr[g * 2]) * mr[g * 2 + 1] * P[P_GNG + c] + P[P_GNB + c];
    float ge = 0.5f * nv * (1.f + erff(nv * 0.70710678118f));
    acc += ge * P[P_PWW + c];
  }
  sacc[chh][w] = acc;
  __syncthreads();
  if (chh == 0) {
    float off = acc + sacc[1][w] + P[P_PWB];
    float ofv = tanhf(off) * 8.0f;
    offf[bh * 128 + w] = ofv;
    dout[16777216 + bh * 128 + w] = ofv;
  }
}

// ---------------- K4 v2: y-only grid sample + transpose -> seq f16 (l,c) --------
__global__ __launch_bounds__(256) void k_deform_v2(const void* __restrict__ x,
                                                   const void* __restrict__ gng,
                                                   const float* __restrict__ offf,
                                                   _Float16* __restrict__ seqc,
                                                   int s0) {
  int bh = s0 + blockIdx.x;
  int b = bh >> 7, h = bh & 127;
  int tid = threadIdx.x;
  int w = tid & 127;
  int half = tid >> 7;
  bool f32x = in_is_f32(gng);
  __shared__ float t[128 * 130];
  float ofv = offf[bh * 128 + w];
  float gy = -1.f + (2.f / 127.f) * (float)h + ofv * (2.f / 127.f);
  gy = fminf(fmaxf(gy, -1.f), 1.f);
  float py = (gy + 1.f) * 0.5f * 127.f;
  py = fminf(fmaxf(py, 0.f), 127.f);
  float y0f = floorf(py);
  float wy = py - y0f;
  int y0 = (int)y0f;
  int y1 = min(y0 + 1, 127);
  const float* xfb = (const float*)x + (size_t)b * 128 * 16384;
  const unsigned short* xbb = (const unsigned short*)x + (size_t)b * 128 * 16384;
  int c0 = half * 64;
  for (int i = 0; i < 64; ++i) {
    int c = c0 + i;
    size_t o0 = (size_t)c * 16384 + y0 * 128 + w;
    size_t o1 = (size_t)c * 16384 + y1 * 128 + w;
    float v0, v1;
    if (f32x) { v0 = xfb[o0]; v1 = xfb[o1]; }
    else      { v0 = b2f(xbb[o0]); v1 = b2f(xbb[o1]); }
    t[c * 130 + w] = v0 + wy * (v1 - v0);
  }
  __syncthreads();
  int c2 = tid & 127;
  int lb = (tid >> 7) * 64;
  _Float16* sp = seqc + (size_t)blockIdx.x * 16384;
  for (int i = 0; i < 64; ++i) {
    int l = lb + i;
    sp[l * 128 + c2] = (_Float16)t[c2 * 130 + l];
  }
}

// ---------------- G1 v4: zxbcdt = seq @ wproj^T via MFMA f16; z out f16 ---------
__global__ __launch_bounds__(256) void k_gemm1_v4(const _Float16* __restrict__ seqh,
                                                  const _Float16* __restrict__ wprojh,
                                                  const float* __restrict__ P,
                                                  _Float16* __restrict__ zh,
                                                  float* __restrict__ xbc,
                                                  float* __restrict__ dtb) {
  __shared__ __align__(16) _Float16 lA[128 * 64];
  __shared__ __align__(16) _Float16 lB[128 * 64];
  int m0 = blockIdx.x * 128;
  int e0 = blockIdx.y * 128;
  int tid = threadIdx.x;
  int lane = tid & 63;
  int wv = tid >> 6;
  f32x4 acc[2][8];
#pragma unroll
  for (int rf = 0; rf < 2; ++rf)
#pragma unroll
    for (int cf = 0; cf < 8; ++cf) acc[rf][cf] = (f32x4){0.f, 0.f, 0.f, 0.f};

  int rsel = lane & 15, q = lane >> 4;
  for (int k0 = 0; k0 < 128; k0 += 64) {
    if (k0) __syncthreads();
#pragma unroll
    for (int p = 0; p < 4; ++p) {
      int idx = tid + 256 * p;
      int row = idx >> 3, ch = idx & 7;
      int dch = ch ^ (row & 7);
      *(half8*)&lA[row * 64 + dch * 8] =
          *(const half8*)&seqh[(size_t)(m0 + row) * 128 + k0 + ch * 8];
      *(half8*)&lB[row * 64 + dch * 8] =
          *(const half8*)&wprojh[(size_t)(e0 + row) * 128 + k0 + ch * 8];
    }
    __syncthreads();
#pragma unroll
    for (int kk = 0; kk < 2; ++kk) {
      half8 a[2];
#pragma unroll
      for (int rf = 0; rf < 2; ++rf) {
        int row = wv * 32 + rf * 16 + rsel;
        int ch = (kk * 4 + q) ^ (row & 7);
        a[rf] = *(const half8*)&lA[row * 64 + ch * 8];
      }
#pragma unroll
      for (int cf = 0; cf < 8; ++cf) {
        int row = cf * 16 + rsel;
        int ch = (kk * 4 + q) ^ (row & 7);
        half8 b = *(const half8*)&lB[row * 64 + ch * 8];
        acc[0][cf] = __builtin_amdgcn_mfma_f32_16x16x32_f16(a[0], b, acc[0][cf], 0, 0, 0);
        acc[1][cf] = __builtin_amdgcn_mfma_f32_16x16x32_f16(a[1], b, acc[1][cf], 0, 0, 0);
      }
    }
  }

#pragma unroll
  for (int rf = 0; rf < 2; ++rf) {
    int mb = m0 + wv * 32 + rf * 16 + q * 4;
    if (e0 < 256) {
#pragma unroll
      for (int cf = 0; cf < 8; ++cf) {
        _Float16* pz = zh + (size_t)mb * 256 + e0 + cf * 16 + rsel;
#pragma unroll
        for (int r = 0; r < 4; ++r) pz[(size_t)r * 256] = (_Float16)acc[rf][cf][r];
      }
    } else if (e0 < 640) {
#pragma unroll
      for (int cf = 0; cf < 8; ++cf) {
        float* px = xbc + (size_t)mb * 384 + (e0 - 256) + cf * 16 + rsel;
#pragma unroll
        for (int r = 0; r < 4; ++r) px[(size_t)r * 384] = acc[rf][cf][r];
      }
    } else {
      if (rsel < 8) {
        float bias = P[P_DTB + rsel];
#pragma unroll
        for (int r = 0; r < 4; ++r) {
          float dv = acc[rf][0][r] + bias;
          float sp = (dv > 20.f) ? dv : log1pf(__expf(dv));
          dtb[(size_t)(mb + r) * 8 + rsel] = sp;
        }
      }
    }
  }
}

// ---------------- K6 v8: scan + fused conv1d; 2 d-values/thread ------------------
// Grid (CH, 2), 128 threads (2 waves). Thread = (head, dp) handling d=dp and
// d=dp+16: h = float2[32]. One broadcast B/C ds_read_b128 feeds both d-lanes
// (halves LDS issue per unit work); float2 math maps to v_pk_fma_f32.
// Staging: thread stages quad q for steps st and st+8 (same conv weights).
__global__ __launch_bounds__(128) void k_scan_v8(const float* __restrict__ xbc,
                                                 const float* __restrict__ dtb,
                                                 const float* __restrict__ P,
                                                 _Float16* __restrict__ ysA,
                                                 _Float16* __restrict__ ysB) {
  int seq = blockIdx.x;
  int sblk = blockIdx.y;          // 0: states 0..31, 1: states 32..63
  int tid = threadIdx.x;          // 0..127
  int head = tid >> 4;            // 0..7
  int dp = tid & 15;              // 0..15
  int e0 = head * 32 + dp;        // x column lo
  int e1 = e0 + 16;               // x column hi
  float A = -__expf(P[P_ALOG + head]);
  float Dk = P[P_DSKIP + head];
  // x-path conv weights for e0 and e1
  float wa0 = P[P_CW + e0 * 4 + 0], wa1 = P[P_CW + e0 * 4 + 1];
  float wa2 = P[P_CW + e0 * 4 + 2], wa3 = P[P_CW + e0 * 4 + 3];
  float cba = P[P_CB + e0];
  float wb0 = P[P_CW + e1 * 4 + 0], wb1 = P[P_CW + e1 * 4 + 1];
  float wb2 = P[P_CW + e1 * 4 + 2], wb3 = P[P_CW + e1 * 4 + 3];
  float cbb = P[P_CB + e1];
  f32x2 h2[32];
#pragma unroll
  for (int s = 0; s < 32; ++s) h2[s] = (f32x2){0.f, 0.f};

  __shared__ __align__(16) float sBC[2][16][64];  // [step][0..31]=B, [32..63]=C
  __shared__ float sdt[2][128];                   // [step*8+head]

  const float* base = xbc + (size_t)seq * 49152;
  const float* dtp = dtb + (size_t)seq * 1024;
  _Float16* yp = (sblk ? ysB : ysA) + (size_t)seq * 32768;

  int st = tid >> 4;              // 0..7 staging step (also st+8)
  int q = tid & 15;               // 0..15 staging quad
  int colbase = (q < 8) ? (256 + sblk * 32 + q * 4)
                        : (320 + sblk * 32 + (q - 8) * 4);
  int ldst = (q < 8) ? q * 4 : 32 + (q - 8) * 4;
  // B/C conv weights for this thread's 4 columns (same for both staged steps)
  float cwt[4][4], cbv[4];
#pragma unroll
  for (int j = 0; j < 4; ++j) {
#pragma unroll
    for (int k = 0; k < 4; ++k) cwt[j][k] = P[P_CW + (colbase + j) * 4 + k];
    cbv[j] = P[P_CB + colbase + j];
  }

  auto conv4 = [&](int row) -> float4 {
    float4 r0 = *(const float4*)(base + (size_t)row * 384 + colbase);
    float4 r1 = make_float4(0.f, 0.f, 0.f, 0.f);
    float4 r2 = r1, r3 = r1;
    if (row >= 1) r1 = *(const float4*)(base + (size_t)(row - 1) * 384 + colbase);
    if (row >= 2) r2 = *(const float4*)(base + (size_t)(row - 2) * 384 + colbase);
    if (row >= 3) r3 = *(const float4*)(base + (size_t)(row - 3) * 384 + colbase);
    float4 o;
    o.x = cbv[0] + cwt[0][3] * r0.x + cwt[0][2] * r1.x + cwt[0][1] * r2.x + cwt[0][0] * r3.x;
    o.y = cbv[1] + cwt[1][3] * r0.y + cwt[1][2] * r1.y + cwt[1][1] * r2.y + cwt[1][0] * r3.y;
    o.z = cbv[2] + cwt[2][3] * r0.z + cwt[2][2] * r1.z + cwt[2][1] * r2.z + cwt[2][0] * r3.z;
    o.w = cbv[3] + cwt[3][3] * r0.w + cwt[3][2] * r1.w + cwt[3][1] * r2.w + cwt[3][0] * r3.w;
    o.x = o.x / (1.f + __expf(-o.x));
    o.y = o.y / (1.f + __expf(-o.y));
    o.z = o.z / (1.f + __expf(-o.z));
    o.w = o.w / (1.f + __expf(-o.w));
    return o;
  };

  // prologue: stage tile 0 (steps st and st+8) into buf0
  {
    float4 rv0 = conv4(st);
    float4 rv1 = conv4(st + 8);
    float rdt = dtp[tid];
    *(float4*)&sBC[0][st][ldst] = rv0;
    *(float4*)&sBC[0][st + 8][ldst] = rv1;
    sdt[0][tid] = rdt;
  }
  __syncthreads();

  f32x2 x0 = {0.f, 0.f}, x1 = {0.f, 0.f}, x2 = {0.f, 0.f};
  for (int t = 0; t < 8; ++t) {
    int buf = t & 1;
    int l0 = t * 16;
    f32x2 xr[16];
#pragma unroll
    for (int s = 0; s < 16; ++s) {
      const float* rp = base + (size_t)(l0 + s) * 384;
      xr[s] = (f32x2){rp[e0], rp[e1]};
    }
    float4 rv0, rv1;
    float rdt = 0.f;
    if (t < 7) {
      rv0 = conv4(l0 + 16 + st);
      rv1 = conv4(l0 + 16 + st + 8);
      rdt = dtp[(l0 + 16) * 8 + tid];
    }
#pragma unroll
    for (int s = 0; s < 16; ++s) {
      // fused causal conv + SiLU for both x columns
      float aa = cba + wa0 * x0.x + wa1 * x1.x + wa2 * x2.x + wa3 * xr[s].x;
      float ab = cbb + wb0 * x0.y + wb1 * x1.y + wb2 * x2.y + wb3 * xr[s].y;
      f32x2 xv2;
      xv2.x = aa / (1.f + __expf(-aa));
      xv2.y = ab / (1.f + __expf(-ab));
      x0 = x1; x1 = x2; x2 = xr[s];
      float dt = sdt[buf][s * 8 + head];
      float dA = __expf(dt * A);
      f32x2 dA2 = {dA, dA};
      f32x2 coef2 = xv2 * dt;
      f32x2 a0 = {0.f, 0.f}, a1 = {0.f, 0.f}, a2 = {0.f, 0.f}, a3 = {0.f, 0.f};
#pragma unroll
      for (int qq = 0; qq < 8; ++qq) {
        float4 bq = *(const float4*)&sBC[buf][s][qq * 4];
        float4 cq = *(const float4*)&sBC[buf][s][32 + qq * 4];
        h2[qq * 4 + 0] = h2[qq * 4 + 0] * dA2 + coef2 * bq.x;  a0 += h2[qq * 4 + 0] * cq.x;
        h2[qq * 4 + 1] = h2[qq * 4 + 1] * dA2 + coef2 * bq.y;  a1 += h2[qq * 4 + 1] * cq.y;
        h2[qq * 4 + 2] = h2[qq * 4 + 2] * dA2 + coef2 * bq.z;  a2 += h2[qq * 4 + 2] * cq.z;
        h2[qq * 4 + 3] = h2[qq * 4 + 3] * dA2 + coef2 * bq.w;  a3 += h2[qq * 4 + 3] * cq.w;
      }
      f32x2 res = (a0 + a1) + (a2 + a3);
      if (sblk == 0) res += xv2 * Dk;
      yp[(size_t)(l0 + s) * 256 + e0] = (_Float16)res.x;
      yp[(size_t)(l0 + s) * 256 + e1] = (_Float16)res.y;
    }
    if (t < 7) {
      *(float4*)&sBC[buf ^ 1][st][ldst] = rv0;
      *(float4*)&sBC[buf ^ 1][st + 8][ldst] = rv1;
      sdt[buf ^ 1][tid] = rdt;
    }
    __syncthreads();
  }
}

// ---------------- K7 v6: gate + RMS norm -> ynorm f16 (f16 inputs) ---------------
__global__ __launch_bounds__(256) void k_gate_v6(const _Float16* __restrict__ ysA,
                                                 const _Float16* __restrict__ ysB,
                                                 const _Float16* __restrict__ zh,
                                                 const float* __restrict__ P,
                                                 _Float16* __restrict__ ynh) {
  int l = blockIdx.x;
  int e = threadIdx.x;
  __shared__ float red[4];
  size_t idx = (size_t)l * 256 + e;
  float yv = (float)ysA[idx] + (float)ysB[idx];
  float zv = (float)zh[idx];
  float g = zv / (1.f + __expf(-zv));
  float y = yv * g;
  float ss = y * y;
  for (int o = 32; o; o >>= 1) ss += __shfl_down(ss, o, 64);
  if ((threadIdx.x & 63) == 0) red[threadIdx.x >> 6] = ss;
  __syncthreads();
  float tot = red[0] + red[1] + red[2] + red[3];
  float r = rsqrtf(tot * (1.f / 256.f) + 1e-5f);
  ynh[idx] = (_Float16)(y * r * P[P_NG + e]);
}

// ---------------- G2 v3: out = ynorm @ outw^T via MFMA f16 ----------------------
__global__ __launch_bounds__(256) void k_gemm2_v3(const _Float16* __restrict__ ynh,
                                                  const _Float16* __restrict__ outwh,
                                                  float* __restrict__ dout,
                                                  int tok0) {
  __shared__ __align__(16) _Float16 lA[128 * 64];
  __shared__ __align__(16) _Float16 lB[64 * 64];
  int t0 = blockIdx.x * 64;
  int tid = threadIdx.x;
  int lane = tid & 63;
  int wv = tid >> 6;
  f32x4 acc[2][4];
#pragma unroll
  for (int rf = 0; rf < 2; ++rf)
#pragma unroll
    for (int cf = 0; cf < 4; ++cf) acc[rf][cf] = (f32x4){0.f, 0.f, 0.f, 0.f};

  int rsel = lane & 15, q = lane >> 4;
  for (int k0 = 0; k0 < 256; k0 += 64) {
    if (k0) __syncthreads();
#pragma unroll
    for (int p = 0; p < 4; ++p) {
      int idx = tid + 256 * p;
      int row = idx >> 3, ch = idx & 7;
      int dch = ch ^ (row & 7);
      *(half8*)&lA[row * 64 + dch * 8] =
          *(const half8*)&outwh[(size_t)row * 256 + k0 + ch * 8];
    }
#pragma unroll
    for (int p = 0; p < 2; ++p) {
      int idx = tid + 256 * p;
      int row = idx >> 3, ch = idx & 7;
      int dch = ch ^ (row & 7);
      *(half8*)&lB[row * 64 + dch * 8] =
          *(const half8*)&ynh[(size_t)(t0 + row) * 256 + k0 + ch * 8];
    }
    __syncthreads();
#pragma unroll
    for (int kk = 0; kk < 2; ++kk) {
      half8 a[2];
#pragma unroll
      for (int rf = 0; rf < 2; ++rf) {
        int row = wv * 32 + rf * 16 + rsel;
        int ch = (kk * 4 + q) ^ (row & 7);
        a[rf] = *(const half8*)&lA[row * 64 + ch * 8];
      }
#pragma unroll
      for (int cf = 0; cf < 4; ++cf) {
        int row = cf * 16 + rsel;
        int ch = (kk * 4 + q) ^ (row & 7);
        half8 b = *(const half8*)&lB[row * 64 + ch * 8];
        acc[0][cf] = __builtin_amdgcn_mfma_f32_16x16x32_f16(a[0], b, acc[0][cf], 0, 0, 0);
        acc[1][cf] = __builtin_amdgcn_mfma_f32_16x16x32_f16(a[1], b, acc[1][cf], 0, 0, 0);
      }
    }
  }

  int l0 = tok0 + t0;
  int b = l0 >> 14;
  int rem0 = l0 & 16383;
#pragma unroll
  for (int rf = 0; rf < 2; ++rf) {
    int cbase = wv * 32 + rf * 16 + q * 4;
#pragma unroll
    for (int cf = 0; cf < 4; ++cf) {
#pragma unroll
      for (int r = 0; r < 4; ++r) {
        dout[(size_t)(b * 128 + cbase + r) * 16384 + rem0 + cf * 16 + rsel] = acc[rf][cf][r];
      }
    }
  }
}

extern "C" void kernel_launch(void* const* d_in, const int* in_sizes, int n_in,
                              void* d_out, int out_size, void* d_ws, size_t ws_size,
                              hipStream_t stream) {
  const void* x      = d_in[0];
  const void* dww    = d_in[1];
  const void* gng    = d_in[2];
  const void* gnb    = d_in[3];
  const void* pww    = d_in[4];
  const void* pwb    = d_in[5];
  const void* wproj  = d_in[6];
  const void* cw     = d_in[7];
  const void* cb     = d_in[8];
  const void* dtbias = d_in[9];
  const void* alog   = d_in[10];
  const void* dskip  = d_in[11];
  const void* ng     = d_in[12];
  const void* outw   = d_in[13];
  float* out = (float*)d_out;

  char* ws = (char*)d_ws;
  float* gst        = (float*)(ws + 0);
  float* mr         = (float*)(ws + 4096);
  float* P          = (float*)(ws + 8192);
  _Float16* wprojh  = (_Float16*)(ws + 40960);
  _Float16* outwh   = (_Float16*)(ws + 372736);
  float* offf       = (float*)(ws + 503808);
  char* cbase       = ws + 1028096;

  // h1 (f32, 67,108,864 B) lives in d_out's out_2d region.
  float* h1f = out;

  // Per-sequence chunk bytes:
  //   seq f16 32768 + zh f16 65536 + xbc 196608 + dtb 4096 + ysA f16 65536
  //   + ysB f16 65536 = 430080.  (ynorm f16 reuses xbc region, dead after scan.)
  const int opts[11] = {1024, 512, 256, 128, 64, 32, 16, 8, 4, 2, 1};
  int CH = 1;
  for (int i = 0; i < 11; ++i) {
    if (1028096ull + (unsigned long long)opts[i] * 430080ull <= (unsigned long long)ws_size) {
      CH = opts[i];
      break;
    }
  }
  int NC = 1024 / CH;

  _Float16* seqh = (_Float16*)(cbase);
  _Float16* zh   = (_Float16*)(cbase + (size_t)CH * 32768);
  float* xbcf    = (float*)(cbase + (size_t)CH * 98304);
  float* dtbf    = (float*)(cbase + (size_t)CH * 294912);
  _Float16* ysA  = (_Float16*)(cbase + (size_t)CH * 299008);
  _Float16* ysB  = (_Float16*)(cbase + (size_t)CH * 364544);
  _Float16* ynh  = (_Float16*)xbcf;

  k_prep_params<<<1, 256, 0, stream>>>(dww, cw, cb, gng, gnb, pww, pwb, dtbias,
                                       alog, dskip, ng, P, gst);
  k_prep_w<<<128, 256, 0, stream>>>(wproj, outw, gng, wprojh, outwh);
  k_dwconv_v3<<<4096, 256, 0, stream>>>(x, gng, P, h1f, gst);
  k_stats<<<1, 64, 0, stream>>>(gst, mr);
  k_gn_off_v2<<<1024, 256, 0, stream>>>(h1f, mr, P, offf, out);

  int M = CH * 128;
  for (int c = 0; c < NC; ++c) {
    int s0 = c * CH;
    k_deform_v2<<<CH, 256, 0, stream>>>(x, gng, offf, seqh, s0);
    k_gemm1_v4<<<dim3(M / 128, 6), 256, 0, stream>>>(seqh, wprojh, P, zh, xbcf, dtbf);
    k_scan_v8<<<dim3(CH, 2), 128, 0, stream>>>(xbcf, dtbf, P, ysA, ysB);
    k_gate_v6<<<CH * 128, 256, 0, stream>>>(ysA, ysB, zh, P, ynh);
    k_gemm2_v3<<<dim3(M / 64), 256, 0, stream>>>(ynh, outwh, out, s0 * 128);
  }
}

// Round 10
// 679.209 us; speedup vs baseline: 2.4349x; 1.1459x over previous
//
#include <hip/hip_runtime.h>
#include <math.h>

// B=8, C=128, H=128, W=128, D_INNER=256, D_STATE=64, HEADDIM=32, NHEADS=8,
// D_CONV=4, GN_GROUPS=8, D_XBC=384, D_INPROJ=648.
// Inputs f32 (probed via gn_g word0). OUTPUT IS F32 (reference output dtype).
// d_out = [out_2d: 16,777,216 f32][offset: 131,072 f32].
// h1 (f32) is staged in d_out's out_2d region.
//
// R1 scan de-spill 3236 -> R2 reg-blocked GEMMs 2123 -> R3 MFMA f16 1078 ->
// R5 scan block-split 1268 -> R6 LDS-tiled 1074 -> R7 conv fused + deform v2
// 866 -> R8 dwconv v3 + f16 ys/z 800 -> R9 scan 2d/thread 778.
// R10: SCAN -> SSD MATRIX FORM on matrix cores (scan was VALU-bound at 65%,
// MfmaUtil 0). L=128 = one chunk: G = C@B^T (shared across heads, MFMA),
// W = G * exp(A(T_l-T_j)) mask built in registers (each element once),
// Y = W @ (dt*X) per head (MFMA). Conv1d returns as separate out-of-place
// f16 kernel; gemm1 writes xbc f16; single ys buffer.

typedef _Float16 half8 __attribute__((ext_vector_type(8)));
typedef float f32x4 __attribute__((ext_vector_type(4)));

__device__ __forceinline__ float b2f(unsigned short u) {
  return __uint_as_float(((unsigned int)u) << 16);
}
__device__ __forceinline__ bool in_is_f32(const void* gng) {
  return ((const unsigned int*)gng)[0] == 0x3F800000u;
}

#define P_DWW 0
#define P_CW 3200
#define P_CB 4736
#define P_GNG 5120
#define P_GNB 5248
#define P_PWW 5376
#define P_PWB 5504
#define P_DTB 5505
#define P_ALOG 5513
#define P_DSKIP 5521
#define P_NG 5529

__global__ void k_prep_params(const void* dww, const void* cw, const void* cb,
                              const void* gng, const void* gnb, const void* pww,
                              const void* pwb, const void* dtbias, const void* alog,
                              const void* dskip, const void* ng, float* __restrict__ P,
                              float* __restrict__ gst) {
  bool f = in_is_f32(gng);
  int tid = threadIdx.x;
  if (tid < 128) gst[tid] = 0.f;
  auto cvt = [&](const void* src, int n, int off) {
    for (int i = tid; i < n; i += 256)
      P[off + i] = f ? ((const float*)src)[i] : b2f(((const unsigned short*)src)[i]);
  };
  cvt(dww, 3200, P_DWW);
  cvt(cw, 1536, P_CW);
  cvt(cb, 384, P_CB);
  cvt(gng, 128, P_GNG);
  cvt(gnb, 128, P_GNB);
  cvt(pww, 128, P_PWW);
  cvt(pwb, 1, P_PWB);
  cvt(dtbias, 8, P_DTB);
  cvt(alog, 8, P_ALOG);
  cvt(dskip, 8, P_DSKIP);
  cvt(ng, 256, P_NG);
}

// wprojh: 768 x 128 f16 (rows >=648 zero).  outwh: 128 x 256 f16.
__global__ void k_prep_w(const void* wproj, const void* outw, const void* gng,
                         _Float16* __restrict__ wprojh, _Float16* __restrict__ outwh) {
  bool f = in_is_f32(gng);
  int stride = gridDim.x * blockDim.x;
  for (int i = blockIdx.x * blockDim.x + threadIdx.x; i < 98304; i += stride) {
    int row = i >> 7;
    float v = 0.f;
    if (row < 648) v = f ? ((const float*)wproj)[i] : b2f(((const unsigned short*)wproj)[i]);
    wprojh[i] = (_Float16)v;
  }
  for (int i = blockIdx.x * blockDim.x + threadIdx.x; i < 32768; i += stride)
    outwh[i] = (_Float16)(f ? ((const float*)outw)[i] : b2f(((const unsigned short*)outw)[i]));
}

// ---------------- K1 v3: depthwise 5x5 conv + group stats -----------------------
__global__ __launch_bounds__(256) void k_dwconv_v3(const void* __restrict__ x,
                                                   const void* __restrict__ gng,
                                                   const float* __restrict__ P,
                                                   float* __restrict__ h1,
                                                   float* __restrict__ gst) {
  int blk = blockIdx.x;
  int bc = blk >> 2, sub = blk & 3;
  int b = bc >> 7, c = bc & 127;
  int ty0 = sub * 32;
  bool f32x = in_is_f32(gng);
  __shared__ __align__(16) float t[36 * 132];
  __shared__ float red[8];
  const float* xf = (const float*)x + (size_t)bc * 16384;
  const unsigned short* xb = (const unsigned short*)x + (size_t)bc * 16384;
  for (int i = threadIdx.x; i < 144; i += 256) {
    int r = i >> 2, e = i & 3;
    t[r * 132 + (e < 2 ? e : 128 + e)] = 0.f;
  }
  for (int i = threadIdx.x; i < 1152; i += 256) {
    int r = i >> 5, cq = i & 31;
    int gy = ty0 + r - 2;
    float4 v = make_float4(0.f, 0.f, 0.f, 0.f);
    if (gy >= 0 && gy < 128) {
      if (f32x) {
        v = *(const float4*)(xf + gy * 128 + cq * 4);
      } else {
        ushort4 u = *(const ushort4*)(xb + gy * 128 + cq * 4);
        v = make_float4(b2f(u.x), b2f(u.y), b2f(u.z), b2f(u.w));
      }
    }
    *(float2*)&t[r * 132 + 2 + cq * 4] = make_float2(v.x, v.y);
    *(float2*)&t[r * 132 + 4 + cq * 4] = make_float2(v.z, v.w);
  }
  float w[25];
#pragma unroll
  for (int k = 0; k < 25; ++k) w[k] = P[P_DWW + c * 25 + k];
  __syncthreads();

  int ox = (threadIdx.x & 31) * 4;
  int oy = (threadIdx.x >> 5) * 4;
  float acc[4][4];
#pragma unroll
  for (int r = 0; r < 4; ++r)
#pragma unroll
    for (int j = 0; j < 4; ++j) acc[r][j] = 0.f;

#pragma unroll
  for (int i = 0; i < 8; ++i) {
    float4 p0 = *(const float4*)&t[(oy + i) * 132 + ox];
    float4 p1 = *(const float4*)&t[(oy + i) * 132 + ox + 4];
    float in8[8] = {p0.x, p0.y, p0.z, p0.w, p1.x, p1.y, p1.z, p1.w};
#pragma unroll
    for (int r = 0; r < 4; ++r) {
      if (i - r >= 0 && i - r <= 4) {
        int ky = i - r;
#pragma unroll
        for (int j = 0; j < 4; ++j)
#pragma unroll
          for (int kx = 0; kx < 5; ++kx)
            acc[r][j] += w[ky * 5 + kx] * in8[j + kx];
      }
    }
  }

  float s = 0.f, sq = 0.f;
  float* hp = h1 + (size_t)bc * 16384;
#pragma unroll
  for (int r = 0; r < 4; ++r) {
    *(float4*)&hp[(ty0 + oy + r) * 128 + ox] =
        make_float4(acc[r][0], acc[r][1], acc[r][2], acc[r][3]);
#pragma unroll
    for (int j = 0; j < 4; ++j) { s += acc[r][j]; sq += acc[r][j] * acc[r][j]; }
  }
  for (int o = 32; o; o >>= 1) { s += __shfl_down(s, o, 64); sq += __shfl_down(sq, o, 64); }
  int wv = threadIdx.x >> 6;
  if ((threadIdx.x & 63) == 0) { red[wv] = s; red[4 + wv] = sq; }
  __syncthreads();
  if (threadIdx.x == 0) {
    float ts = red[0] + red[1] + red[2] + red[3];
    float tq = red[4] + red[5] + red[6] + red[7];
    int g = (b << 3) + (c >> 4);
    atomicAdd(&gst[g * 2], ts);
    atomicAdd(&gst[g * 2 + 1], tq);
  }
}

__global__ void k_stats(const float* __restrict__ gst, float* __restrict__ mr) {
  int g = threadIdx.x;
  if (g < 64) {
    const float invN = 1.f / 262144.f;
    float mean = gst[g * 2] * invN;
    float var = gst[g * 2 + 1] * invN - mean * mean;
    mr[g * 2] = mean;
    mr[g * 2 + 1] = rsqrtf(var + 1e-5f);
  }
}

// ---------------- K3 v2: GN + GELU + 1x1 conv + tanh*8 -> offset ----------------
__global__ __launch_bounds__(256) void k_gn_off_v2(const float* __restrict__ h1,
                                                   const float* __restrict__ mr,
                                                   const float* __restrict__ P,
                                                   float* __restrict__ offf,
                                                   float* __restrict__ dout) {
  int bh = blockIdx.x;
  int b = bh >> 7, h = bh & 127;
  int tid = threadIdx.x;
  int w = tid & 127;
  int chh = tid >> 7;
  __shared__ float sacc[2][128];
  float acc = 0.f;
  for (int ci = 0; ci < 64; ++ci) {
    int c = chh * 64 + ci;
    float v = h1[(((size_t)(b * 128 + c)) * 128 + h) * 128 + w];
    int g = b * 8 + (c >> 4);
    float nv = (v - mr[g * 2]) * mr[g * 2 + 1] * P[P_GNG + c] + P[P_GNB + c];
    float ge = 0.5f * nv * (1.f + erff(nv * 0.70710678118f));
    acc += ge * P[P_PWW + c];
  }
  sacc[chh][w] = acc;
  __syncthreads();
  if (chh == 0) {
    float off = acc + sacc[1][w] + P[P_PWB];
    float ofv = tanhf(off) * 8.0f;
    offf[bh * 128 + w] = ofv;
    dout[16777216 + bh * 128 + w] = ofv;
  }
}

// ---------------- K4 v2: y-only grid sample + transpose -> seq f16 (l,c) --------
__global__ __launch_bounds__(256) void k_deform_v2(const void* __restrict__ x,
                                                   const void* __restrict__ gng,
                                                   const float* __restrict__ offf,
                                                   _Float16* __restrict__ seqc,
                                                   int s0) {
  int bh = s0 + blockIdx.x;
  int b = bh >> 7, h = bh & 127;
  int tid = threadIdx.x;
  int w = tid & 127;
  int half = tid >> 7;
  bool f32x = in_is_f32(gng);
  __shared__ float t[128 * 130];
  float ofv = offf[bh * 128 + w];
  float gy = -1.f + (2.f / 127.f) * (float)h + ofv * (2.f / 127.f);
  gy = fminf(fmaxf(gy, -1.f), 1.f);
  float py = (gy + 1.f) * 0.5f * 127.f;
  py = fminf(fmaxf(py, 0.f), 127.f);
  float y0f = floorf(py);
  float wy = py - y0f;
  int y0 = (int)y0f;
  int y1 = min(y0 + 1, 127);
  const float* xfb = (const float*)x + (size_t)b * 128 * 16384;
  const unsigned short* xbb = (const unsigned short*)x + (size_t)b * 128 * 16384;
  int c0 = half * 64;
  for (int i = 0; i < 64; ++i) {
    int c = c0 + i;
    size_t o0 = (size_t)c * 16384 + y0 * 128 + w;
    size_t o1 = (size_t)c * 16384 + y1 * 128 + w;
    float v0, v1;
    if (f32x) { v0 = xfb[o0]; v1 = xfb[o1]; }
    else      { v0 = b2f(xbb[o0]); v1 = b2f(xbb[o1]); }
    t[c * 130 + w] = v0 + wy * (v1 - v0);
  }
  __syncthreads();
  int c2 = tid & 127;
  int lb = (tid >> 7) * 64;
  _Float16* sp = seqc + (size_t)blockIdx.x * 16384;
  for (int i = 0; i < 64; ++i) {
    int l = lb + i;
    sp[l * 128 + c2] = (_Float16)t[c2 * 130 + l];
  }
}

// ---------------- G1 v5: zxbcdt = seq @ wproj^T via MFMA f16; z,xbc out f16 -----
__global__ __launch_bounds__(256) void k_gemm1_v5(const _Float16* __restrict__ seqh,
                                                  const _Float16* __restrict__ wprojh,
                                                  const float* __restrict__ P,
                                                  _Float16* __restrict__ zh,
                                                  _Float16* __restrict__ xbch,
                                                  float* __restrict__ dtb) {
  __shared__ __align__(16) _Float16 lA[128 * 64];
  __shared__ __align__(16) _Float16 lB[128 * 64];
  int m0 = blockIdx.x * 128;
  int e0 = blockIdx.y * 128;
  int tid = threadIdx.x;
  int lane = tid & 63;
  int wv = tid >> 6;
  f32x4 acc[2][8];
#pragma unroll
  for (int rf = 0; rf < 2; ++rf)
#pragma unroll
    for (int cf = 0; cf < 8; ++cf) acc[rf][cf] = (f32x4){0.f, 0.f, 0.f, 0.f};

  int rsel = lane & 15, q = lane >> 4;
  for (int k0 = 0; k0 < 128; k0 += 64) {
    if (k0) __syncthreads();
#pragma unroll
    for (int p = 0; p < 4; ++p) {
      int idx = tid + 256 * p;
      int row = idx >> 3, ch = idx & 7;
      int dch = ch ^ (row & 7);
      *(half8*)&lA[row * 64 + dch * 8] =
          *(const half8*)&seqh[(size_t)(m0 + row) * 128 + k0 + ch * 8];
      *(half8*)&lB[row * 64 + dch * 8] =
          *(const half8*)&wprojh[(size_t)(e0 + row) * 128 + k0 + ch * 8];
    }
    __syncthreads();
#pragma unroll
    for (int kk = 0; kk < 2; ++kk) {
      half8 a[2];
#pragma unroll
      for (int rf = 0; rf < 2; ++rf) {
        int row = wv * 32 + rf * 16 + rsel;
        int ch = (kk * 4 + q) ^ (row & 7);
        a[rf] = *(const half8*)&lA[row * 64 + ch * 8];
      }
#pragma unroll
      for (int cf = 0; cf < 8; ++cf) {
        int row = cf * 16 + rsel;
        int ch = (kk * 4 + q) ^ (row & 7);
        half8 b = *(const half8*)&lB[row * 64 + ch * 8];
        acc[0][cf] = __builtin_amdgcn_mfma_f32_16x16x32_f16(a[0], b, acc[0][cf], 0, 0, 0);
        acc[1][cf] = __builtin_amdgcn_mfma_f32_16x16x32_f16(a[1], b, acc[1][cf], 0, 0, 0);
      }
    }
  }

#pragma unroll
  for (int rf = 0; rf < 2; ++rf) {
    int mb = m0 + wv * 32 + rf * 16 + q * 4;
    if (e0 < 256) {
#pragma unroll
      for (int cf = 0; cf < 8; ++cf) {
        _Float16* pz = zh + (size_t)mb * 256 + e0 + cf * 16 + rsel;
#pragma unroll
        for (int r = 0; r < 4; ++r) pz[(size_t)r * 256] = (_Float16)acc[rf][cf][r];
      }
    } else if (e0 < 640) {
#pragma unroll
      for (int cf = 0; cf < 8; ++cf) {
        _Float16* px = xbch + (size_t)mb * 384 + (e0 - 256) + cf * 16 + rsel;
#pragma unroll
        for (int r = 0; r < 4; ++r) px[(size_t)r * 384] = (_Float16)acc[rf][cf][r];
      }
    } else {
      if (rsel < 8) {
        float bias = P[P_DTB + rsel];
#pragma unroll
        for (int r = 0; r < 4; ++r) {
          float dv = acc[rf][0][r] + bias;
          float sp = (dv > 20.f) ? dv : log1pf(__expf(dv));
          dtb[(size_t)(mb + r) * 8 + rsel] = sp;
        }
      }
    }
  }
}

// ---------------- K5: causal conv1d + SiLU, out-of-place f16 -> f16 --------------
__global__ __launch_bounds__(256) void k_conv_h(const _Float16* __restrict__ xbch,
                                                _Float16* __restrict__ xch,
                                                const float* __restrict__ P) {
  const _Float16* in = xbch + (size_t)blockIdx.x * 49152;
  _Float16* out = xch + (size_t)blockIdx.x * 49152;
  for (int e = threadIdx.x; e < 384; e += 256) {
    float w0 = P[P_CW + e * 4 + 0], w1 = P[P_CW + e * 4 + 1];
    float w2 = P[P_CW + e * 4 + 2], w3 = P[P_CW + e * 4 + 3];
    float bb = P[P_CB + e];
    float x0 = 0.f, x1 = 0.f, x2 = 0.f;
    for (int l = 0; l < 128; ++l) {
      float x3 = (float)in[l * 384 + e];
      float a = bb + w0 * x0 + w1 * x1 + w2 * x2 + w3 * x3;
      out[l * 384 + e] = (_Float16)(a / (1.f + __expf(-a)));
      x0 = x1; x1 = x2; x2 = x3;
    }
  }
}

// ---------------- K6 v9: SSD matrix-form scan on matrix cores --------------------
// Block = 1 seq, 256 thr (4 waves). L=128 = one chunk (no inter-chunk state).
// Phase 0: dt -> LDS, T = cumsum(dt) per head.
// Phase 1: G = C @ B^T (M=128 x N=128 x K=64) MFMA, operands direct from global
//          (L2-hot), G -> LDS f16 with chunk^(row&7) swizzle.
// Phase 2 per head: Xt[d][j] = dt_j * X[j][d] (swizzled LDS); A-frag built in
//          registers: W[l][j] = (j<=l) ? G[l][j]*exp(A_h(T_l-T_j)) : 0 (each
//          element exactly once); Y = W @ Xt via MFMA; +Dk*x epilogue -> ys f16.
__global__ __launch_bounds__(256) void k_ssd(const _Float16* __restrict__ xch,
                                             const float* __restrict__ dtb,
                                             const float* __restrict__ P,
                                             _Float16* __restrict__ ys) {
  int seq = blockIdx.x;
  int tid = threadIdx.x;
  int lane = tid & 63, wv = tid >> 6;
  int rsel = lane & 15, q = lane >> 4;
  __shared__ __align__(16) _Float16 G[128 * 128];   // 32 KB
  __shared__ __align__(16) _Float16 Xt[32 * 128];   // 8 KB
  __shared__ float dts[128 * 8];                    // 4 KB [l][h]
  __shared__ float Ts[8 * 128];                     // 4 KB [h][l]
  const _Float16* xb = xch + (size_t)seq * 49152;
  const float* dtp = dtb + (size_t)seq * 1024;

  // phase 0: dt staging + per-head cumsum (threads 0..7 serial; others proceed)
  for (int i = tid; i < 1024; i += 256) dts[i] = dtp[i];
  __syncthreads();
  if (tid < 8) {
    float a = 0.f;
    for (int l = 0; l < 128; ++l) { a += dts[l * 8 + tid]; Ts[tid * 128 + l] = a; }
  }

  // phase 1: G = C @ B^T, K=64 (C cols 320.., B cols 256..)
  f32x4 gacc[2][8];
#pragma unroll
  for (int rf = 0; rf < 2; ++rf)
#pragma unroll
    for (int cf = 0; cf < 8; ++cf) gacc[rf][cf] = (f32x4){0.f, 0.f, 0.f, 0.f};
#pragma unroll
  for (int kk = 0; kk < 2; ++kk) {
    half8 a[2];
#pragma unroll
    for (int rf = 0; rf < 2; ++rf) {
      int l = wv * 32 + rf * 16 + rsel;
      a[rf] = *(const half8*)&xb[(size_t)l * 384 + 320 + kk * 32 + q * 8];
    }
#pragma unroll
    for (int cf = 0; cf < 8; ++cf) {
      int j = cf * 16 + rsel;
      half8 b = *(const half8*)&xb[(size_t)j * 384 + 256 + kk * 32 + q * 8];
      gacc[0][cf] = __builtin_amdgcn_mfma_f32_16x16x32_f16(a[0], b, gacc[0][cf], 0, 0, 0);
      gacc[1][cf] = __builtin_amdgcn_mfma_f32_16x16x32_f16(a[1], b, gacc[1][cf], 0, 0, 0);
    }
  }
  // store G f16 swizzled: idx = l*128 + ((j>>3 ^ (l&7))<<3) + (j&7)
#pragma unroll
  for (int rf = 0; rf < 2; ++rf) {
#pragma unroll
    for (int r = 0; r < 4; ++r) {
      int l = wv * 32 + rf * 16 + q * 4 + r;
#pragma unroll
      for (int cf = 0; cf < 8; ++cf) {
        int j = cf * 16 + rsel;
        G[l * 128 + (((j >> 3) ^ (l & 7)) << 3) + (j & 7)] = (_Float16)gacc[rf][cf][r];
      }
    }
  }
  __syncthreads();

  // phase 2: per head
  _Float16* yp = ys + (size_t)seq * 32768;
  for (int h = 0; h < 8; ++h) {
    // stage Xt[d][j] = dt_j * xconv[j][h*32+d], swizzled
    {
      int j = tid >> 1, ds = (tid & 1) * 16;
      float dtj = dts[j * 8 + h];
      half8 v0 = *(const half8*)&xb[(size_t)j * 384 + h * 32 + ds];
      half8 v1 = *(const half8*)&xb[(size_t)j * 384 + h * 32 + ds + 8];
#pragma unroll
      for (int e = 0; e < 8; ++e) {
        int d0 = ds + e, d1 = ds + 8 + e;
        Xt[d0 * 128 + (((j >> 3) ^ (d0 & 7)) << 3) + (j & 7)] = (_Float16)((float)v0[e] * dtj);
        Xt[d1 * 128 + (((j >> 3) ^ (d1 & 7)) << 3) + (j & 7)] = (_Float16)((float)v1[e] * dtj);
      }
    }
    __syncthreads();
    float Ah = -__expf(P[P_ALOG + h]);
    float Dk = P[P_DSKIP + h];
    f32x4 acc[2][2];
#pragma unroll
    for (int rf = 0; rf < 2; ++rf)
#pragma unroll
      for (int cf = 0; cf < 2; ++cf) acc[rf][cf] = (f32x4){0.f, 0.f, 0.f, 0.f};
#pragma unroll
    for (int kk = 0; kk < 4; ++kk) {
      int jb = kk * 32 + q * 8;
      int chk = kk * 4 + q;
      float4 tj0 = *(const float4*)&Ts[h * 128 + jb];
      float4 tj1 = *(const float4*)&Ts[h * 128 + jb + 4];
      float tj[8] = {tj0.x, tj0.y, tj0.z, tj0.w, tj1.x, tj1.y, tj1.z, tj1.w};
      half8 a[2];
#pragma unroll
      for (int rf = 0; rf < 2; ++rf) {
        int l = wv * 32 + rf * 16 + rsel;
        half8 g = *(const half8*)&G[l * 128 + ((chk ^ (l & 7)) << 3)];
        float Tl = Ts[h * 128 + l];
        half8 w;
#pragma unroll
        for (int e = 0; e < 8; ++e) {
          int j = jb + e;
          float m = (j <= l) ? __expf(Ah * (Tl - tj[e])) : 0.f;
          w[e] = (_Float16)((float)g[e] * m);
        }
        a[rf] = w;
      }
#pragma unroll
      for (int cf = 0; cf < 2; ++cf) {
        int d = cf * 16 + rsel;
        half8 b = *(const half8*)&Xt[d * 128 + ((chk ^ (d & 7)) << 3)];
        acc[0][cf] = __builtin_amdgcn_mfma_f32_16x16x32_f16(a[0], b, acc[0][cf], 0, 0, 0);
        acc[1][cf] = __builtin_amdgcn_mfma_f32_16x16x32_f16(a[1], b, acc[1][cf], 0, 0, 0);
      }
    }
    // epilogue: + Dk * xconv, store ys
#pragma unroll
    for (int rf = 0; rf < 2; ++rf) {
      int lb = wv * 32 + rf * 16 + q * 4;
#pragma unroll
      for (int cf = 0; cf < 2; ++cf) {
        int d = cf * 16 + rsel;
#pragma unroll
        for (int r = 0; r < 4; ++r) {
          int l = lb + r;
          float xv = (float)xb[(size_t)l * 384 + h * 32 + d];
          yp[(size_t)l * 256 + h * 32 + d] = (_Float16)(acc[rf][cf][r] + Dk * xv);
        }
      }
    }
    __syncthreads();
  }
}

// ---------------- K7 v7: gate + RMS norm -> ynorm f16 (single ys) ----------------
__global__ __launch_bounds__(256) void k_gate_v7(const _Float16* __restrict__ ys,
                                                 const _Float16* __restrict__ zh,
                                                 const float* __restrict__ P,
                                                 _Float16* __restrict__ ynh) {
  int l = blockIdx.x;
  int e = threadIdx.x;
  __shared__ float red[4];
  size_t idx = (size_t)l * 256 + e;
  float yv = (float)ys[idx];
  float zv = (float)zh[idx];
  float g = zv / (1.f + __expf(-zv));
  float y = yv * g;
  float ss = y * y;
  for (int o = 32; o; o >>= 1) ss += __shfl_down(ss, o, 64);
  if ((threadIdx.x & 63) == 0) red[threadIdx.x >> 6] = ss;
  __syncthreads();
  float tot = red[0] + red[1] + red[2] + red[3];
  float r = rsqrtf(tot * (1.f / 256.f) + 1e-5f);
  ynh[idx] = (_Float16)(y * r * P[P_NG + e]);
}

// ---------------- G2 v3: out = ynorm @ outw^T via MFMA f16 ----------------------
__global__ __launch_bounds__(256) void k_gemm2_v3(const _Float16* __restrict__ ynh,
                                                  const _Float16* __restrict__ outwh,
                                                  float* __restrict__ dout,
                                                  int tok0) {
  __shared__ __align__(16) _Float16 lA[128 * 64];
  __shared__ __align__(16) _Float16 lB[64 * 64];
  int t0 = blockIdx.x * 64;
  int tid = threadIdx.x;
  int lane = tid & 63;
  int wv = tid >> 6;
  f32x4 acc[2][4];
#pragma unroll
  for (int rf = 0; rf < 2; ++rf)
#pragma unroll
    for (int cf = 0; cf < 4; ++cf) acc[rf][cf] = (f32x4){0.f, 0.f, 0.f, 0.f};

  int rsel = lane & 15, q = lane >> 4;
  for (int k0 = 0; k0 < 256; k0 += 64) {
    if (k0) __syncthreads();
#pragma unroll
    for (int p = 0; p < 4; ++p) {
      int idx = tid + 256 * p;
      int row = idx >> 3, ch = idx & 7;
      int dch = ch ^ (row & 7);
      *(half8*)&lA[row * 64 + dch * 8] =
          *(const half8*)&outwh[(size_t)row * 256 + k0 + ch * 8];
    }
#pragma unroll
    for (int p = 0; p < 2; ++p) {
      int idx = tid + 256 * p;
      int row = idx >> 3, ch = idx & 7;
      int dch = ch ^ (row & 7);
      *(half8*)&lB[row * 64 + dch * 8] =
          *(const half8*)&ynh[(size_t)(t0 + row) * 256 + k0 + ch * 8];
    }
    __syncthreads();
#pragma unroll
    for (int kk = 0; kk < 2; ++kk) {
      half8 a[2];
#pragma unroll
      for (int rf = 0; rf < 2; ++rf) {
        int row = wv * 32 + rf * 16 + rsel;
        int ch = (kk * 4 + q) ^ (row & 7);
        a[rf] = *(const half8*)&lA[row * 64 + ch * 8];
      }
#pragma unroll
      for (int cf = 0; cf < 4; ++cf) {
        int row = cf * 16 + rsel;
        int ch = (kk * 4 + q) ^ (row & 7);
        half8 b = *(const half8*)&lB[row * 64 + ch * 8];
        acc[0][cf] = __builtin_amdgcn_mfma_f32_16x16x32_f16(a[0], b, acc[0][cf], 0, 0, 0);
        acc[1][cf] = __builtin_amdgcn_mfma_f32_16x16x32_f16(a[1], b, acc[1][cf], 0, 0, 0);
      }
    }
  }

  int l0 = tok0 + t0;
  int b = l0 >> 14;
  int rem0 = l0 & 16383;
#pragma unroll
  for (int rf = 0; rf < 2; ++rf) {
    int cbase = wv * 32 + rf * 16 + q * 4;
#pragma unroll
    for (int cf = 0; cf < 4; ++cf) {
#pragma unroll
      for (int r = 0; r < 4; ++r) {
        dout[(size_t)(b * 128 + cbase + r) * 16384 + rem0 + cf * 16 + rsel] = acc[rf][cf][r];
      }
    }
  }
}

extern "C" void kernel_launch(void* const* d_in, const int* in_sizes, int n_in,
                              void* d_out, int out_size, void* d_ws, size_t ws_size,
                              hipStream_t stream) {
  const void* x      = d_in[0];
  const void* dww    = d_in[1];
  const void* gng    = d_in[2];
  const void* gnb    = d_in[3];
  const void* pww    = d_in[4];
  const void* pwb    = d_in[5];
  const void* wproj  = d_in[6];
  const void* cw     = d_in[7];
  const void* cb     = d_in[8];
  const void* dtbias = d_in[9];
  const void* alog   = d_in[10];
  const void* dskip  = d_in[11];
  const void* ng     = d_in[12];
  const void* outw   = d_in[13];
  float* out = (float*)d_out;

  char* ws = (char*)d_ws;
  float* gst        = (float*)(ws + 0);
  float* mr         = (float*)(ws + 4096);
  float* P          = (float*)(ws + 8192);
  _Float16* wprojh  = (_Float16*)(ws + 40960);
  _Float16* outwh   = (_Float16*)(ws + 372736);
  float* offf       = (float*)(ws + 503808);
  char* cbase       = ws + 1028096;

  // h1 (f32, 67,108,864 B) lives in d_out's out_2d region.
  float* h1f = out;

  // Per-sequence chunk bytes:
  //   seq f16 32768 + zh f16 65536 + xbch f16 98304 + xch f16 98304
  //   + dtb 4096 + ys f16 65536 = 364544.  (ynorm f16 reuses xbch region.)
  const int opts[11] = {1024, 512, 256, 128, 64, 32, 16, 8, 4, 2, 1};
  int CH = 1;
  for (int i = 0; i < 11; ++i) {
    if (1028096ull + (unsigned long long)opts[i] * 364544ull <= (unsigned long long)ws_size) {
      CH = opts[i];
      break;
    }
  }
  int NC = 1024 / CH;

  _Float16* seqh = (_Float16*)(cbase);
  _Float16* zh   = (_Float16*)(cbase + (size_t)CH * 32768);
  _Float16* xbch = (_Float16*)(cbase + (size_t)CH * 98304);
  _Float16* xch  = (_Float16*)(cbase + (size_t)CH * 196608);
  float* dtbf    = (float*)(cbase + (size_t)CH * 294912);
  _Float16* ysh  = (_Float16*)(cbase + (size_t)CH * 299008);
  _Float16* ynh  = xbch;   // xbch dead after conv

  k_prep_params<<<1, 256, 0, stream>>>(dww, cw, cb, gng, gnb, pww, pwb, dtbias,
                                       alog, dskip, ng, P, gst);
  k_prep_w<<<128, 256, 0, stream>>>(wproj, outw, gng, wprojh, outwh);
  k_dwconv_v3<<<4096, 256, 0, stream>>>(x, gng, P, h1f, gst);
  k_stats<<<1, 64, 0, stream>>>(gst, mr);
  k_gn_off_v2<<<1024, 256, 0, stream>>>(h1f, mr, P, offf, out);

  int M = CH * 128;
  for (int c = 0; c < NC; ++c) {
    int s0 = c * CH;
    k_deform_v2<<<CH, 256, 0, stream>>>(x, gng, offf, seqh, s0);
    k_gemm1_v5<<<dim3(M / 128, 6), 256, 0, stream>>>(seqh, wprojh, P, zh, xbch, dtbf);
    k_conv_h<<<CH, 256, 0, stream>>>(xbch, xch, P);
    k_ssd<<<CH, 256, 0, stream>>>(xch, dtbf, P, ysh);
    k_gate_v7<<<CH * 128, 256, 0, stream>>>(ysh, zh, P, ynh);
    k_gemm2_v3<<<dim3(M / 64), 256, 0, stream>>>(ynh, outwh, out, s0 * 128);
  }
}

// Round 11
// 593.646 us; speedup vs baseline: 2.7858x; 1.1441x over previous
//
#include <hip/hip_runtime.h>
#include <math.h>

// B=8, C=128, H=128, W=128, D_INNER=256, D_STATE=64, HEADDIM=32, NHEADS=8,
// D_CONV=4, GN_GROUPS=8, D_XBC=384, D_INPROJ=648.
// Inputs f32 (probed via gn_g word0). OUTPUT IS F32 (reference output dtype).
// d_out = [out_2d: 16,777,216 f32][offset: 131,072 f32].
// h1 (f32) is staged in d_out's out_2d region.
//
// R1 scan de-spill 3236 -> R2 reg-blocked GEMMs 2123 -> R3 MFMA f16 1078 ->
// R5 scan block-split 1268 -> R6 LDS-tiled 1074 -> R7 conv fused + deform v2
// 866 -> R8 dwconv v3 + f16 ys/z 800 -> R9 scan 2d/thread 778 -> R10 SSD
// matrix-form scan on MFMA 679.
// R11: (a) conv1d+SiLU fused into gemm1 epilogue (gemm1's 128-row M-tile = one
// seq; xbc D-tile staged to LDS, rolling 4-tap conv per column -> xch) -- kills
// k_conv_h and the xbch round trip. (b) dwconv v4: LDS-FREE (24 predicated
// float4 loads/thread, L1-resident tile; v3 had 4.39M bank conflicts + barrier
// stalls at VALUBusy 13%). (c) deform LDS stride 130->129 (conflict-free).

typedef _Float16 half8 __attribute__((ext_vector_type(8)));
typedef float f32x4 __attribute__((ext_vector_type(4)));

__device__ __forceinline__ float b2f(unsigned short u) {
  return __uint_as_float(((unsigned int)u) << 16);
}
__device__ __forceinline__ bool in_is_f32(const void* gng) {
  return ((const unsigned int*)gng)[0] == 0x3F800000u;
}

#define P_DWW 0
#define P_CW 3200
#define P_CB 4736
#define P_GNG 5120
#define P_GNB 5248
#define P_PWW 5376
#define P_PWB 5504
#define P_DTB 5505
#define P_ALOG 5513
#define P_DSKIP 5521
#define P_NG 5529

__global__ void k_prep_params(const void* dww, const void* cw, const void* cb,
                              const void* gng, const void* gnb, const void* pww,
                              const void* pwb, const void* dtbias, const void* alog,
                              const void* dskip, const void* ng, float* __restrict__ P,
                              float* __restrict__ gst) {
  bool f = in_is_f32(gng);
  int tid = threadIdx.x;
  if (tid < 128) gst[tid] = 0.f;
  auto cvt = [&](const void* src, int n, int off) {
    for (int i = tid; i < n; i += 256)
      P[off + i] = f ? ((const float*)src)[i] : b2f(((const unsigned short*)src)[i]);
  };
  cvt(dww, 3200, P_DWW);
  cvt(cw, 1536, P_CW);
  cvt(cb, 384, P_CB);
  cvt(gng, 128, P_GNG);
  cvt(gnb, 128, P_GNB);
  cvt(pww, 128, P_PWW);
  cvt(pwb, 1, P_PWB);
  cvt(dtbias, 8, P_DTB);
  cvt(alog, 8, P_ALOG);
  cvt(dskip, 8, P_DSKIP);
  cvt(ng, 256, P_NG);
}

// wprojh: 768 x 128 f16 (rows >=648 zero).  outwh: 128 x 256 f16.
__global__ void k_prep_w(const void* wproj, const void* outw, const void* gng,
                         _Float16* __restrict__ wprojh, _Float16* __restrict__ outwh) {
  bool f = in_is_f32(gng);
  int stride = gridDim.x * blockDim.x;
  for (int i = blockIdx.x * blockDim.x + threadIdx.x; i < 98304; i += stride) {
    int row = i >> 7;
    float v = 0.f;
    if (row < 648) v = f ? ((const float*)wproj)[i] : b2f(((const unsigned short*)wproj)[i]);
    wprojh[i] = (_Float16)v;
  }
  for (int i = blockIdx.x * blockDim.x + threadIdx.x; i < 32768; i += stride)
    outwh[i] = (_Float16)(f ? ((const float*)outw)[i] : b2f(((const unsigned short*)outw)[i]));
}

// ---------------- K1 v4: depthwise 5x5 conv + group stats, LDS-FREE -------------
// 4 blocks per (b,c): 128w x 32h tile. Thread: 4x4 outputs from 24 predicated
// aligned float4 global loads (3 chunks x 8 rows); ~19KB tile is L1-resident so
// neighbor threads hit cache. No staging barrier, no bank conflicts.
__global__ __launch_bounds__(256) void k_dwconv_v4(const void* __restrict__ x,
                                                   const void* __restrict__ gng,
                                                   const float* __restrict__ P,
                                                   float* __restrict__ h1,
                                                   float* __restrict__ gst) {
  int blk = blockIdx.x;
  int bc = blk >> 2, sub = blk & 3;
  int b = bc >> 7, c = bc & 127;
  int ty0 = sub * 32;
  bool f32x = in_is_f32(gng);
  __shared__ float red[8];
  const float* xf = (const float*)x + (size_t)bc * 16384;
  const unsigned short* xb = (const unsigned short*)x + (size_t)bc * 16384;
  float w[25];
#pragma unroll
  for (int k = 0; k < 25; ++k) w[k] = P[P_DWW + c * 25 + k];

  int ox = (threadIdx.x & 31) * 4;   // 0..124
  int oy = (threadIdx.x >> 5) * 4;   // 0..28
  float acc[4][4];
#pragma unroll
  for (int r = 0; r < 4; ++r)
#pragma unroll
    for (int j = 0; j < 4; ++j) acc[r][j] = 0.f;

#pragma unroll
  for (int i = 0; i < 8; ++i) {
    int gy = ty0 + oy - 2 + i;
    float in12[12];
#pragma unroll
    for (int k = 0; k < 12; ++k) in12[k] = 0.f;
    if (gy >= 0 && gy < 128) {
      if (f32x) {
        const float* rowp = xf + gy * 128;
        if (ox >= 4) {
          float4 v = *(const float4*)(rowp + ox - 4);
          in12[0] = v.x; in12[1] = v.y; in12[2] = v.z; in12[3] = v.w;
        }
        float4 v0 = *(const float4*)(rowp + ox);
        in12[4] = v0.x; in12[5] = v0.y; in12[6] = v0.z; in12[7] = v0.w;
        if (ox < 124) {
          float4 v1 = *(const float4*)(rowp + ox + 4);
          in12[8] = v1.x; in12[9] = v1.y; in12[10] = v1.z; in12[11] = v1.w;
        }
      } else {
        const unsigned short* rowp = xb + gy * 128;
        if (ox >= 4) {
          ushort4 u = *(const ushort4*)(rowp + ox - 4);
          in12[0] = b2f(u.x); in12[1] = b2f(u.y); in12[2] = b2f(u.z); in12[3] = b2f(u.w);
        }
        ushort4 u0 = *(const ushort4*)(rowp + ox);
        in12[4] = b2f(u0.x); in12[5] = b2f(u0.y); in12[6] = b2f(u0.z); in12[7] = b2f(u0.w);
        if (ox < 124) {
          ushort4 u1 = *(const ushort4*)(rowp + ox + 4);
          in12[8] = b2f(u1.x); in12[9] = b2f(u1.y); in12[10] = b2f(u1.z); in12[11] = b2f(u1.w);
        }
      }
    }
#pragma unroll
    for (int r = 0; r < 4; ++r) {
      if (i - r >= 0 && i - r <= 4) {
        int ky = i - r;
#pragma unroll
        for (int j = 0; j < 4; ++j)
#pragma unroll
          for (int kx = 0; kx < 5; ++kx)
            acc[r][j] += w[ky * 5 + kx] * in12[j + kx + 2];
      }
    }
  }

  float s = 0.f, sq = 0.f;
  float* hp = h1 + (size_t)bc * 16384;
#pragma unroll
  for (int r = 0; r < 4; ++r) {
    *(float4*)&hp[(ty0 + oy + r) * 128 + ox] =
        make_float4(acc[r][0], acc[r][1], acc[r][2], acc[r][3]);
#pragma unroll
    for (int j = 0; j < 4; ++j) { s += acc[r][j]; sq += acc[r][j] * acc[r][j]; }
  }
  for (int o = 32; o; o >>= 1) { s += __shfl_down(s, o, 64); sq += __shfl_down(sq, o, 64); }
  int wv = threadIdx.x >> 6;
  if ((threadIdx.x & 63) == 0) { red[wv] = s; red[4 + wv] = sq; }
  __syncthreads();
  if (threadIdx.x == 0) {
    float ts = red[0] + red[1] + red[2] + red[3];
    float tq = red[4] + red[5] + red[6] + red[7];
    int g = (b << 3) + (c >> 4);
    atomicAdd(&gst[g * 2], ts);
    atomicAdd(&gst[g * 2 + 1], tq);
  }
}

__global__ void k_stats(const float* __restrict__ gst, float* __restrict__ mr) {
  int g = threadIdx.x;
  if (g < 64) {
    const float invN = 1.f / 262144.f;
    float mean = gst[g * 2] * invN;
    float var = gst[g * 2 + 1] * invN - mean * mean;
    mr[g * 2] = mean;
    mr[g * 2 + 1] = rsqrtf(var + 1e-5f);
  }
}

// ---------------- K3 v2: GN + GELU + 1x1 conv + tanh*8 -> offset ----------------
__global__ __launch_bounds__(256) void k_gn_off_v2(const float* __restrict__ h1,
                                                   const float* __restrict__ mr,
                                                   const float* __restrict__ P,
                                                   float* __restrict__ offf,
                                                   float* __restrict__ dout) {
  int bh = blockIdx.x;
  int b = bh >> 7, h = bh & 127;
  int tid = threadIdx.x;
  int w = tid & 127;
  int chh = tid >> 7;
  __shared__ float sacc[2][128];
  float acc = 0.f;
  for (int ci = 0; ci < 64; ++ci) {
    int c = chh * 64 + ci;
    float v = h1[(((size_t)(b * 128 + c)) * 128 + h) * 128 + w];
    int g = b * 8 + (c >> 4);
    float nv = (v - mr[g * 2]) * mr[g * 2 + 1] * P[P_GNG + c] + P[P_GNB + c];
    float ge = 0.5f * nv * (1.f + erff(nv * 0.70710678118f));
    acc += ge * P[P_PWW + c];
  }
  sacc[chh][w] = acc;
  __syncthreads();
  if (chh == 0) {
    float off = acc + sacc[1][w] + P[P_PWB];
    float ofv = tanhf(off) * 8.0f;
    offf[bh * 128 + w] = ofv;
    dout[16777216 + bh * 128 + w] = ofv;
  }
}

// ---------------- K4 v3: y-only grid sample + transpose -> seq f16 (l,c) --------
// stride 129: (c+w)%32 and (c2+l)%32 bank patterns -> conflict-free both phases.
__global__ __launch_bounds__(256) void k_deform_v3(const void* __restrict__ x,
                                                   const void* __restrict__ gng,
                                                   const float* __restrict__ offf,
                                                   _Float16* __restrict__ seqc,
                                                   int s0) {
  int bh = s0 + blockIdx.x;
  int b = bh >> 7, h = bh & 127;
  int tid = threadIdx.x;
  int w = tid & 127;
  int half = tid >> 7;
  bool f32x = in_is_f32(gng);
  __shared__ float t[128 * 129];
  float ofv = offf[bh * 128 + w];
  float gy = -1.f + (2.f / 127.f) * (float)h + ofv * (2.f / 127.f);
  gy = fminf(fmaxf(gy, -1.f), 1.f);
  float py = (gy + 1.f) * 0.5f * 127.f;
  py = fminf(fmaxf(py, 0.f), 127.f);
  float y0f = floorf(py);
  float wy = py - y0f;
  int y0 = (int)y0f;
  int y1 = min(y0 + 1, 127);
  const float* xfb = (const float*)x + (size_t)b * 128 * 16384;
  const unsigned short* xbb = (const unsigned short*)x + (size_t)b * 128 * 16384;
  int c0 = half * 64;
  for (int i = 0; i < 64; ++i) {
    int c = c0 + i;
    size_t o0 = (size_t)c * 16384 + y0 * 128 + w;
    size_t o1 = (size_t)c * 16384 + y1 * 128 + w;
    float v0, v1;
    if (f32x) { v0 = xfb[o0]; v1 = xfb[o1]; }
    else      { v0 = b2f(xbb[o0]); v1 = b2f(xbb[o1]); }
    t[c * 129 + w] = v0 + wy * (v1 - v0);
  }
  __syncthreads();
  int c2 = tid & 127;
  int lb = (tid >> 7) * 64;
  _Float16* sp = seqc + (size_t)blockIdx.x * 16384;
  for (int i = 0; i < 64; ++i) {
    int l = lb + i;
    sp[l * 128 + c2] = (_Float16)t[c2 * 129 + l];
  }
}

// ---------------- G1 v6: zxbcdt GEMM with FUSED conv1d+SiLU epilogue ------------
// M-tile (128 rows) = one sequence. xbc blocks (e0=256/384/512): D-tile staged
// f16 into LDS, barrier, per-column rolling 4-tap causal conv + SiLU -> xch.
// z block -> zh f16; dt block -> softplus -> dtb f32.
__global__ __launch_bounds__(256) void k_gemm1_v6(const _Float16* __restrict__ seqh,
                                                  const _Float16* __restrict__ wprojh,
                                                  const float* __restrict__ P,
                                                  _Float16* __restrict__ zh,
                                                  _Float16* __restrict__ xch,
                                                  float* __restrict__ dtb) {
  __shared__ __align__(16) _Float16 lds[16384];   // lA | lB, reused as sx[128][128]
  _Float16* lA = lds;
  _Float16* lB = lds + 8192;
  int m0 = blockIdx.x * 128;
  int e0 = blockIdx.y * 128;
  int tid = threadIdx.x;
  int lane = tid & 63;
  int wv = tid >> 6;
  f32x4 acc[2][8];
#pragma unroll
  for (int rf = 0; rf < 2; ++rf)
#pragma unroll
    for (int cf = 0; cf < 8; ++cf) acc[rf][cf] = (f32x4){0.f, 0.f, 0.f, 0.f};

  int rsel = lane & 15, q = lane >> 4;
  for (int k0 = 0; k0 < 128; k0 += 64) {
    if (k0) __syncthreads();
#pragma unroll
    for (int p = 0; p < 4; ++p) {
      int idx = tid + 256 * p;
      int row = idx >> 3, ch = idx & 7;
      int dch = ch ^ (row & 7);
      *(half8*)&lA[row * 64 + dch * 8] =
          *(const half8*)&seqh[(size_t)(m0 + row) * 128 + k0 + ch * 8];
      *(half8*)&lB[row * 64 + dch * 8] =
          *(const half8*)&wprojh[(size_t)(e0 + row) * 128 + k0 + ch * 8];
    }
    __syncthreads();
#pragma unroll
    for (int kk = 0; kk < 2; ++kk) {
      half8 a[2];
#pragma unroll
      for (int rf = 0; rf < 2; ++rf) {
        int row = wv * 32 + rf * 16 + rsel;
        int ch = (kk * 4 + q) ^ (row & 7);
        a[rf] = *(const half8*)&lA[row * 64 + ch * 8];
      }
#pragma unroll
      for (int cf = 0; cf < 8; ++cf) {
        int row = cf * 16 + rsel;
        int ch = (kk * 4 + q) ^ (row & 7);
        half8 b = *(const half8*)&lB[row * 64 + ch * 8];
        acc[0][cf] = __builtin_amdgcn_mfma_f32_16x16x32_f16(a[0], b, acc[0][cf], 0, 0, 0);
        acc[1][cf] = __builtin_amdgcn_mfma_f32_16x16x32_f16(a[1], b, acc[1][cf], 0, 0, 0);
      }
    }
  }

  if (e0 < 256) {
#pragma unroll
    for (int rf = 0; rf < 2; ++rf) {
      int mb = m0 + wv * 32 + rf * 16 + q * 4;
#pragma unroll
      for (int cf = 0; cf < 8; ++cf) {
        _Float16* pz = zh + (size_t)mb * 256 + e0 + cf * 16 + rsel;
#pragma unroll
        for (int r = 0; r < 4; ++r) pz[(size_t)r * 256] = (_Float16)acc[rf][cf][r];
      }
    }
  } else if (e0 < 640) {
    // stage D-tile f16 into LDS as sx[row][col]
    __syncthreads();
#pragma unroll
    for (int rf = 0; rf < 2; ++rf) {
#pragma unroll
      for (int r = 0; r < 4; ++r) {
        int row = wv * 32 + rf * 16 + q * 4 + r;
#pragma unroll
        for (int cf = 0; cf < 8; ++cf)
          lds[row * 128 + cf * 16 + rsel] = (_Float16)acc[rf][cf][r];
      }
    }
    __syncthreads();
    // rolling 4-tap causal conv + SiLU, thread = (col, row-half)
    int cc = tid & 127;
    int rh = tid >> 7;
    int eg = (e0 - 256) + cc;            // global xbc column 0..383
    float w0 = P[P_CW + eg * 4 + 0], w1 = P[P_CW + eg * 4 + 1];
    float w2 = P[P_CW + eg * 4 + 2], w3 = P[P_CW + eg * 4 + 3];
    float bb = P[P_CB + eg];
    int r0 = rh * 64;
    float x0 = (r0 >= 3) ? (float)lds[(r0 - 3) * 128 + cc] : 0.f;
    float x1 = (r0 >= 2) ? (float)lds[(r0 - 2) * 128 + cc] : 0.f;
    float x2 = (r0 >= 1) ? (float)lds[(r0 - 1) * 128 + cc] : 0.f;
    _Float16* xo = xch + (size_t)m0 * 384 + eg;
    for (int r = r0; r < r0 + 64; ++r) {
      float x3 = (float)lds[r * 128 + cc];
      float a = bb + w0 * x0 + w1 * x1 + w2 * x2 + w3 * x3;
      xo[(size_t)r * 384] = (_Float16)(a / (1.f + __expf(-a)));
      x0 = x1; x1 = x2; x2 = x3;
    }
  } else {
#pragma unroll
    for (int rf = 0; rf < 2; ++rf) {
      int mb = m0 + wv * 32 + rf * 16 + q * 4;
      if (rsel < 8) {
        float bias = P[P_DTB + rsel];
#pragma unroll
        for (int r = 0; r < 4; ++r) {
          float dv = acc[rf][0][r] + bias;
          float sp = (dv > 20.f) ? dv : log1pf(__expf(dv));
          dtb[(size_t)(mb + r) * 8 + rsel] = sp;
        }
      }
    }
  }
}

// ---------------- K6 v9: SSD matrix-form scan on matrix cores --------------------
__global__ __launch_bounds__(256) void k_ssd(const _Float16* __restrict__ xch,
                                             const float* __restrict__ dtb,
                                             const float* __restrict__ P,
                                             _Float16* __restrict__ ys) {
  int seq = blockIdx.x;
  int tid = threadIdx.x;
  int lane = tid & 63, wv = tid >> 6;
  int rsel = lane & 15, q = lane >> 4;
  __shared__ __align__(16) _Float16 G[128 * 128];   // 32 KB
  __shared__ __align__(16) _Float16 Xt[32 * 128];   // 8 KB
  __shared__ float dts[128 * 8];                    // 4 KB [l][h]
  __shared__ float Ts[8 * 128];                     // 4 KB [h][l]
  const _Float16* xb = xch + (size_t)seq * 49152;
  const float* dtp = dtb + (size_t)seq * 1024;

  for (int i = tid; i < 1024; i += 256) dts[i] = dtp[i];
  __syncthreads();
  if (tid < 8) {
    float a = 0.f;
    for (int l = 0; l < 128; ++l) { a += dts[l * 8 + tid]; Ts[tid * 128 + l] = a; }
  }

  // phase 1: G = C @ B^T
  f32x4 gacc[2][8];
#pragma unroll
  for (int rf = 0; rf < 2; ++rf)
#pragma unroll
    for (int cf = 0; cf < 8; ++cf) gacc[rf][cf] = (f32x4){0.f, 0.f, 0.f, 0.f};
#pragma unroll
  for (int kk = 0; kk < 2; ++kk) {
    half8 a[2];
#pragma unroll
    for (int rf = 0; rf < 2; ++rf) {
      int l = wv * 32 + rf * 16 + rsel;
      a[rf] = *(const half8*)&xb[(size_t)l * 384 + 320 + kk * 32 + q * 8];
    }
#pragma unroll
    for (int cf = 0; cf < 8; ++cf) {
      int j = cf * 16 + rsel;
      half8 b = *(const half8*)&xb[(size_t)j * 384 + 256 + kk * 32 + q * 8];
      gacc[0][cf] = __builtin_amdgcn_mfma_f32_16x16x32_f16(a[0], b, gacc[0][cf], 0, 0, 0);
      gacc[1][cf] = __builtin_amdgcn_mfma_f32_16x16x32_f16(a[1], b, gacc[1][cf], 0, 0, 0);
    }
  }
#pragma unroll
  for (int rf = 0; rf < 2; ++rf) {
#pragma unroll
    for (int r = 0; r < 4; ++r) {
      int l = wv * 32 + rf * 16 + q * 4 + r;
#pragma unroll
      for (int cf = 0; cf < 8; ++cf) {
        int j = cf * 16 + rsel;
        G[l * 128 + (((j >> 3) ^ (l & 7)) << 3) + (j & 7)] = (_Float16)gacc[rf][cf][r];
      }
    }
  }
  __syncthreads();

  // phase 2: per head
  _Float16* yp = ys + (size_t)seq * 32768;
  for (int h = 0; h < 8; ++h) {
    {
      int j = tid >> 1, ds = (tid & 1) * 16;
      float dtj = dts[j * 8 + h];
      half8 v0 = *(const half8*)&xb[(size_t)j * 384 + h * 32 + ds];
      half8 v1 = *(const half8*)&xb[(size_t)j * 384 + h * 32 + ds + 8];
#pragma unroll
      for (int e = 0; e < 8; ++e) {
        int d0 = ds + e, d1 = ds + 8 + e;
        Xt[d0 * 128 + (((j >> 3) ^ (d0 & 7)) << 3) + (j & 7)] = (_Float16)((float)v0[e] * dtj);
        Xt[d1 * 128 + (((j >> 3) ^ (d1 & 7)) << 3) + (j & 7)] = (_Float16)((float)v1[e] * dtj);
      }
    }
    __syncthreads();
    float Ah = -__expf(P[P_ALOG + h]);
    float Dk = P[P_DSKIP + h];
    f32x4 acc[2][2];
#pragma unroll
    for (int rf = 0; rf < 2; ++rf)
#pragma unroll
      for (int cf = 0; cf < 2; ++cf) acc[rf][cf] = (f32x4){0.f, 0.f, 0.f, 0.f};
#pragma unroll
    for (int kk = 0; kk < 4; ++kk) {
      int jb = kk * 32 + q * 8;
      int chk = kk * 4 + q;
      float4 tj0 = *(const float4*)&Ts[h * 128 + jb];
      float4 tj1 = *(const float4*)&Ts[h * 128 + jb + 4];
      float tj[8] = {tj0.x, tj0.y, tj0.z, tj0.w, tj1.x, tj1.y, tj1.z, tj1.w};
      half8 a[2];
#pragma unroll
      for (int rf = 0; rf < 2; ++rf) {
        int l = wv * 32 + rf * 16 + rsel;
        half8 g = *(const half8*)&G[l * 128 + ((chk ^ (l & 7)) << 3)];
        float Tl = Ts[h * 128 + l];
        half8 w;
#pragma unroll
        for (int e = 0; e < 8; ++e) {
          int j = jb + e;
          float m = (j <= l) ? __expf(Ah * (Tl - tj[e])) : 0.f;
          w[e] = (_Float16)((float)g[e] * m);
        }
        a[rf] = w;
      }
#pragma unroll
      for (int cf = 0; cf < 2; ++cf) {
        int d = cf * 16 + rsel;
        half8 b = *(const half8*)&Xt[d * 128 + ((chk ^ (d & 7)) << 3)];
        acc[0][cf] = __builtin_amdgcn_mfma_f32_16x16x32_f16(a[0], b, acc[0][cf], 0, 0, 0);
        acc[1][cf] = __builtin_amdgcn_mfma_f32_16x16x32_f16(a[1], b, acc[1][cf], 0, 0, 0);
      }
    }
#pragma unroll
    for (int rf = 0; rf < 2; ++rf) {
      int lb = wv * 32 + rf * 16 + q * 4;
#pragma unroll
      for (int cf = 0; cf < 2; ++cf) {
        int d = cf * 16 + rsel;
#pragma unroll
        for (int r = 0; r < 4; ++r) {
          int l = lb + r;
          float xv = (float)xb[(size_t)l * 384 + h * 32 + d];
          yp[(size_t)l * 256 + h * 32 + d] = (_Float16)(acc[rf][cf][r] + Dk * xv);
        }
      }
    }
    __syncthreads();
  }
}

// ---------------- K7 v7: gate + RMS norm -> ynorm f16 ----------------------------
__global__ __launch_bounds__(256) void k_gate_v7(const _Float16* __restrict__ ys,
                                                 const _Float16* __restrict__ zh,
                                                 const float* __restrict__ P,
                                                 _Float16* __restrict__ ynh) {
  int l = blockIdx.x;
  int e = threadIdx.x;
  __shared__ float red[4];
  size_t idx = (size_t)l * 256 + e;
  float yv = (float)ys[idx];
  float zv = (float)zh[idx];
  float g = zv / (1.f + __expf(-zv));
  float y = yv * g;
  float ss = y * y;
  for (int o = 32; o; o >>= 1) ss += __shfl_down(ss, o, 64);
  if ((threadIdx.x & 63) == 0) red[threadIdx.x >> 6] = ss;
  __syncthreads();
  float tot = red[0] + red[1] + red[2] + red[3];
  float r = rsqrtf(tot * (1.f / 256.f) + 1e-5f);
  ynh[idx] = (_Float16)(y * r * P[P_NG + e]);
}

// ---------------- G2 v3: out = ynorm @ outw^T via MFMA f16 ----------------------
__global__ __launch_bounds__(256) void k_gemm2_v3(const _Float16* __restrict__ ynh,
                                                  const _Float16* __restrict__ outwh,
                                                  float* __restrict__ dout,
                                                  int tok0) {
  __shared__ __align__(16) _Float16 lA[128 * 64];
  __shared__ __align__(16) _Float16 lB[64 * 64];
  int t0 = blockIdx.x * 64;
  int tid = threadIdx.x;
  int lane = tid & 63;
  int wv = tid >> 6;
  f32x4 acc[2][4];
#pragma unroll
  for (int rf = 0; rf < 2; ++rf)
#pragma unroll
    for (int cf = 0; cf < 4; ++cf) acc[rf][cf] = (f32x4){0.f, 0.f, 0.f, 0.f};

  int rsel = lane & 15, q = lane >> 4;
  for (int k0 = 0; k0 < 256; k0 += 64) {
    if (k0) __syncthreads();
#pragma unroll
    for (int p = 0; p < 4; ++p) {
      int idx = tid + 256 * p;
      int row = idx >> 3, ch = idx & 7;
      int dch = ch ^ (row & 7);
      *(half8*)&lA[row * 64 + dch * 8] =
          *(const half8*)&outwh[(size_t)row * 256 + k0 + ch * 8];
    }
#pragma unroll
    for (int p = 0; p < 2; ++p) {
      int idx = tid + 256 * p;
      int row = idx >> 3, ch = idx & 7;
      int dch = ch ^ (row & 7);
      *(half8*)&lB[row * 64 + dch * 8] =
          *(const half8*)&ynh[(size_t)(t0 + row) * 256 + k0 + ch * 8];
    }
    __syncthreads();
#pragma unroll
    for (int kk = 0; kk < 2; ++kk) {
      half8 a[2];
#pragma unroll
      for (int rf = 0; rf < 2; ++rf) {
        int row = wv * 32 + rf * 16 + rsel;
        int ch = (kk * 4 + q) ^ (row & 7);
        a[rf] = *(const half8*)&lA[row * 64 + ch * 8];
      }
#pragma unroll
      for (int cf = 0; cf < 4; ++cf) {
        int row = cf * 16 + rsel;
        int ch = (kk * 4 + q) ^ (row & 7);
        half8 b = *(const half8*)&lB[row * 64 + ch * 8];
        acc[0][cf] = __builtin_amdgcn_mfma_f32_16x16x32_f16(a[0], b, acc[0][cf], 0, 0, 0);
        acc[1][cf] = __builtin_amdgcn_mfma_f32_16x16x32_f16(a[1], b, acc[1][cf], 0, 0, 0);
      }
    }
  }

  int l0 = tok0 + t0;
  int b = l0 >> 14;
  int rem0 = l0 & 16383;
#pragma unroll
  for (int rf = 0; rf < 2; ++rf) {
    int cbase = wv * 32 + rf * 16 + q * 4;
#pragma unroll
    for (int cf = 0; cf < 4; ++cf) {
#pragma unroll
      for (int r = 0; r < 4; ++r) {
        dout[(size_t)(b * 128 + cbase + r) * 16384 + rem0 + cf * 16 + rsel] = acc[rf][cf][r];
      }
    }
  }
}

extern "C" void kernel_launch(void* const* d_in, const int* in_sizes, int n_in,
                              void* d_out, int out_size, void* d_ws, size_t ws_size,
                              hipStream_t stream) {
  const void* x      = d_in[0];
  const void* dww    = d_in[1];
  const void* gng    = d_in[2];
  const void* gnb    = d_in[3];
  const void* pww    = d_in[4];
  const void* pwb    = d_in[5];
  const void* wproj  = d_in[6];
  const void* cw     = d_in[7];
  const void* cb     = d_in[8];
  const void* dtbias = d_in[9];
  const void* alog   = d_in[10];
  const void* dskip  = d_in[11];
  const void* ng     = d_in[12];
  const void* outw   = d_in[13];
  float* out = (float*)d_out;

  char* ws = (char*)d_ws;
  float* gst        = (float*)(ws + 0);
  float* mr         = (float*)(ws + 4096);
  float* P          = (float*)(ws + 8192);
  _Float16* wprojh  = (_Float16*)(ws + 40960);
  _Float16* outwh   = (_Float16*)(ws + 372736);
  float* offf       = (float*)(ws + 503808);
  char* cbase       = ws + 1028096;

  // h1 (f32, 67,108,864 B) lives in d_out's out_2d region.
  float* h1f = out;

  // Per-sequence chunk bytes:
  //   seq f16 32768 + zh f16 65536 + xch f16 98304 + dtb 4096 + ys f16 65536
  //   = 266240.  (ynorm f16 reuses xch region, dead after ssd.)
  const int opts[11] = {1024, 512, 256, 128, 64, 32, 16, 8, 4, 2, 1};
  int CH = 1;
  for (int i = 0; i < 11; ++i) {
    if (1028096ull + (unsigned long long)opts[i] * 266240ull <= (unsigned long long)ws_size) {
      CH = opts[i];
      break;
    }
  }
  int NC = 1024 / CH;

  _Float16* seqh = (_Float16*)(cbase);
  _Float16* zh   = (_Float16*)(cbase + (size_t)CH * 32768);
  _Float16* xch  = (_Float16*)(cbase + (size_t)CH * 98304);
  float* dtbf    = (float*)(cbase + (size_t)CH * 196608);
  _Float16* ysh  = (_Float16*)(cbase + (size_t)CH * 200704);
  _Float16* ynh  = xch;   // xch dead after ssd

  k_prep_params<<<1, 256, 0, stream>>>(dww, cw, cb, gng, gnb, pww, pwb, dtbias,
                                       alog, dskip, ng, P, gst);
  k_prep_w<<<128, 256, 0, stream>>>(wproj, outw, gng, wprojh, outwh);
  k_dwconv_v4<<<4096, 256, 0, stream>>>(x, gng, P, h1f, gst);
  k_stats<<<1, 64, 0, stream>>>(gst, mr);
  k_gn_off_v2<<<1024, 256, 0, stream>>>(h1f, mr, P, offf, out);

  int M = CH * 128;
  for (int c = 0; c < NC; ++c) {
    int s0 = c * CH;
    k_deform_v3<<<CH, 256, 0, stream>>>(x, gng, offf, seqh, s0);
    k_gemm1_v6<<<dim3(M / 128, 6), 256, 0, stream>>>(seqh, wprojh, P, zh, xch, dtbf);
    k_ssd<<<CH, 256, 0, stream>>>(xch, dtbf, P, ysh);
    k_gate_v7<<<CH * 128, 256, 0, stream>>>(ysh, zh, P, ynh);
    k_gemm2_v3<<<dim3(M / 64), 256, 0, stream>>>(ynh, outwh, out, s0 * 128);
  }
}

// Round 12
// 544.199 us; speedup vs baseline: 3.0389x; 1.0909x over previous
//
#include <hip/hip_runtime.h>
#include <math.h>

// B=8, C=128, H=128, W=128, D_INNER=256, D_STATE=64, HEADDIM=32, NHEADS=8,
// D_CONV=4, GN_GROUPS=8, D_XBC=384, D_INPROJ=648.
// Inputs f32 (probed via gn_g word0). OUTPUT IS F32 (reference output dtype).
// d_out = [out_2d: 16,777,216 f32][offset: 131,072 f32].
// h1 (f16 since R12) is staged in d_out's out_2d region.
//
// R1 scan de-spill 3236 -> R2 reg-blocked GEMMs 2123 -> R3 MFMA f16 1078 ->
// R6 scan LDS-tiled 1074 -> R7 conv fused + deform v2 866 -> R8 800 ->
// R9 778 -> R10 SSD matrix-form scan 679 -> R11 conv1d fused into gemm1 594.
// R12: (a) dwconv v5 - LDS staging RETURNS with aligned layout [36][136]
// (v3's conflicts were the +2 misaligned halo forcing b64 pairs; v4's LDS-free
// was latency-bound at VALUBusy 16%): b128 conflict-free stage, 3 aligned b128
// LDS reads/row, zero-padded halo chunks. (b) h1 stored f16 (write+read traffic
// halved). (c) gate v8: grid 65536 -> CH blocks (8 tokens/pass, shfl reduce).

typedef _Float16 half8 __attribute__((ext_vector_type(8)));
typedef _Float16 half4 __attribute__((ext_vector_type(4)));
typedef float f32x4 __attribute__((ext_vector_type(4)));

__device__ __forceinline__ float b2f(unsigned short u) {
  return __uint_as_float(((unsigned int)u) << 16);
}
__device__ __forceinline__ bool in_is_f32(const void* gng) {
  return ((const unsigned int*)gng)[0] == 0x3F800000u;
}

#define P_DWW 0
#define P_CW 3200
#define P_CB 4736
#define P_GNG 5120
#define P_GNB 5248
#define P_PWW 5376
#define P_PWB 5504
#define P_DTB 5505
#define P_ALOG 5513
#define P_DSKIP 5521
#define P_NG 5529

__global__ void k_prep_params(const void* dww, const void* cw, const void* cb,
                              const void* gng, const void* gnb, const void* pww,
                              const void* pwb, const void* dtbias, const void* alog,
                              const void* dskip, const void* ng, float* __restrict__ P,
                              float* __restrict__ gst) {
  bool f = in_is_f32(gng);
  int tid = threadIdx.x;
  if (tid < 128) gst[tid] = 0.f;
  auto cvt = [&](const void* src, int n, int off) {
    for (int i = tid; i < n; i += 256)
      P[off + i] = f ? ((const float*)src)[i] : b2f(((const unsigned short*)src)[i]);
  };
  cvt(dww, 3200, P_DWW);
  cvt(cw, 1536, P_CW);
  cvt(cb, 384, P_CB);
  cvt(gng, 128, P_GNG);
  cvt(gnb, 128, P_GNB);
  cvt(pww, 128, P_PWW);
  cvt(pwb, 1, P_PWB);
  cvt(dtbias, 8, P_DTB);
  cvt(alog, 8, P_ALOG);
  cvt(dskip, 8, P_DSKIP);
  cvt(ng, 256, P_NG);
}

// wprojh: 768 x 128 f16 (rows >=648 zero).  outwh: 128 x 256 f16.
__global__ void k_prep_w(const void* wproj, const void* outw, const void* gng,
                         _Float16* __restrict__ wprojh, _Float16* __restrict__ outwh) {
  bool f = in_is_f32(gng);
  int stride = gridDim.x * blockDim.x;
  for (int i = blockIdx.x * blockDim.x + threadIdx.x; i < 98304; i += stride) {
    int row = i >> 7;
    float v = 0.f;
    if (row < 648) v = f ? ((const float*)wproj)[i] : b2f(((const unsigned short*)wproj)[i]);
    wprojh[i] = (_Float16)v;
  }
  for (int i = blockIdx.x * blockDim.x + threadIdx.x; i < 32768; i += stride)
    outwh[i] = (_Float16)(f ? ((const float*)outw)[i] : b2f(((const unsigned short*)outw)[i]));
}

// ---------------- K1 v5: depthwise 5x5 conv + group stats, aligned LDS ----------
// 4 blocks per (b,c): 128w x 32h tile. LDS [36][136] f32: data at float col 4*cq
// (16B-aligned, conflict-free b128 stage: consecutive lanes -> consecutive
// chunks), cols 128..135 zero pad. Compute: 3 aligned b128 LDS reads per row
// (chunk ox-4 predicated-zero), 4x4 outputs/thread. h1 out f16.
__global__ __launch_bounds__(256) void k_dwconv_v5(const void* __restrict__ x,
                                                   const void* __restrict__ gng,
                                                   const float* __restrict__ P,
                                                   _Float16* __restrict__ h1h,
                                                   float* __restrict__ gst) {
  int blk = blockIdx.x;
  int bc = blk >> 2, sub = blk & 3;
  int b = bc >> 7, c = bc & 127;
  int ty0 = sub * 32;
  bool f32x = in_is_f32(gng);
  __shared__ __align__(16) float t[36 * 136];
  __shared__ float red[8];
  const float* xf = (const float*)x + (size_t)bc * 16384;
  const unsigned short* xb = (const unsigned short*)x + (size_t)bc * 16384;
  // zero pad cols 128..135
  for (int i = threadIdx.x; i < 72; i += 256) {
    int r = i >> 1;
    *(float4*)&t[136 * r + 128 + (i & 1) * 4] = make_float4(0.f, 0.f, 0.f, 0.f);
  }
  // stage 36 rows x 128 cols, aligned b128
  for (int i = threadIdx.x; i < 1152; i += 256) {
    int r = i >> 5, cq = i & 31;
    int gy = ty0 + r - 2;
    float4 v = make_float4(0.f, 0.f, 0.f, 0.f);
    if (gy >= 0 && gy < 128) {
      if (f32x) {
        v = *(const float4*)(xf + gy * 128 + cq * 4);
      } else {
        ushort4 u = *(const ushort4*)(xb + gy * 128 + cq * 4);
        v = make_float4(b2f(u.x), b2f(u.y), b2f(u.z), b2f(u.w));
      }
    }
    *(float4*)&t[136 * r + 4 * cq] = v;
  }
  float w[25];
#pragma unroll
  for (int k = 0; k < 25; ++k) w[k] = P[P_DWW + c * 25 + k];
  __syncthreads();

  int ox = (threadIdx.x & 31) * 4;   // 0..124
  int oy = (threadIdx.x >> 5) * 4;   // 0..28
  float acc[4][4];
#pragma unroll
  for (int r = 0; r < 4; ++r)
#pragma unroll
    for (int j = 0; j < 4; ++j) acc[r][j] = 0.f;

#pragma unroll
  for (int i = 0; i < 8; ++i) {
    int base = 136 * (oy + i);
    float4 c0 = make_float4(0.f, 0.f, 0.f, 0.f);
    if (ox >= 4) c0 = *(const float4*)&t[base + ox - 4];
    float4 c1 = *(const float4*)&t[base + ox];
    float4 c2 = *(const float4*)&t[base + ox + 4];
    float in12[12] = {c0.x, c0.y, c0.z, c0.w, c1.x, c1.y, c1.z, c1.w,
                      c2.x, c2.y, c2.z, c2.w};
#pragma unroll
    for (int r = 0; r < 4; ++r) {
      if (i - r >= 0 && i - r <= 4) {
        int ky = i - r;
#pragma unroll
        for (int j = 0; j < 4; ++j)
#pragma unroll
          for (int kx = 0; kx < 5; ++kx)
            acc[r][j] += w[ky * 5 + kx] * in12[j + kx + 2];
      }
    }
  }

  float s = 0.f, sq = 0.f;
  _Float16* hp = h1h + (size_t)bc * 16384;
#pragma unroll
  for (int r = 0; r < 4; ++r) {
    half4 o;
#pragma unroll
    for (int j = 0; j < 4; ++j) {
      o[j] = (_Float16)acc[r][j];
      s += acc[r][j]; sq += acc[r][j] * acc[r][j];
    }
    *(half4*)&hp[(ty0 + oy + r) * 128 + ox] = o;
  }
  for (int o = 32; o; o >>= 1) { s += __shfl_down(s, o, 64); sq += __shfl_down(sq, o, 64); }
  int wv = threadIdx.x >> 6;
  if ((threadIdx.x & 63) == 0) { red[wv] = s; red[4 + wv] = sq; }
  __syncthreads();
  if (threadIdx.x == 0) {
    float ts = red[0] + red[1] + red[2] + red[3];
    float tq = red[4] + red[5] + red[6] + red[7];
    int g = (b << 3) + (c >> 4);
    atomicAdd(&gst[g * 2], ts);
    atomicAdd(&gst[g * 2 + 1], tq);
  }
}

__global__ void k_stats(const float* __restrict__ gst, float* __restrict__ mr) {
  int g = threadIdx.x;
  if (g < 64) {
    const float invN = 1.f / 262144.f;
    float mean = gst[g * 2] * invN;
    float var = gst[g * 2 + 1] * invN - mean * mean;
    mr[g * 2] = mean;
    mr[g * 2 + 1] = rsqrtf(var + 1e-5f);
  }
}

// ---------------- K3 v3: GN + GELU + 1x1 conv + tanh*8 -> offset (h1 f16) -------
__global__ __launch_bounds__(256) void k_gn_off_v3(const _Float16* __restrict__ h1h,
                                                   const float* __restrict__ mr,
                                                   const float* __restrict__ P,
                                                   float* __restrict__ offf,
                                                   float* __restrict__ dout) {
  int bh = blockIdx.x;
  int b = bh >> 7, h = bh & 127;
  int tid = threadIdx.x;
  int w = tid & 127;
  int chh = tid >> 7;
  __shared__ float sacc[2][128];
  float acc = 0.f;
  for (int ci = 0; ci < 64; ++ci) {
    int c = chh * 64 + ci;
    float v = (float)h1h[(((size_t)(b * 128 + c)) * 128 + h) * 128 + w];
    int g = b * 8 + (c >> 4);
    float nv = (v - mr[g * 2]) * mr[g * 2 + 1] * P[P_GNG + c] + P[P_GNB + c];
    float ge = 0.5f * nv * (1.f + erff(nv * 0.70710678118f));
    acc += ge * P[P_PWW + c];
  }
  sacc[chh][w] = acc;
  __syncthreads();
  if (chh == 0) {
    float off = acc + sacc[1][w] + P[P_PWB];
    float ofv = tanhf(off) * 8.0f;
    offf[bh * 128 + w] = ofv;
    dout[16777216 + bh * 128 + w] = ofv;
  }
}

// ---------------- K4 v3: y-only grid sample + transpose -> seq f16 (l,c) --------
__global__ __launch_bounds__(256) void k_deform_v3(const void* __restrict__ x,
                                                   const void* __restrict__ gng,
                                                   const float* __restrict__ offf,
                                                   _Float16* __restrict__ seqc,
                                                   int s0) {
  int bh = s0 + blockIdx.x;
  int b = bh >> 7, h = bh & 127;
  int tid = threadIdx.x;
  int w = tid & 127;
  int half = tid >> 7;
  bool f32x = in_is_f32(gng);
  __shared__ float t[128 * 129];
  float ofv = offf[bh * 128 + w];
  float gy = -1.f + (2.f / 127.f) * (float)h + ofv * (2.f / 127.f);
  gy = fminf(fmaxf(gy, -1.f), 1.f);
  float py = (gy + 1.f) * 0.5f * 127.f;
  py = fminf(fmaxf(py, 0.f), 127.f);
  float y0f = floorf(py);
  float wy = py - y0f;
  int y0 = (int)y0f;
  int y1 = min(y0 + 1, 127);
  const float* xfb = (const float*)x + (size_t)b * 128 * 16384;
  const unsigned short* xbb = (const unsigned short*)x + (size_t)b * 128 * 16384;
  int c0 = half * 64;
  for (int i = 0; i < 64; ++i) {
    int c = c0 + i;
    size_t o0 = (size_t)c * 16384 + y0 * 128 + w;
    size_t o1 = (size_t)c * 16384 + y1 * 128 + w;
    float v0, v1;
    if (f32x) { v0 = xfb[o0]; v1 = xfb[o1]; }
    else      { v0 = b2f(xbb[o0]); v1 = b2f(xbb[o1]); }
    t[c * 129 + w] = v0 + wy * (v1 - v0);
  }
  __syncthreads();
  int c2 = tid & 127;
  int lb = (tid >> 7) * 64;
  _Float16* sp = seqc + (size_t)blockIdx.x * 16384;
  for (int i = 0; i < 64; ++i) {
    int l = lb + i;
    sp[l * 128 + c2] = (_Float16)t[c2 * 129 + l];
  }
}

// ---------------- G1 v6: zxbcdt GEMM with FUSED conv1d+SiLU epilogue ------------
__global__ __launch_bounds__(256) void k_gemm1_v6(const _Float16* __restrict__ seqh,
                                                  const _Float16* __restrict__ wprojh,
                                                  const float* __restrict__ P,
                                                  _Float16* __restrict__ zh,
                                                  _Float16* __restrict__ xch,
                                                  float* __restrict__ dtb) {
  __shared__ __align__(16) _Float16 lds[16384];   // lA | lB, reused as sx[128][128]
  _Float16* lA = lds;
  _Float16* lB = lds + 8192;
  int m0 = blockIdx.x * 128;
  int e0 = blockIdx.y * 128;
  int tid = threadIdx.x;
  int lane = tid & 63;
  int wv = tid >> 6;
  f32x4 acc[2][8];
#pragma unroll
  for (int rf = 0; rf < 2; ++rf)
#pragma unroll
    for (int cf = 0; cf < 8; ++cf) acc[rf][cf] = (f32x4){0.f, 0.f, 0.f, 0.f};

  int rsel = lane & 15, q = lane >> 4;
  for (int k0 = 0; k0 < 128; k0 += 64) {
    if (k0) __syncthreads();
#pragma unroll
    for (int p = 0; p < 4; ++p) {
      int idx = tid + 256 * p;
      int row = idx >> 3, ch = idx & 7;
      int dch = ch ^ (row & 7);
      *(half8*)&lA[row * 64 + dch * 8] =
          *(const half8*)&seqh[(size_t)(m0 + row) * 128 + k0 + ch * 8];
      *(half8*)&lB[row * 64 + dch * 8] =
          *(const half8*)&wprojh[(size_t)(e0 + row) * 128 + k0 + ch * 8];
    }
    __syncthreads();
#pragma unroll
    for (int kk = 0; kk < 2; ++kk) {
      half8 a[2];
#pragma unroll
      for (int rf = 0; rf < 2; ++rf) {
        int row = wv * 32 + rf * 16 + rsel;
        int ch = (kk * 4 + q) ^ (row & 7);
        a[rf] = *(const half8*)&lA[row * 64 + ch * 8];
      }
#pragma unroll
      for (int cf = 0; cf < 8; ++cf) {
        int row = cf * 16 + rsel;
        int ch = (kk * 4 + q) ^ (row & 7);
        half8 b = *(const half8*)&lB[row * 64 + ch * 8];
        acc[0][cf] = __builtin_amdgcn_mfma_f32_16x16x32_f16(a[0], b, acc[0][cf], 0, 0, 0);
        acc[1][cf] = __builtin_amdgcn_mfma_f32_16x16x32_f16(a[1], b, acc[1][cf], 0, 0, 0);
      }
    }
  }

  if (e0 < 256) {
#pragma unroll
    for (int rf = 0; rf < 2; ++rf) {
      int mb = m0 + wv * 32 + rf * 16 + q * 4;
#pragma unroll
      for (int cf = 0; cf < 8; ++cf) {
        _Float16* pz = zh + (size_t)mb * 256 + e0 + cf * 16 + rsel;
#pragma unroll
        for (int r = 0; r < 4; ++r) pz[(size_t)r * 256] = (_Float16)acc[rf][cf][r];
      }
    }
  } else if (e0 < 640) {
    __syncthreads();
#pragma unroll
    for (int rf = 0; rf < 2; ++rf) {
#pragma unroll
      for (int r = 0; r < 4; ++r) {
        int row = wv * 32 + rf * 16 + q * 4 + r;
#pragma unroll
        for (int cf = 0; cf < 8; ++cf)
          lds[row * 128 + cf * 16 + rsel] = (_Float16)acc[rf][cf][r];
      }
    }
    __syncthreads();
    int cc = tid & 127;
    int rh = tid >> 7;
    int eg = (e0 - 256) + cc;            // global xbc column 0..383
    float w0 = P[P_CW + eg * 4 + 0], w1 = P[P_CW + eg * 4 + 1];
    float w2 = P[P_CW + eg * 4 + 2], w3 = P[P_CW + eg * 4 + 3];
    float bb = P[P_CB + eg];
    int r0 = rh * 64;
    float x0 = (r0 >= 3) ? (float)lds[(r0 - 3) * 128 + cc] : 0.f;
    float x1 = (r0 >= 2) ? (float)lds[(r0 - 2) * 128 + cc] : 0.f;
    float x2 = (r0 >= 1) ? (float)lds[(r0 - 1) * 128 + cc] : 0.f;
    _Float16* xo = xch + (size_t)m0 * 384 + eg;
    for (int r = r0; r < r0 + 64; ++r) {
      float x3 = (float)lds[r * 128 + cc];
      float a = bb + w0 * x0 + w1 * x1 + w2 * x2 + w3 * x3;
      xo[(size_t)r * 384] = (_Float16)(a / (1.f + __expf(-a)));
      x0 = x1; x1 = x2; x2 = x3;
    }
  } else {
#pragma unroll
    for (int rf = 0; rf < 2; ++rf) {
      int mb = m0 + wv * 32 + rf * 16 + q * 4;
      if (rsel < 8) {
        float bias = P[P_DTB + rsel];
#pragma unroll
        for (int r = 0; r < 4; ++r) {
          float dv = acc[rf][0][r] + bias;
          float sp = (dv > 20.f) ? dv : log1pf(__expf(dv));
          dtb[(size_t)(mb + r) * 8 + rsel] = sp;
        }
      }
    }
  }
}

// ---------------- K6 v9: SSD matrix-form scan on matrix cores --------------------
__global__ __launch_bounds__(256) void k_ssd(const _Float16* __restrict__ xch,
                                             const float* __restrict__ dtb,
                                             const float* __restrict__ P,
                                             _Float16* __restrict__ ys) {
  int seq = blockIdx.x;
  int tid = threadIdx.x;
  int lane = tid & 63, wv = tid >> 6;
  int rsel = lane & 15, q = lane >> 4;
  __shared__ __align__(16) _Float16 G[128 * 128];   // 32 KB
  __shared__ __align__(16) _Float16 Xt[32 * 128];   // 8 KB
  __shared__ float dts[128 * 8];                    // 4 KB [l][h]
  __shared__ float Ts[8 * 128];                     // 4 KB [h][l]
  const _Float16* xb = xch + (size_t)seq * 49152;
  const float* dtp = dtb + (size_t)seq * 1024;

  for (int i = tid; i < 1024; i += 256) dts[i] = dtp[i];
  __syncthreads();
  if (tid < 8) {
    float a = 0.f;
    for (int l = 0; l < 128; ++l) { a += dts[l * 8 + tid]; Ts[tid * 128 + l] = a; }
  }

  // phase 1: G = C @ B^T
  f32x4 gacc[2][8];
#pragma unroll
  for (int rf = 0; rf < 2; ++rf)
#pragma unroll
    for (int cf = 0; cf < 8; ++cf) gacc[rf][cf] = (f32x4){0.f, 0.f, 0.f, 0.f};
#pragma unroll
  for (int kk = 0; kk < 2; ++kk) {
    half8 a[2];
#pragma unroll
    for (int rf = 0; rf < 2; ++rf) {
      int l = wv * 32 + rf * 16 + rsel;
      a[rf] = *(const half8*)&xb[(size_t)l * 384 + 320 + kk * 32 + q * 8];
    }
#pragma unroll
    for (int cf = 0; cf < 8; ++cf) {
      int j = cf * 16 + rsel;
      half8 b = *(const half8*)&xb[(size_t)j * 384 + 256 + kk * 32 + q * 8];
      gacc[0][cf] = __builtin_amdgcn_mfma_f32_16x16x32_f16(a[0], b, gacc[0][cf], 0, 0, 0);
      gacc[1][cf] = __builtin_amdgcn_mfma_f32_16x16x32_f16(a[1], b, gacc[1][cf], 0, 0, 0);
    }
  }
#pragma unroll
  for (int rf = 0; rf < 2; ++rf) {
#pragma unroll
    for (int r = 0; r < 4; ++r) {
      int l = wv * 32 + rf * 16 + q * 4 + r;
#pragma unroll
      for (int cf = 0; cf < 8; ++cf) {
        int j = cf * 16 + rsel;
        G[l * 128 + (((j >> 3) ^ (l & 7)) << 3) + (j & 7)] = (_Float16)gacc[rf][cf][r];
      }
    }
  }
  __syncthreads();

  // phase 2: per head
  _Float16* yp = ys + (size_t)seq * 32768;
  for (int h = 0; h < 8; ++h) {
    {
      int j = tid >> 1, ds = (tid & 1) * 16;
      float dtj = dts[j * 8 + h];
      half8 v0 = *(const half8*)&xb[(size_t)j * 384 + h * 32 + ds];
      half8 v1 = *(const half8*)&xb[(size_t)j * 384 + h * 32 + ds + 8];
#pragma unroll
      for (int e = 0; e < 8; ++e) {
        int d0 = ds + e, d1 = ds + 8 + e;
        Xt[d0 * 128 + (((j >> 3) ^ (d0 & 7)) << 3) + (j & 7)] = (_Float16)((float)v0[e] * dtj);
        Xt[d1 * 128 + (((j >> 3) ^ (d1 & 7)) << 3) + (j & 7)] = (_Float16)((float)v1[e] * dtj);
      }
    }
    __syncthreads();
    float Ah = -__expf(P[P_ALOG + h]);
    float Dk = P[P_DSKIP + h];
    f32x4 acc[2][2];
#pragma unroll
    for (int rf = 0; rf < 2; ++rf)
#pragma unroll
      for (int cf = 0; cf < 2; ++cf) acc[rf][cf] = (f32x4){0.f, 0.f, 0.f, 0.f};
#pragma unroll
    for (int kk = 0; kk < 4; ++kk) {
      int jb = kk * 32 + q * 8;
      int chk = kk * 4 + q;
      float4 tj0 = *(const float4*)&Ts[h * 128 + jb];
      float4 tj1 = *(const float4*)&Ts[h * 128 + jb + 4];
      float tj[8] = {tj0.x, tj0.y, tj0.z, tj0.w, tj1.x, tj1.y, tj1.z, tj1.w};
      half8 a[2];
#pragma unroll
      for (int rf = 0; rf < 2; ++rf) {
        int l = wv * 32 + rf * 16 + rsel;
        half8 g = *(const half8*)&G[l * 128 + ((chk ^ (l & 7)) << 3)];
        float Tl = Ts[h * 128 + l];
        half8 w;
#pragma unroll
        for (int e = 0; e < 8; ++e) {
          int j = jb + e;
          float m = (j <= l) ? __expf(Ah * (Tl - tj[e])) : 0.f;
          w[e] = (_Float16)((float)g[e] * m);
        }
        a[rf] = w;
      }
#pragma unroll
      for (int cf = 0; cf < 2; ++cf) {
        int d = cf * 16 + rsel;
        half8 b = *(const half8*)&Xt[d * 128 + ((chk ^ (d & 7)) << 3)];
        acc[0][cf] = __builtin_amdgcn_mfma_f32_16x16x32_f16(a[0], b, acc[0][cf], 0, 0, 0);
        acc[1][cf] = __builtin_amdgcn_mfma_f32_16x16x32_f16(a[1], b, acc[1][cf], 0, 0, 0);
      }
    }
#pragma unroll
    for (int rf = 0; rf < 2; ++rf) {
      int lb = wv * 32 + rf * 16 + q * 4;
#pragma unroll
      for (int cf = 0; cf < 2; ++cf) {
        int d = cf * 16 + rsel;
#pragma unroll
        for (int r = 0; r < 4; ++r) {
          int l = lb + r;
          float xv = (float)xb[(size_t)l * 384 + h * 32 + d];
          yp[(size_t)l * 256 + h * 32 + d] = (_Float16)(acc[rf][cf][r] + Dk * xv);
        }
      }
    }
    __syncthreads();
  }
}

// ---------------- K7 v8: gate + RMS norm, block per SEQ --------------------------
// 256 thr: 8 tokens per pass (32 lanes/token, 8 ch/lane f16x8), 16 passes.
__global__ __launch_bounds__(256) void k_gate_v8(const _Float16* __restrict__ ys,
                                                 const _Float16* __restrict__ zh,
                                                 const float* __restrict__ P,
                                                 _Float16* __restrict__ ynh) {
  int seq = blockIdx.x;
  size_t base = (size_t)seq * 32768;
  int lane = threadIdx.x & 63;
  int wv = threadIdx.x >> 6;
  int sub = lane >> 5;     // token parity within wave
  int ln = lane & 31;      // 32 lanes per token
  for (int it = 0; it < 16; ++it) {
    int l = it * 8 + wv * 2 + sub;
    size_t off = base + (size_t)l * 256 + ln * 8;
    half8 yv8 = *(const half8*)&ys[off];
    half8 zv8 = *(const half8*)&zh[off];
    float yg[8];
    float ss = 0.f;
#pragma unroll
    for (int e = 0; e < 8; ++e) {
      float zv = (float)zv8[e];
      float g = zv / (1.f + __expf(-zv));
      float y = (float)yv8[e] * g;
      yg[e] = y;
      ss += y * y;
    }
    ss += __shfl_xor(ss, 1, 64);
    ss += __shfl_xor(ss, 2, 64);
    ss += __shfl_xor(ss, 4, 64);
    ss += __shfl_xor(ss, 8, 64);
    ss += __shfl_xor(ss, 16, 64);
    float r = rsqrtf(ss * (1.f / 256.f) + 1e-5f);
    half8 o;
#pragma unroll
    for (int e = 0; e < 8; ++e) o[e] = (_Float16)(yg[e] * r * P[P_NG + ln * 8 + e]);
    *(half8*)&ynh[off] = o;
  }
}

// ---------------- G2 v3: out = ynorm @ outw^T via MFMA f16 ----------------------
__global__ __launch_bounds__(256) void k_gemm2_v3(const _Float16* __restrict__ ynh,
                                                  const _Float16* __restrict__ outwh,
                                                  float* __restrict__ dout,
                                                  int tok0) {
  __shared__ __align__(16) _Float16 lA[128 * 64];
  __shared__ __align__(16) _Float16 lB[64 * 64];
  int t0 = blockIdx.x * 64;
  int tid = threadIdx.x;
  int lane = tid & 63;
  int wv = tid >> 6;
  f32x4 acc[2][4];
#pragma unroll
  for (int rf = 0; rf < 2; ++rf)
#pragma unroll
    for (int cf = 0; cf < 4; ++cf) acc[rf][cf] = (f32x4){0.f, 0.f, 0.f, 0.f};

  int rsel = lane & 15, q = lane >> 4;
  for (int k0 = 0; k0 < 256; k0 += 64) {
    if (k0) __syncthreads();
#pragma unroll
    for (int p = 0; p < 4; ++p) {
      int idx = tid + 256 * p;
      int row = idx >> 3, ch = idx & 7;
      int dch = ch ^ (row & 7);
      *(half8*)&lA[row * 64 + dch * 8] =
          *(const half8*)&outwh[(size_t)row * 256 + k0 + ch * 8];
    }
#pragma unroll
    for (int p = 0; p < 2; ++p) {
      int idx = tid + 256 * p;
      int row = idx >> 3, ch = idx & 7;
      int dch = ch ^ (row & 7);
      *(half8*)&lB[row * 64 + dch * 8] =
          *(const half8*)&ynh[(size_t)(t0 + row) * 256 + k0 + ch * 8];
    }
    __syncthreads();
#pragma unroll
    for (int kk = 0; kk < 2; ++kk) {
      half8 a[2];
#pragma unroll
      for (int rf = 0; rf < 2; ++rf) {
        int row = wv * 32 + rf * 16 + rsel;
        int ch = (kk * 4 + q) ^ (row & 7);
        a[rf] = *(const half8*)&lA[row * 64 + ch * 8];
      }
#pragma unroll
      for (int cf = 0; cf < 4; ++cf) {
        int row = cf * 16 + rsel;
        int ch = (kk * 4 + q) ^ (row & 7);
        half8 b = *(const half8*)&lB[row * 64 + ch * 8];
        acc[0][cf] = __builtin_amdgcn_mfma_f32_16x16x32_f16(a[0], b, acc[0][cf], 0, 0, 0);
        acc[1][cf] = __builtin_amdgcn_mfma_f32_16x16x32_f16(a[1], b, acc[1][cf], 0, 0, 0);
      }
    }
  }

  int l0 = tok0 + t0;
  int b = l0 >> 14;
  int rem0 = l0 & 16383;
#pragma unroll
  for (int rf = 0; rf < 2; ++rf) {
    int cbase = wv * 32 + rf * 16 + q * 4;
#pragma unroll
    for (int cf = 0; cf < 4; ++cf) {
#pragma unroll
      for (int r = 0; r < 4; ++r) {
        dout[(size_t)(b * 128 + cbase + r) * 16384 + rem0 + cf * 16 + rsel] = acc[rf][cf][r];
      }
    }
  }
}

extern "C" void kernel_launch(void* const* d_in, const int* in_sizes, int n_in,
                              void* d_out, int out_size, void* d_ws, size_t ws_size,
                              hipStream_t stream) {
  const void* x      = d_in[0];
  const void* dww    = d_in[1];
  const void* gng    = d_in[2];
  const void* gnb    = d_in[3];
  const void* pww    = d_in[4];
  const void* pwb    = d_in[5];
  const void* wproj  = d_in[6];
  const void* cw     = d_in[7];
  const void* cb     = d_in[8];
  const void* dtbias = d_in[9];
  const void* alog   = d_in[10];
  const void* dskip  = d_in[11];
  const void* ng     = d_in[12];
  const void* outw   = d_in[13];
  float* out = (float*)d_out;

  char* ws = (char*)d_ws;
  float* gst        = (float*)(ws + 0);
  float* mr         = (float*)(ws + 4096);
  float* P          = (float*)(ws + 8192);
  _Float16* wprojh  = (_Float16*)(ws + 40960);
  _Float16* outwh   = (_Float16*)(ws + 372736);
  float* offf       = (float*)(ws + 503808);
  char* cbase       = ws + 1028096;

  // h1 (f16, 33.5 MB) lives in d_out's out_2d region (fully overwritten later).
  _Float16* h1h = (_Float16*)out;

  // Per-sequence chunk bytes:
  //   seq f16 32768 + zh f16 65536 + xch f16 98304 + dtb 4096 + ys f16 65536
  //   = 266240.  (ynorm f16 reuses xch region, dead after ssd.)
  const int opts[11] = {1024, 512, 256, 128, 64, 32, 16, 8, 4, 2, 1};
  int CH = 1;
  for (int i = 0; i < 11; ++i) {
    if (1028096ull + (unsigned long long)opts[i] * 266240ull <= (unsigned long long)ws_size) {
      CH = opts[i];
      break;
    }
  }
  int NC = 1024 / CH;

  _Float16* seqh = (_Float16*)(cbase);
  _Float16* zh   = (_Float16*)(cbase + (size_t)CH * 32768);
  _Float16* xch  = (_Float16*)(cbase + (size_t)CH * 98304);
  float* dtbf    = (float*)(cbase + (size_t)CH * 196608);
  _Float16* ysh  = (_Float16*)(cbase + (size_t)CH * 200704);
  _Float16* ynh  = xch;   // xch dead after ssd

  k_prep_params<<<1, 256, 0, stream>>>(dww, cw, cb, gng, gnb, pww, pwb, dtbias,
                                       alog, dskip, ng, P, gst);
  k_prep_w<<<128, 256, 0, stream>>>(wproj, outw, gng, wprojh, outwh);
  k_dwconv_v5<<<4096, 256, 0, stream>>>(x, gng, P, h1h, gst);
  k_stats<<<1, 64, 0, stream>>>(gst, mr);
  k_gn_off_v3<<<1024, 256, 0, stream>>>(h1h, mr, P, offf, out);

  int M = CH * 128;
  for (int c = 0; c < NC; ++c) {
    int s0 = c * CH;
    k_deform_v3<<<CH, 256, 0, stream>>>(x, gng, offf, seqh, s0);
    k_gemm1_v6<<<dim3(M / 128, 6), 256, 0, stream>>>(seqh, wprojh, P, zh, xch, dtbf);
    k_ssd<<<CH, 256, 0, stream>>>(xch, dtbf, P, ysh);
    k_gate_v8<<<CH, 256, 0, stream>>>(ysh, zh, P, ynh);
    k_gemm2_v3<<<dim3(M / 64), 256, 0, stream>>>(ynh, outwh, out, s0 * 128);
  }
}